// Round 1
// baseline (8891.623 us; speedup 1.0000x reference)
//
#include <hip/hip_runtime.h>

#define N_NODES 100000
#define N_EDGES 1600000
#define CDIM    128
#define BATCH   50000
#define NLAYERS 3
#define EPS_BN  1e-5f

// ---------------------------------------------------------------------------
// Fold BN params: s = g*rsqrt(v+eps), t = b - m*s
// Layout in sc[]: [0..383] layer scales, [384..767] layer shifts,
// [768..895] head1 scale, [896..1023] head1 shift,
// [1024..1087] head2 scale, [1088..1151] head2 shift
// ---------------------------------------------------------------------------
__global__ void fold_bn_kernel(const float* __restrict__ g, const float* __restrict__ b,
                               const float* __restrict__ m, const float* __restrict__ v,
                               const float* __restrict__ cg1, const float* __restrict__ cbe1,
                               const float* __restrict__ cm1, const float* __restrict__ cv1,
                               const float* __restrict__ cg2, const float* __restrict__ cbe2,
                               const float* __restrict__ cm2, const float* __restrict__ cv2,
                               float* __restrict__ sc) {
    int i = threadIdx.x;
    if (i < NLAYERS * CDIM) {
        float s = g[i] * rsqrtf(v[i] + EPS_BN);
        sc[i] = s;
        sc[NLAYERS * CDIM + i] = b[i] - m[i] * s;
    }
    if (i < CDIM) {
        float s = cg1[i] * rsqrtf(cv1[i] + EPS_BN);
        sc[768 + i] = s;
        sc[896 + i] = cbe1[i] - cm1[i] * s;
    }
    if (i < 64) {
        float s = cg2[i] * rsqrtf(cv2[i] + EPS_BN);
        sc[1024 + i] = s;
        sc[1088 + i] = cbe2[i] - cm2[i] * s;
    }
}

// ---------------------------------------------------------------------------
// Edge scatter: agg[dst] += h[src]; cnt[dst] += 1.
// 32 lanes per edge, each lane handles 4 channels (float4 gather + 4 atomics).
// ---------------------------------------------------------------------------
__global__ __launch_bounds__(256) void scatter_edges(const int* __restrict__ ei,
                                                     const float* __restrict__ h,
                                                     float* __restrict__ agg,
                                                     float* __restrict__ cnt) {
    int t = blockIdx.x * 256 + threadIdx.x;
    int e = t >> 5;
    int lane = t & 31;
    if (e >= N_EDGES) return;
    int s = ei[e];
    int d = ei[N_EDGES + e];
    float4 v = ((const float4*)(h + (size_t)s * CDIM))[lane];
    float* ar = agg + (size_t)d * CDIM + lane * 4;
    atomicAdd(ar + 0, v.x);
    atomicAdd(ar + 1, v.y);
    atomicAdd(ar + 2, v.z);
    atomicAdd(ar + 3, v.w);
    if (lane == 0) atomicAdd(cnt + d, 1.0f);
}

// ---------------------------------------------------------------------------
// Fused SAGE layer (in-place on h):
//   h[i,c] = relu( (agg[i,:]/max(cnt,1)) @ Wl + bl + h[i,:] @ Wr )[c] * s[c] + t[c]
// Block: 32 rows x 128 cols, 256 threads, 4x4 register tile per thread.
// ---------------------------------------------------------------------------
__global__ __launch_bounds__(256) void sage_gemm(const float* __restrict__ agg,
                                                 const float* __restrict__ cnt,
                                                 float* __restrict__ h,
                                                 const float* __restrict__ Wl,
                                                 const float* __restrict__ bl,
                                                 const float* __restrict__ Wr,
                                                 const float* __restrict__ scale,
                                                 const float* __restrict__ shift) {
    __shared__ float sA[32][CDIM + 4];  // row stride 132 floats: 16B-aligned rows, bank shift 4/row
    __shared__ float sH[32][CDIM + 4];

    int row0 = blockIdx.x * 32;
    int tid = threadIdx.x;

    // Stage tiles: 32 rows x 128 cols each => 1024 float4 per array, 4 per thread
    for (int it = 0; it < 4; ++it) {
        int idx = it * 256 + tid;       // 0..1023
        int r = idx >> 5;               // 32 float4 per row
        int c4 = idx & 31;
        int row = row0 + r;
        float rin = 1.0f / fmaxf(cnt[row], 1.0f);
        float4 a = ((const float4*)(agg + (size_t)row * CDIM))[c4];
        a.x *= rin; a.y *= rin; a.z *= rin; a.w *= rin;
        *((float4*)&sA[r][c4 * 4]) = a;
        float4 hv = ((const float4*)(h + (size_t)row * CDIM))[c4];
        *((float4*)&sH[r][c4 * 4]) = hv;
    }
    __syncthreads();

    int cg = tid & 31;       // col group: cols cg*4 .. cg*4+3
    int rg = tid >> 5;       // row group: rows rg*4 .. rg*4+3
    int c0 = cg * 4;
    int r0 = rg * 4;

    float acc[4][4];
#pragma unroll
    for (int r = 0; r < 4; ++r)
#pragma unroll
        for (int c = 0; c < 4; ++c) acc[r][c] = 0.0f;

    for (int k = 0; k < CDIM; ++k) {
        float4 wl = ((const float4*)(Wl + (size_t)k * CDIM))[cg];
        float4 wr = ((const float4*)(Wr + (size_t)k * CDIM))[cg];
#pragma unroll
        for (int r = 0; r < 4; ++r) {
            float a = sA[r0 + r][k];
            float hh = sH[r0 + r][k];
            acc[r][0] += a * wl.x + hh * wr.x;
            acc[r][1] += a * wl.y + hh * wr.y;
            acc[r][2] += a * wl.z + hh * wr.z;
            acc[r][3] += a * wl.w + hh * wr.w;
        }
    }

    float4 bb = *((const float4*)(bl + c0));
    float4 ss = *((const float4*)(scale + c0));
    float4 tt = *((const float4*)(shift + c0));
#pragma unroll
    for (int r = 0; r < 4; ++r) {
        float4 o;
        o.x = fmaxf(acc[r][0] + bb.x, 0.0f) * ss.x + tt.x;
        o.y = fmaxf(acc[r][1] + bb.y, 0.0f) * ss.y + tt.y;
        o.z = fmaxf(acc[r][2] + bb.z, 0.0f) * ss.z + tt.z;
        o.w = fmaxf(acc[r][3] + bb.w, 0.0f) * ss.w + tt.w;
        ((float4*)(h + (size_t)(row0 + r0 + r) * CDIM))[cg] = o;
    }
}

// ---------------------------------------------------------------------------
// Head GEMM 1: out[i,c] = relu( (hin[i,:] @ W + bias)[c] * s[c] + t[c] ), 128->128
// ---------------------------------------------------------------------------
__global__ __launch_bounds__(256) void head_gemm1(const float* __restrict__ hin,
                                                  const float* __restrict__ W,
                                                  const float* __restrict__ bias,
                                                  const float* __restrict__ scale,
                                                  const float* __restrict__ shift,
                                                  float* __restrict__ out) {
    __shared__ float sH[32][CDIM + 4];
    int row0 = blockIdx.x * 32;
    int tid = threadIdx.x;

    for (int it = 0; it < 4; ++it) {
        int idx = it * 256 + tid;
        int r = idx >> 5;
        int c4 = idx & 31;
        int row = row0 + r;
        float4 hv = make_float4(0.f, 0.f, 0.f, 0.f);
        if (row < BATCH) hv = ((const float4*)(hin + (size_t)row * CDIM))[c4];
        *((float4*)&sH[r][c4 * 4]) = hv;
    }
    __syncthreads();

    int cg = tid & 31;
    int rg = tid >> 5;
    int c0 = cg * 4;
    int r0 = rg * 4;

    float acc[4][4];
#pragma unroll
    for (int r = 0; r < 4; ++r)
#pragma unroll
        for (int c = 0; c < 4; ++c) acc[r][c] = 0.0f;

    for (int k = 0; k < CDIM; ++k) {
        float4 w = ((const float4*)(W + (size_t)k * CDIM))[cg];
#pragma unroll
        for (int r = 0; r < 4; ++r) {
            float hh = sH[r0 + r][k];
            acc[r][0] += hh * w.x;
            acc[r][1] += hh * w.y;
            acc[r][2] += hh * w.z;
            acc[r][3] += hh * w.w;
        }
    }

    float4 bb = *((const float4*)(bias + c0));
    float4 ss = *((const float4*)(scale + c0));
    float4 tt = *((const float4*)(shift + c0));
#pragma unroll
    for (int r = 0; r < 4; ++r) {
        int row = row0 + r0 + r;
        if (row >= BATCH) continue;
        float4 o;
        o.x = fmaxf((acc[r][0] + bb.x) * ss.x + tt.x, 0.0f);
        o.y = fmaxf((acc[r][1] + bb.y) * ss.y + tt.y, 0.0f);
        o.z = fmaxf((acc[r][2] + bb.z) * ss.z + tt.z, 0.0f);
        o.w = fmaxf((acc[r][3] + bb.w) * ss.w + tt.w, 0.0f);
        ((float4*)(out + (size_t)row * CDIM))[cg] = o;
    }
}

// ---------------------------------------------------------------------------
// Head GEMM 2: 128 -> 64, relu(bn(.)), 64 rows x 64 cols per block
// ---------------------------------------------------------------------------
__global__ __launch_bounds__(256) void head_gemm2(const float* __restrict__ hin,
                                                  const float* __restrict__ W,
                                                  const float* __restrict__ bias,
                                                  const float* __restrict__ scale,
                                                  const float* __restrict__ shift,
                                                  float* __restrict__ out) {
    __shared__ float sH[64][CDIM + 4];
    int row0 = blockIdx.x * 64;
    int tid = threadIdx.x;

    for (int it = 0; it < 8; ++it) {
        int idx = it * 256 + tid;       // 0..2047
        int r = idx >> 5;
        int c4 = idx & 31;
        int row = row0 + r;
        float4 hv = make_float4(0.f, 0.f, 0.f, 0.f);
        if (row < BATCH) hv = ((const float4*)(hin + (size_t)row * CDIM))[c4];
        *((float4*)&sH[r][c4 * 4]) = hv;
    }
    __syncthreads();

    int cg = tid & 15;       // 16 col groups x 4 = 64 cols
    int rg = tid >> 4;       // 16 row groups x 4 = 64 rows
    int c0 = cg * 4;
    int r0 = rg * 4;

    float acc[4][4];
#pragma unroll
    for (int r = 0; r < 4; ++r)
#pragma unroll
        for (int c = 0; c < 4; ++c) acc[r][c] = 0.0f;

    for (int k = 0; k < CDIM; ++k) {
        float4 w = ((const float4*)(W + (size_t)k * 64))[cg];
#pragma unroll
        for (int r = 0; r < 4; ++r) {
            float hh = sH[r0 + r][k];
            acc[r][0] += hh * w.x;
            acc[r][1] += hh * w.y;
            acc[r][2] += hh * w.z;
            acc[r][3] += hh * w.w;
        }
    }

    float4 bb = *((const float4*)(bias + c0));
    float4 ss = *((const float4*)(scale + c0));
    float4 tt = *((const float4*)(shift + c0));
#pragma unroll
    for (int r = 0; r < 4; ++r) {
        int row = row0 + r0 + r;
        if (row >= BATCH) continue;
        float4 o;
        o.x = fmaxf((acc[r][0] + bb.x) * ss.x + tt.x, 0.0f);
        o.y = fmaxf((acc[r][1] + bb.y) * ss.y + tt.y, 0.0f);
        o.z = fmaxf((acc[r][2] + bb.z) * ss.z + tt.z, 0.0f);
        o.w = fmaxf((acc[r][3] + bb.w) * ss.w + tt.w, 0.0f);
        ((float4*)(out + (size_t)row * 64))[cg] = o;
    }
}

// ---------------------------------------------------------------------------
// Final: out[i] = t2[i,:] @ W3 + b3
// ---------------------------------------------------------------------------
__global__ __launch_bounds__(256) void head_final(const float* __restrict__ t2,
                                                  const float* __restrict__ W3,
                                                  const float* __restrict__ b3,
                                                  float* __restrict__ out) {
    __shared__ float w[64];
    if (threadIdx.x < 64) w[threadIdx.x] = W3[threadIdx.x];
    __syncthreads();
    int i = blockIdx.x * 256 + threadIdx.x;
    if (i >= BATCH) return;
    const float4* r = (const float4*)(t2 + (size_t)i * 64);
    float acc = b3[0];
#pragma unroll
    for (int k = 0; k < 16; ++k) {
        float4 v = r[k];
        acc += v.x * w[4 * k] + v.y * w[4 * k + 1] + v.z * w[4 * k + 2] + v.w * w[4 * k + 3];
    }
    out[i] = acc;
}

// ---------------------------------------------------------------------------
extern "C" void kernel_launch(void* const* d_in, const int* in_sizes, int n_in,
                              void* d_out, int out_size, void* d_ws, size_t ws_size,
                              hipStream_t stream) {
    const float* x    = (const float*)d_in[0];
    const int*   ei   = (const int*)d_in[1];
    const float* Wl   = (const float*)d_in[3];
    const float* bl   = (const float*)d_in[4];
    const float* Wr   = (const float*)d_in[5];
    const float* bn_g = (const float*)d_in[6];
    const float* bn_b = (const float*)d_in[7];
    const float* bn_m = (const float*)d_in[8];
    const float* bn_v = (const float*)d_in[9];
    const float* cW1  = (const float*)d_in[10];
    const float* cb1  = (const float*)d_in[11];
    const float* cg1  = (const float*)d_in[12];
    const float* cbe1 = (const float*)d_in[13];
    const float* cm1  = (const float*)d_in[14];
    const float* cv1  = (const float*)d_in[15];
    const float* cW2  = (const float*)d_in[16];
    const float* cb2  = (const float*)d_in[17];
    const float* cg2  = (const float*)d_in[18];
    const float* cbe2 = (const float*)d_in[19];
    const float* cm2  = (const float*)d_in[20];
    const float* cv2  = (const float*)d_in[21];
    const float* cW3  = (const float*)d_in[22];
    const float* cb3  = (const float*)d_in[23];

    float* ws  = (float*)d_ws;
    float* h   = ws;                        // N*C = 12.8M floats
    float* agg = ws + (size_t)N_NODES * CDIM;      // 12.8M floats
    float* cnt = agg + (size_t)N_NODES * CDIM;     // 100k floats
    float* sc  = cnt + N_NODES;                    // 1152 floats
    float* t1  = agg;                              // reuse agg after last scatter (B*128)
    float* t2  = agg + (size_t)BATCH * CDIM;       // B*64, still inside agg region

    // h <- x
    hipMemcpyAsync(h, x, (size_t)N_NODES * CDIM * sizeof(float),
                   hipMemcpyDeviceToDevice, stream);

    fold_bn_kernel<<<1, 384, 0, stream>>>(bn_g, bn_b, bn_m, bn_v,
                                          cg1, cbe1, cm1, cv1,
                                          cg2, cbe2, cm2, cv2, sc);

    for (int l = 0; l < NLAYERS; ++l) {
        hipMemsetAsync(agg, 0, (size_t)N_NODES * CDIM * sizeof(float), stream);
        hipMemsetAsync(cnt, 0, (size_t)N_NODES * sizeof(float), stream);
        scatter_edges<<<(N_EDGES * 32 + 255) / 256, 256, 0, stream>>>(ei, h, agg, cnt);
        sage_gemm<<<N_NODES / 32, 256, 0, stream>>>(
            agg, cnt, h,
            Wl + (size_t)l * CDIM * CDIM, bl + (size_t)l * CDIM,
            Wr + (size_t)l * CDIM * CDIM,
            sc + l * CDIM, sc + 384 + l * CDIM);
    }

    head_gemm1<<<(BATCH + 31) / 32, 256, 0, stream>>>(h, cW1, cb1, sc + 768, sc + 896, t1);
    head_gemm2<<<(BATCH + 63) / 64, 256, 0, stream>>>(t1, cW2, cb2, sc + 1024, sc + 1088, t2);
    head_final<<<(BATCH + 255) / 256, 256, 0, stream>>>(t2, cW3, cb3, (float*)d_out);
}

// Round 2
// 1256.407 us; speedup vs baseline: 7.0770x; 7.0770x over previous
//
#include <hip/hip_runtime.h>

#define N_NODES 100000
#define N_EDGES 1600000
#define CDIM    128
#define BATCH   50000
#define NLAYERS 3
#define EPS_BN  1e-5f

// ---------------------------------------------------------------------------
// Fold BN params: s = g*rsqrt(v+eps), t = b - m*s
// sc[] layout: [0..383] layer scales, [384..767] layer shifts,
// [768..895] head1 scale, [896..1023] head1 shift,
// [1024..1087] head2 scale, [1088..1151] head2 shift
// ---------------------------------------------------------------------------
__global__ void fold_bn_kernel(const float* __restrict__ g, const float* __restrict__ b,
                               const float* __restrict__ m, const float* __restrict__ v,
                               const float* __restrict__ cg1, const float* __restrict__ cbe1,
                               const float* __restrict__ cm1, const float* __restrict__ cv1,
                               const float* __restrict__ cg2, const float* __restrict__ cbe2,
                               const float* __restrict__ cm2, const float* __restrict__ cv2,
                               float* __restrict__ sc) {
    int i = threadIdx.x;
    if (i < NLAYERS * CDIM) {
        float s = g[i] * rsqrtf(v[i] + EPS_BN);
        sc[i] = s;
        sc[NLAYERS * CDIM + i] = b[i] - m[i] * s;
    }
    if (i < CDIM) {
        float s = cg1[i] * rsqrtf(cv1[i] + EPS_BN);
        sc[768 + i] = s;
        sc[896 + i] = cbe1[i] - cm1[i] * s;
    }
    if (i < 64) {
        float s = cg2[i] * rsqrtf(cv2[i] + EPS_BN);
        sc[1024 + i] = s;
        sc[1088 + i] = cbe2[i] - cm2[i] * s;
    }
}

// ---------------------------------------------------------------------------
// CSR build step 1: in-degree histogram (int atomics on 100k counters)
// ---------------------------------------------------------------------------
__global__ __launch_bounds__(256) void hist_kernel(const int* __restrict__ ei,
                                                   int* __restrict__ deg) {
    int e = blockIdx.x * 256 + threadIdx.x;
    if (e >= N_EDGES) return;
    atomicAdd(&deg[ei[N_EDGES + e]], 1);
}

// ---------------------------------------------------------------------------
// CSR build step 2: exclusive prefix scan of deg[0..N) -> rowptr[0..N]
// Single block, 1024 threads, ~98 elements/thread serial + Hillis-Steele.
// ---------------------------------------------------------------------------
__global__ __launch_bounds__(1024) void scan_kernel(const int* __restrict__ deg,
                                                    int* __restrict__ rowptr) {
    __shared__ int sums[1024];
    int t = threadIdx.x;
    const int CH = (N_NODES + 1023) / 1024;   // 98
    int start = t * CH;
    int end = min(start + CH, N_NODES);
    int s = 0;
    for (int i = start; i < end; ++i) s += deg[i];
    sums[t] = s;
    __syncthreads();
    for (int off = 1; off < 1024; off <<= 1) {
        int v = (t >= off) ? sums[t - off] : 0;
        __syncthreads();
        sums[t] += v;
        __syncthreads();
    }
    int ex = (t == 0) ? 0 : sums[t - 1];
    for (int i = start; i < end; ++i) { rowptr[i] = ex; ex += deg[i]; }
    if (t == 1023) rowptr[N_NODES] = ex;
}

// ---------------------------------------------------------------------------
// CSR build step 3: fill edge list (src ids grouped by dst)
// ---------------------------------------------------------------------------
__global__ __launch_bounds__(256) void fill_kernel(const int* __restrict__ ei,
                                                   const int* __restrict__ rowptr,
                                                   int* __restrict__ cursor,
                                                   int* __restrict__ elist) {
    int e = blockIdx.x * 256 + threadIdx.x;
    if (e >= N_EDGES) return;
    int s = ei[e];
    int d = ei[N_EDGES + e];
    int pos = rowptr[d] + atomicAdd(&cursor[d], 1);
    elist[pos] = s;
}

// ---------------------------------------------------------------------------
// Gather-aggregate: agg[i,:] = (1/max(deg,1)) * sum_{j in N(i)} h[j,:]
// 32 lanes per node (float4 per lane), 8 nodes per 256-thread block.
// ---------------------------------------------------------------------------
__global__ __launch_bounds__(256) void gather_agg(const int* __restrict__ rowptr,
                                                  const int* __restrict__ elist,
                                                  const float* __restrict__ h,
                                                  float* __restrict__ agg) {
    int t = blockIdx.x * 256 + threadIdx.x;
    int node = t >> 5;
    int lane = t & 31;
    if (node >= N_NODES) return;
    int beg = rowptr[node];
    int end = rowptr[node + 1];
    float4 acc = make_float4(0.f, 0.f, 0.f, 0.f);
    int j = beg;
    for (; j + 2 <= end; j += 2) {
        int s0 = elist[j];
        int s1 = elist[j + 1];
        float4 v0 = ((const float4*)(h + (size_t)s0 * CDIM))[lane];
        float4 v1 = ((const float4*)(h + (size_t)s1 * CDIM))[lane];
        acc.x += v0.x + v1.x;
        acc.y += v0.y + v1.y;
        acc.z += v0.z + v1.z;
        acc.w += v0.w + v1.w;
    }
    if (j < end) {
        int s0 = elist[j];
        float4 v0 = ((const float4*)(h + (size_t)s0 * CDIM))[lane];
        acc.x += v0.x; acc.y += v0.y; acc.z += v0.z; acc.w += v0.w;
    }
    float rin = 1.0f / fmaxf((float)(end - beg), 1.0f);
    acc.x *= rin; acc.y *= rin; acc.z *= rin; acc.w *= rin;
    ((float4*)(agg + (size_t)node * CDIM))[lane] = acc;
}

// ---------------------------------------------------------------------------
// Fused SAGE layer (in-place on h):
//   h[i,c] = relu( agg[i,:] @ Wl + bl + h[i,:] @ Wr )[c] * s[c] + t[c]
// Block: 32 rows x 128 cols, 256 threads, 4x4 register tile per thread.
// ---------------------------------------------------------------------------
__global__ __launch_bounds__(256) void sage_gemm(const float* __restrict__ agg,
                                                 float* __restrict__ h,
                                                 const float* __restrict__ Wl,
                                                 const float* __restrict__ bl,
                                                 const float* __restrict__ Wr,
                                                 const float* __restrict__ scale,
                                                 const float* __restrict__ shift) {
    __shared__ float sA[32][CDIM + 4];
    __shared__ float sH[32][CDIM + 4];

    int row0 = blockIdx.x * 32;
    int tid = threadIdx.x;

    for (int it = 0; it < 4; ++it) {
        int idx = it * 256 + tid;       // 0..1023
        int r = idx >> 5;
        int c4 = idx & 31;
        int row = row0 + r;
        float4 a = ((const float4*)(agg + (size_t)row * CDIM))[c4];
        *((float4*)&sA[r][c4 * 4]) = a;
        float4 hv = ((const float4*)(h + (size_t)row * CDIM))[c4];
        *((float4*)&sH[r][c4 * 4]) = hv;
    }
    __syncthreads();

    int cg = tid & 31;
    int rg = tid >> 5;
    int c0 = cg * 4;
    int r0 = rg * 4;

    float acc[4][4];
#pragma unroll
    for (int r = 0; r < 4; ++r)
#pragma unroll
        for (int c = 0; c < 4; ++c) acc[r][c] = 0.0f;

    for (int k = 0; k < CDIM; ++k) {
        float4 wl = ((const float4*)(Wl + (size_t)k * CDIM))[cg];
        float4 wr = ((const float4*)(Wr + (size_t)k * CDIM))[cg];
#pragma unroll
        for (int r = 0; r < 4; ++r) {
            float a = sA[r0 + r][k];
            float hh = sH[r0 + r][k];
            acc[r][0] += a * wl.x + hh * wr.x;
            acc[r][1] += a * wl.y + hh * wr.y;
            acc[r][2] += a * wl.z + hh * wr.z;
            acc[r][3] += a * wl.w + hh * wr.w;
        }
    }

    float4 bb = *((const float4*)(bl + c0));
    float4 ss = *((const float4*)(scale + c0));
    float4 tt = *((const float4*)(shift + c0));
#pragma unroll
    for (int r = 0; r < 4; ++r) {
        float4 o;
        o.x = fmaxf(acc[r][0] + bb.x, 0.0f) * ss.x + tt.x;
        o.y = fmaxf(acc[r][1] + bb.y, 0.0f) * ss.y + tt.y;
        o.z = fmaxf(acc[r][2] + bb.z, 0.0f) * ss.z + tt.z;
        o.w = fmaxf(acc[r][3] + bb.w, 0.0f) * ss.w + tt.w;
        ((float4*)(h + (size_t)(row0 + r0 + r) * CDIM))[cg] = o;
    }
}

// ---------------------------------------------------------------------------
// Head GEMM 1: out[i,c] = relu( bn(hin[i,:] @ W + bias) ), 128->128
// ---------------------------------------------------------------------------
__global__ __launch_bounds__(256) void head_gemm1(const float* __restrict__ hin,
                                                  const float* __restrict__ W,
                                                  const float* __restrict__ bias,
                                                  const float* __restrict__ scale,
                                                  const float* __restrict__ shift,
                                                  float* __restrict__ out) {
    __shared__ float sH[32][CDIM + 4];
    int row0 = blockIdx.x * 32;
    int tid = threadIdx.x;

    for (int it = 0; it < 4; ++it) {
        int idx = it * 256 + tid;
        int r = idx >> 5;
        int c4 = idx & 31;
        int row = row0 + r;
        float4 hv = make_float4(0.f, 0.f, 0.f, 0.f);
        if (row < BATCH) hv = ((const float4*)(hin + (size_t)row * CDIM))[c4];
        *((float4*)&sH[r][c4 * 4]) = hv;
    }
    __syncthreads();

    int cg = tid & 31;
    int rg = tid >> 5;
    int c0 = cg * 4;
    int r0 = rg * 4;

    float acc[4][4];
#pragma unroll
    for (int r = 0; r < 4; ++r)
#pragma unroll
        for (int c = 0; c < 4; ++c) acc[r][c] = 0.0f;

    for (int k = 0; k < CDIM; ++k) {
        float4 w = ((const float4*)(W + (size_t)k * CDIM))[cg];
#pragma unroll
        for (int r = 0; r < 4; ++r) {
            float hh = sH[r0 + r][k];
            acc[r][0] += hh * w.x;
            acc[r][1] += hh * w.y;
            acc[r][2] += hh * w.z;
            acc[r][3] += hh * w.w;
        }
    }

    float4 bb = *((const float4*)(bias + c0));
    float4 ss = *((const float4*)(scale + c0));
    float4 tt = *((const float4*)(shift + c0));
#pragma unroll
    for (int r = 0; r < 4; ++r) {
        int row = row0 + r0 + r;
        if (row >= BATCH) continue;
        float4 o;
        o.x = fmaxf((acc[r][0] + bb.x) * ss.x + tt.x, 0.0f);
        o.y = fmaxf((acc[r][1] + bb.y) * ss.y + tt.y, 0.0f);
        o.z = fmaxf((acc[r][2] + bb.z) * ss.z + tt.z, 0.0f);
        o.w = fmaxf((acc[r][3] + bb.w) * ss.w + tt.w, 0.0f);
        ((float4*)(out + (size_t)row * CDIM))[cg] = o;
    }
}

// ---------------------------------------------------------------------------
// Head GEMM 2: 128 -> 64, relu(bn(.)), 64 rows x 64 cols per block
// ---------------------------------------------------------------------------
__global__ __launch_bounds__(256) void head_gemm2(const float* __restrict__ hin,
                                                  const float* __restrict__ W,
                                                  const float* __restrict__ bias,
                                                  const float* __restrict__ scale,
                                                  const float* __restrict__ shift,
                                                  float* __restrict__ out) {
    __shared__ float sH[64][CDIM + 4];
    int row0 = blockIdx.x * 64;
    int tid = threadIdx.x;

    for (int it = 0; it < 8; ++it) {
        int idx = it * 256 + tid;       // 0..2047
        int r = idx >> 5;
        int c4 = idx & 31;
        int row = row0 + r;
        float4 hv = make_float4(0.f, 0.f, 0.f, 0.f);
        if (row < BATCH) hv = ((const float4*)(hin + (size_t)row * CDIM))[c4];
        *((float4*)&sH[r][c4 * 4]) = hv;
    }
    __syncthreads();

    int cg = tid & 15;
    int rg = tid >> 4;
    int c0 = cg * 4;
    int r0 = rg * 4;

    float acc[4][4];
#pragma unroll
    for (int r = 0; r < 4; ++r)
#pragma unroll
        for (int c = 0; c < 4; ++c) acc[r][c] = 0.0f;

    for (int k = 0; k < CDIM; ++k) {
        float4 w = ((const float4*)(W + (size_t)k * 64))[cg];
#pragma unroll
        for (int r = 0; r < 4; ++r) {
            float hh = sH[r0 + r][k];
            acc[r][0] += hh * w.x;
            acc[r][1] += hh * w.y;
            acc[r][2] += hh * w.z;
            acc[r][3] += hh * w.w;
        }
    }

    float4 bb = *((const float4*)(bias + c0));
    float4 ss = *((const float4*)(scale + c0));
    float4 tt = *((const float4*)(shift + c0));
#pragma unroll
    for (int r = 0; r < 4; ++r) {
        int row = row0 + r0 + r;
        if (row >= BATCH) continue;
        float4 o;
        o.x = fmaxf((acc[r][0] + bb.x) * ss.x + tt.x, 0.0f);
        o.y = fmaxf((acc[r][1] + bb.y) * ss.y + tt.y, 0.0f);
        o.z = fmaxf((acc[r][2] + bb.z) * ss.z + tt.z, 0.0f);
        o.w = fmaxf((acc[r][3] + bb.w) * ss.w + tt.w, 0.0f);
        ((float4*)(out + (size_t)row * 64))[cg] = o;
    }
}

// ---------------------------------------------------------------------------
// Final: out[i] = t2[i,:] @ W3 + b3
// ---------------------------------------------------------------------------
__global__ __launch_bounds__(256) void head_final(const float* __restrict__ t2,
                                                  const float* __restrict__ W3,
                                                  const float* __restrict__ b3,
                                                  float* __restrict__ out) {
    __shared__ float w[64];
    if (threadIdx.x < 64) w[threadIdx.x] = W3[threadIdx.x];
    __syncthreads();
    int i = blockIdx.x * 256 + threadIdx.x;
    if (i >= BATCH) return;
    const float4* r = (const float4*)(t2 + (size_t)i * 64);
    float acc = b3[0];
#pragma unroll
    for (int k = 0; k < 16; ++k) {
        float4 v = r[k];
        acc += v.x * w[4 * k] + v.y * w[4 * k + 1] + v.z * w[4 * k + 2] + v.w * w[4 * k + 3];
    }
    out[i] = acc;
}

// ---------------------------------------------------------------------------
extern "C" void kernel_launch(void* const* d_in, const int* in_sizes, int n_in,
                              void* d_out, int out_size, void* d_ws, size_t ws_size,
                              hipStream_t stream) {
    const float* x    = (const float*)d_in[0];
    const int*   ei   = (const int*)d_in[1];
    const float* Wl   = (const float*)d_in[3];
    const float* bl   = (const float*)d_in[4];
    const float* Wr   = (const float*)d_in[5];
    const float* bn_g = (const float*)d_in[6];
    const float* bn_b = (const float*)d_in[7];
    const float* bn_m = (const float*)d_in[8];
    const float* bn_v = (const float*)d_in[9];
    const float* cW1  = (const float*)d_in[10];
    const float* cb1  = (const float*)d_in[11];
    const float* cg1  = (const float*)d_in[12];
    const float* cbe1 = (const float*)d_in[13];
    const float* cm1  = (const float*)d_in[14];
    const float* cv1  = (const float*)d_in[15];
    const float* cW2  = (const float*)d_in[16];
    const float* cb2  = (const float*)d_in[17];
    const float* cg2  = (const float*)d_in[18];
    const float* cbe2 = (const float*)d_in[19];
    const float* cm2  = (const float*)d_in[20];
    const float* cv2  = (const float*)d_in[21];
    const float* cW3  = (const float*)d_in[22];
    const float* cb3  = (const float*)d_in[23];

    // Workspace layout (floats/ints, 4 B each):
    float* ws  = (float*)d_ws;
    float* h   = ws;                                   // N*C floats
    float* agg = h + (size_t)N_NODES * CDIM;           // N*C floats
    float* sc  = agg + (size_t)N_NODES * CDIM;         // 1152 floats
    int* rowptr = (int*)(sc + 1152);                   // N+1 ints
    int* ideg   = rowptr + (N_NODES + 1);              // N ints (deg, then cursors)
    int* elist  = ideg + N_NODES;                      // E ints
    float* t1  = agg;                                  // head temps reuse agg
    float* t2  = agg + (size_t)BATCH * CDIM;

    // h <- x
    hipMemcpyAsync(h, x, (size_t)N_NODES * CDIM * sizeof(float),
                   hipMemcpyDeviceToDevice, stream);

    fold_bn_kernel<<<1, 384, 0, stream>>>(bn_g, bn_b, bn_m, bn_v,
                                          cg1, cbe1, cm1, cv1,
                                          cg2, cbe2, cm2, cv2, sc);

    // ---- build CSR once (edges constant across layers) ----
    hipMemsetAsync(ideg, 0, N_NODES * sizeof(int), stream);
    hist_kernel<<<(N_EDGES + 255) / 256, 256, 0, stream>>>(ei, ideg);
    scan_kernel<<<1, 1024, 0, stream>>>(ideg, rowptr);
    hipMemsetAsync(ideg, 0, N_NODES * sizeof(int), stream);
    fill_kernel<<<(N_EDGES + 255) / 256, 256, 0, stream>>>(ei, rowptr, ideg, elist);

    // ---- 3 SAGE layers ----
    for (int l = 0; l < NLAYERS; ++l) {
        gather_agg<<<(N_NODES * 32 + 255) / 256, 256, 0, stream>>>(rowptr, elist, h, agg);
        sage_gemm<<<N_NODES / 32, 256, 0, stream>>>(
            agg, h,
            Wl + (size_t)l * CDIM * CDIM, bl + (size_t)l * CDIM,
            Wr + (size_t)l * CDIM * CDIM,
            sc + l * CDIM, sc + 384 + l * CDIM);
    }

    // ---- MLP head on first BATCH rows ----
    head_gemm1<<<(BATCH + 31) / 32, 256, 0, stream>>>(h, cW1, cb1, sc + 768, sc + 896, t1);
    head_gemm2<<<(BATCH + 63) / 64, 256, 0, stream>>>(t1, cW2, cb2, sc + 1024, sc + 1088, t2);
    head_final<<<(BATCH + 255) / 256, 256, 0, stream>>>(t2, cW3, cb3, (float*)d_out);
}

// Round 3
// 1018.617 us; speedup vs baseline: 8.7291x; 1.2334x over previous
//
#include <hip/hip_runtime.h>

#define N_NODES 100000
#define N_EDGES 1600000
#define CDIM    128
#define BATCH   50000
#define NLAYERS 3
#define EPS_BN  1e-5f
#define SBLK    1024   // elements per scan block
#define NSB     ((N_NODES + SBLK - 1) / SBLK)   // 98

// ---------------------------------------------------------------------------
// Fold BN params: s = g*rsqrt(v+eps), t = b - m*s
// sc[] layout: [0..383] layer scales, [384..767] layer shifts,
// [768..895] head1 scale, [896..1023] head1 shift,
// [1024..1087] head2 scale, [1088..1151] head2 shift
// ---------------------------------------------------------------------------
__global__ void fold_bn_kernel(const float* __restrict__ g, const float* __restrict__ b,
                               const float* __restrict__ m, const float* __restrict__ v,
                               const float* __restrict__ cg1, const float* __restrict__ cbe1,
                               const float* __restrict__ cm1, const float* __restrict__ cv1,
                               const float* __restrict__ cg2, const float* __restrict__ cbe2,
                               const float* __restrict__ cm2, const float* __restrict__ cv2,
                               float* __restrict__ sc) {
    int i = threadIdx.x;
    if (i < NLAYERS * CDIM) {
        float s = g[i] * rsqrtf(v[i] + EPS_BN);
        sc[i] = s;
        sc[NLAYERS * CDIM + i] = b[i] - m[i] * s;
    }
    if (i < CDIM) {
        float s = cg1[i] * rsqrtf(cv1[i] + EPS_BN);
        sc[768 + i] = s;
        sc[896 + i] = cbe1[i] - cm1[i] * s;
    }
    if (i < 64) {
        float s = cg2[i] * rsqrtf(cv2[i] + EPS_BN);
        sc[1024 + i] = s;
        sc[1088 + i] = cbe2[i] - cm2[i] * s;
    }
}

// ---------------------------------------------------------------------------
// CSR step 1: in-degree histogram
// ---------------------------------------------------------------------------
__global__ __launch_bounds__(256) void hist_kernel(const int* __restrict__ ei,
                                                   int* __restrict__ deg) {
    int e = blockIdx.x * 256 + threadIdx.x;
    if (e >= N_EDGES) return;
    atomicAdd(&deg[ei[N_EDGES + e]], 1);
}

// ---------------------------------------------------------------------------
// CSR step 2a: per-block exclusive scan (1024 elems/block, 256 thr x 4)
// writes within-block exclusive prefix to rowptr, block total to bsum
// ---------------------------------------------------------------------------
__global__ __launch_bounds__(256) void scan_blocks(const int* __restrict__ deg,
                                                   int* __restrict__ rowptr,
                                                   int* __restrict__ bsum) {
    __shared__ int lsum[256];
    int b = blockIdx.x, t = threadIdx.x;
    int base = b * SBLK + t * 4;
    int v[4];
#pragma unroll
    for (int k = 0; k < 4; ++k) {
        int i = base + k;
        v[k] = (i < N_NODES) ? deg[i] : 0;
    }
    int s = v[0] + v[1] + v[2] + v[3];
    lsum[t] = s;
    __syncthreads();
    for (int off = 1; off < 256; off <<= 1) {
        int x = (t >= off) ? lsum[t - off] : 0;
        __syncthreads();
        lsum[t] += x;
        __syncthreads();
    }
    int ex = (t == 0) ? 0 : lsum[t - 1];
#pragma unroll
    for (int k = 0; k < 4; ++k) {
        int i = base + k;
        if (i < N_NODES) rowptr[i] = ex;
        ex += v[k];
    }
    if (t == 255) bsum[b] = lsum[255];
}

// ---------------------------------------------------------------------------
// CSR step 2b: single-block scan of NSB block sums -> exclusive boff
// ---------------------------------------------------------------------------
__global__ __launch_bounds__(128) void scan_bsums(const int* __restrict__ bsum,
                                                  int* __restrict__ boff,
                                                  int* __restrict__ rowptr) {
    __shared__ int s[128];
    int t = threadIdx.x;
    int v = (t < NSB) ? bsum[t] : 0;
    s[t] = v;
    __syncthreads();
    for (int off = 1; off < 128; off <<= 1) {
        int x = (t >= off) ? s[t - off] : 0;
        __syncthreads();
        s[t] += x;
        __syncthreads();
    }
    if (t < NSB) boff[t] = (t == 0) ? 0 : s[t - 1];
    if (t == 127) rowptr[N_NODES] = N_EDGES;   // total is constant
}

// ---------------------------------------------------------------------------
// CSR step 2c: add block offsets
// ---------------------------------------------------------------------------
__global__ __launch_bounds__(256) void scan_add(int* __restrict__ rowptr,
                                                const int* __restrict__ boff) {
    int off = boff[blockIdx.x];
    int base = blockIdx.x * SBLK + threadIdx.x * 4;
#pragma unroll
    for (int k = 0; k < 4; ++k) {
        int i = base + k;
        if (i < N_NODES) rowptr[i] += off;
    }
}

// ---------------------------------------------------------------------------
// CSR step 3: fill edge list (src ids grouped by dst)
// ---------------------------------------------------------------------------
__global__ __launch_bounds__(256) void fill_kernel(const int* __restrict__ ei,
                                                   const int* __restrict__ rowptr,
                                                   int* __restrict__ cursor,
                                                   int* __restrict__ elist) {
    int e = blockIdx.x * 256 + threadIdx.x;
    if (e >= N_EDGES) return;
    int s = ei[e];
    int d = ei[N_EDGES + e];
    int pos = rowptr[d] + atomicAdd(&cursor[d], 1);
    elist[pos] = s;
}

// ---------------------------------------------------------------------------
// Fused SAGE layer: gather-aggregate 32 rows into LDS, then
//   hout[i,c] = relu( mean_agg[i,:] @ Wl + bl + hin[i,:] @ Wr )[c]*s[c] + t[c]
// Block: 32 rows x 128 cols, 256 threads, 4x4 register tile per thread.
// hin/hout are separate buffers (ping-pong): fusion means other blocks read
// hin rows while we write hout — no in-place.
// ---------------------------------------------------------------------------
__global__ __launch_bounds__(256) void sage_fused(const int* __restrict__ rowptr,
                                                  const int* __restrict__ elist,
                                                  const float* __restrict__ hin,
                                                  float* __restrict__ hout,
                                                  const float* __restrict__ Wl,
                                                  const float* __restrict__ bl,
                                                  const float* __restrict__ Wr,
                                                  const float* __restrict__ scale,
                                                  const float* __restrict__ shift) {
    __shared__ float sA[32][CDIM + 4];
    __shared__ float sH[32][CDIM + 4];

    int row0 = blockIdx.x * 32;
    int tid = threadIdx.x;
    int lane = tid & 31;      // channel group: floats lane*4..lane*4+3
    int grp = tid >> 5;       // 8 node-groups

    // ---- gather phase: 4 rounds x 8 nodes ----
    for (int rr = 0; rr < 4; ++rr) {
        int r = rr * 8 + grp;
        int node = row0 + r;
        int beg = rowptr[node];
        int end = rowptr[node + 1];
        float4 acc = make_float4(0.f, 0.f, 0.f, 0.f);
        int j = beg;
        for (; j + 4 <= end; j += 4) {
            int s0 = elist[j], s1 = elist[j + 1], s2 = elist[j + 2], s3 = elist[j + 3];
            float4 v0 = ((const float4*)(hin + (size_t)s0 * CDIM))[lane];
            float4 v1 = ((const float4*)(hin + (size_t)s1 * CDIM))[lane];
            float4 v2 = ((const float4*)(hin + (size_t)s2 * CDIM))[lane];
            float4 v3 = ((const float4*)(hin + (size_t)s3 * CDIM))[lane];
            acc.x += (v0.x + v1.x) + (v2.x + v3.x);
            acc.y += (v0.y + v1.y) + (v2.y + v3.y);
            acc.z += (v0.z + v1.z) + (v2.z + v3.z);
            acc.w += (v0.w + v1.w) + (v2.w + v3.w);
        }
        for (; j < end; ++j) {
            int s0 = elist[j];
            float4 v0 = ((const float4*)(hin + (size_t)s0 * CDIM))[lane];
            acc.x += v0.x; acc.y += v0.y; acc.z += v0.z; acc.w += v0.w;
        }
        float rin = 1.0f / fmaxf((float)(end - beg), 1.0f);
        acc.x *= rin; acc.y *= rin; acc.z *= rin; acc.w *= rin;
        *((float4*)&sA[r][lane * 4]) = acc;
    }

    // ---- stage own rows of hin ----
    for (int it = 0; it < 4; ++it) {
        int idx = it * 256 + tid;     // 0..1023
        int r = idx >> 5;
        int c4 = idx & 31;
        float4 hv = ((const float4*)(hin + (size_t)(row0 + r) * CDIM))[c4];
        *((float4*)&sH[r][c4 * 4]) = hv;
    }
    __syncthreads();

    // ---- GEMM phase ----
    int cg = tid & 31;
    int rg = tid >> 5;
    int c0 = cg * 4;
    int r0 = rg * 4;

    float acc[4][4];
#pragma unroll
    for (int r = 0; r < 4; ++r)
#pragma unroll
        for (int c = 0; c < 4; ++c) acc[r][c] = 0.0f;

    for (int k = 0; k < CDIM; ++k) {
        float4 wl = ((const float4*)(Wl + (size_t)k * CDIM))[cg];
        float4 wr = ((const float4*)(Wr + (size_t)k * CDIM))[cg];
#pragma unroll
        for (int r = 0; r < 4; ++r) {
            float a = sA[r0 + r][k];
            float hh = sH[r0 + r][k];
            acc[r][0] += a * wl.x + hh * wr.x;
            acc[r][1] += a * wl.y + hh * wr.y;
            acc[r][2] += a * wl.z + hh * wr.z;
            acc[r][3] += a * wl.w + hh * wr.w;
        }
    }

    float4 bb = *((const float4*)(bl + c0));
    float4 ss = *((const float4*)(scale + c0));
    float4 tt = *((const float4*)(shift + c0));
#pragma unroll
    for (int r = 0; r < 4; ++r) {
        float4 o;
        o.x = fmaxf(acc[r][0] + bb.x, 0.0f) * ss.x + tt.x;
        o.y = fmaxf(acc[r][1] + bb.y, 0.0f) * ss.y + tt.y;
        o.z = fmaxf(acc[r][2] + bb.z, 0.0f) * ss.z + tt.z;
        o.w = fmaxf(acc[r][3] + bb.w, 0.0f) * ss.w + tt.w;
        ((float4*)(hout + (size_t)(row0 + r0 + r) * CDIM))[cg] = o;
    }
}

// ---------------------------------------------------------------------------
// Head GEMM 1: out[i,c] = relu( bn(hin[i,:] @ W + bias) ), 128->128
// ---------------------------------------------------------------------------
__global__ __launch_bounds__(256) void head_gemm1(const float* __restrict__ hin,
                                                  const float* __restrict__ W,
                                                  const float* __restrict__ bias,
                                                  const float* __restrict__ scale,
                                                  const float* __restrict__ shift,
                                                  float* __restrict__ out) {
    __shared__ float sH[32][CDIM + 4];
    int row0 = blockIdx.x * 32;
    int tid = threadIdx.x;

    for (int it = 0; it < 4; ++it) {
        int idx = it * 256 + tid;
        int r = idx >> 5;
        int c4 = idx & 31;
        int row = row0 + r;
        float4 hv = make_float4(0.f, 0.f, 0.f, 0.f);
        if (row < BATCH) hv = ((const float4*)(hin + (size_t)row * CDIM))[c4];
        *((float4*)&sH[r][c4 * 4]) = hv;
    }
    __syncthreads();

    int cg = tid & 31;
    int rg = tid >> 5;
    int c0 = cg * 4;
    int r0 = rg * 4;

    float acc[4][4];
#pragma unroll
    for (int r = 0; r < 4; ++r)
#pragma unroll
        for (int c = 0; c < 4; ++c) acc[r][c] = 0.0f;

    for (int k = 0; k < CDIM; ++k) {
        float4 w = ((const float4*)(W + (size_t)k * CDIM))[cg];
#pragma unroll
        for (int r = 0; r < 4; ++r) {
            float hh = sH[r0 + r][k];
            acc[r][0] += hh * w.x;
            acc[r][1] += hh * w.y;
            acc[r][2] += hh * w.z;
            acc[r][3] += hh * w.w;
        }
    }

    float4 bb = *((const float4*)(bias + c0));
    float4 ss = *((const float4*)(scale + c0));
    float4 tt = *((const float4*)(shift + c0));
#pragma unroll
    for (int r = 0; r < 4; ++r) {
        int row = row0 + r0 + r;
        if (row >= BATCH) continue;
        float4 o;
        o.x = fmaxf((acc[r][0] + bb.x) * ss.x + tt.x, 0.0f);
        o.y = fmaxf((acc[r][1] + bb.y) * ss.y + tt.y, 0.0f);
        o.z = fmaxf((acc[r][2] + bb.z) * ss.z + tt.z, 0.0f);
        o.w = fmaxf((acc[r][3] + bb.w) * ss.w + tt.w, 0.0f);
        ((float4*)(out + (size_t)row * CDIM))[cg] = o;
    }
}

// ---------------------------------------------------------------------------
// Head GEMM 2: 128 -> 64, relu(bn(.)), 64 rows x 64 cols per block
// ---------------------------------------------------------------------------
__global__ __launch_bounds__(256) void head_gemm2(const float* __restrict__ hin,
                                                  const float* __restrict__ W,
                                                  const float* __restrict__ bias,
                                                  const float* __restrict__ scale,
                                                  const float* __restrict__ shift,
                                                  float* __restrict__ out) {
    __shared__ float sH[64][CDIM + 4];
    int row0 = blockIdx.x * 64;
    int tid = threadIdx.x;

    for (int it = 0; it < 8; ++it) {
        int idx = it * 256 + tid;
        int r = idx >> 5;
        int c4 = idx & 31;
        int row = row0 + r;
        float4 hv = make_float4(0.f, 0.f, 0.f, 0.f);
        if (row < BATCH) hv = ((const float4*)(hin + (size_t)row * CDIM))[c4];
        *((float4*)&sH[r][c4 * 4]) = hv;
    }
    __syncthreads();

    int cg = tid & 15;
    int rg = tid >> 4;
    int c0 = cg * 4;
    int r0 = rg * 4;

    float acc[4][4];
#pragma unroll
    for (int r = 0; r < 4; ++r)
#pragma unroll
        for (int c = 0; c < 4; ++c) acc[r][c] = 0.0f;

    for (int k = 0; k < CDIM; ++k) {
        float4 w = ((const float4*)(W + (size_t)k * 64))[cg];
#pragma unroll
        for (int r = 0; r < 4; ++r) {
            float hh = sH[r0 + r][k];
            acc[r][0] += hh * w.x;
            acc[r][1] += hh * w.y;
            acc[r][2] += hh * w.z;
            acc[r][3] += hh * w.w;
        }
    }

    float4 bb = *((const float4*)(bias + c0));
    float4 ss = *((const float4*)(scale + c0));
    float4 tt = *((const float4*)(shift + c0));
#pragma unroll
    for (int r = 0; r < 4; ++r) {
        int row = row0 + r0 + r;
        if (row >= BATCH) continue;
        float4 o;
        o.x = fmaxf((acc[r][0] + bb.x) * ss.x + tt.x, 0.0f);
        o.y = fmaxf((acc[r][1] + bb.y) * ss.y + tt.y, 0.0f);
        o.z = fmaxf((acc[r][2] + bb.z) * ss.z + tt.z, 0.0f);
        o.w = fmaxf((acc[r][3] + bb.w) * ss.w + tt.w, 0.0f);
        ((float4*)(out + (size_t)row * 64))[cg] = o;
    }
}

// ---------------------------------------------------------------------------
// Final: out[i] = t2[i,:] @ W3 + b3
// ---------------------------------------------------------------------------
__global__ __launch_bounds__(256) void head_final(const float* __restrict__ t2,
                                                  const float* __restrict__ W3,
                                                  const float* __restrict__ b3,
                                                  float* __restrict__ out) {
    __shared__ float w[64];
    if (threadIdx.x < 64) w[threadIdx.x] = W3[threadIdx.x];
    __syncthreads();
    int i = blockIdx.x * 256 + threadIdx.x;
    if (i >= BATCH) return;
    const float4* r = (const float4*)(t2 + (size_t)i * 64);
    float acc = b3[0];
#pragma unroll
    for (int k = 0; k < 16; ++k) {
        float4 v = r[k];
        acc += v.x * w[4 * k] + v.y * w[4 * k + 1] + v.z * w[4 * k + 2] + v.w * w[4 * k + 3];
    }
    out[i] = acc;
}

// ---------------------------------------------------------------------------
extern "C" void kernel_launch(void* const* d_in, const int* in_sizes, int n_in,
                              void* d_out, int out_size, void* d_ws, size_t ws_size,
                              hipStream_t stream) {
    const float* x    = (const float*)d_in[0];
    const int*   ei   = (const int*)d_in[1];
    const float* Wl   = (const float*)d_in[3];
    const float* bl   = (const float*)d_in[4];
    const float* Wr   = (const float*)d_in[5];
    const float* bn_g = (const float*)d_in[6];
    const float* bn_b = (const float*)d_in[7];
    const float* bn_m = (const float*)d_in[8];
    const float* bn_v = (const float*)d_in[9];
    const float* cW1  = (const float*)d_in[10];
    const float* cb1  = (const float*)d_in[11];
    const float* cg1  = (const float*)d_in[12];
    const float* cbe1 = (const float*)d_in[13];
    const float* cm1  = (const float*)d_in[14];
    const float* cv1  = (const float*)d_in[15];
    const float* cW2  = (const float*)d_in[16];
    const float* cb2  = (const float*)d_in[17];
    const float* cg2  = (const float*)d_in[18];
    const float* cbe2 = (const float*)d_in[19];
    const float* cm2  = (const float*)d_in[20];
    const float* cv2  = (const float*)d_in[21];
    const float* cW3  = (const float*)d_in[22];
    const float* cb3  = (const float*)d_in[23];

    // Workspace layout:
    float* ws  = (float*)d_ws;
    float* b0  = ws;                                   // N*C floats (ping)
    float* b1  = b0 + (size_t)N_NODES * CDIM;          // N*C floats (pong)
    float* sc  = b1 + (size_t)N_NODES * CDIM;          // 1152 floats
    int* rowptr = (int*)(sc + 1152);                   // N+1 ints
    int* ideg   = rowptr + (N_NODES + 1);              // N ints (deg/cursor)
    int* bsum   = ideg + N_NODES;                      // 128 ints
    int* boff   = bsum + 128;                          // 128 ints
    int* elist  = boff + 128;                          // E ints
    float* t1 = b1;                                    // head temps reuse pong
    float* t2 = b1 + (size_t)BATCH * CDIM;

    fold_bn_kernel<<<1, 384, 0, stream>>>(bn_g, bn_b, bn_m, bn_v,
                                          cg1, cbe1, cm1, cv1,
                                          cg2, cbe2, cm2, cv2, sc);

    // ---- build CSR once ----
    hipMemsetAsync(ideg, 0, N_NODES * sizeof(int), stream);
    hist_kernel<<<(N_EDGES + 255) / 256, 256, 0, stream>>>(ei, ideg);
    scan_blocks<<<NSB, 256, 0, stream>>>(ideg, rowptr, bsum);
    scan_bsums<<<1, 128, 0, stream>>>(bsum, boff, rowptr);
    scan_add<<<NSB, 256, 0, stream>>>(rowptr, boff);
    hipMemsetAsync(ideg, 0, N_NODES * sizeof(int), stream);
    fill_kernel<<<(N_EDGES + 255) / 256, 256, 0, stream>>>(ei, rowptr, ideg, elist);

    // ---- 3 fused SAGE layers (ping-pong: x->b0->b1->b0) ----
    const float* lin[NLAYERS] = { x, b0, b1 };
    float* lout[NLAYERS]      = { b0, b1, b0 };
    for (int l = 0; l < NLAYERS; ++l) {
        sage_fused<<<N_NODES / 32, 256, 0, stream>>>(
            rowptr, elist, lin[l], lout[l],
            Wl + (size_t)l * CDIM * CDIM, bl + (size_t)l * CDIM,
            Wr + (size_t)l * CDIM * CDIM,
            sc + l * CDIM, sc + 384 + l * CDIM);
    }

    // ---- MLP head on first BATCH rows (input: b0) ----
    head_gemm1<<<(BATCH + 31) / 32, 256, 0, stream>>>(b0, cW1, cb1, sc + 768, sc + 896, t1);
    head_gemm2<<<(BATCH + 63) / 64, 256, 0, stream>>>(t1, cW2, cb2, sc + 1024, sc + 1088, t2);
    head_final<<<(BATCH + 255) / 256, 256, 0, stream>>>(t2, cW3, cb3, (float*)d_out);
}

// Round 4
// 936.874 us; speedup vs baseline: 9.4907x; 1.0873x over previous
//
#include <hip/hip_runtime.h>

#define N_NODES 100000
#define N_EDGES 1600000
#define CDIM    128
#define BATCH   50000
#define NLAYERS 3
#define EPS_BN  1e-5f
#define SBLK    1024
#define NSB     ((N_NODES + SBLK - 1) / SBLK)   // 98

// bf16 helpers: storage is ushort (bf16 bit pattern)
__device__ __forceinline__ float bf2f(unsigned short u) {
    unsigned int x = ((unsigned int)u) << 16;
    return __uint_as_float(x);
}
__device__ __forceinline__ unsigned short f2bf(float f) {
    unsigned int u = __float_as_uint(f);
    u = u + 0x7FFFu + ((u >> 16) & 1u);   // RTNE
    return (unsigned short)(u >> 16);
}
// unpack uint (2 bf16, little-endian: low ushort = first elem) -> 2 floats
__device__ __forceinline__ void unpk(unsigned int u, float& lo, float& hi) {
    lo = __uint_as_float(u << 16);
    hi = __uint_as_float(u & 0xFFFF0000u);
}

// ---------------------------------------------------------------------------
// Fold BN params: s = g*rsqrt(v+eps), t = b - m*s
// sc[]: [0..383] layer scales, [384..767] layer shifts,
// [768..895]/[896..1023] head1 s/t, [1024..1087]/[1088..1151] head2 s/t
// ---------------------------------------------------------------------------
__global__ void fold_bn_kernel(const float* __restrict__ g, const float* __restrict__ b,
                               const float* __restrict__ m, const float* __restrict__ v,
                               const float* __restrict__ cg1, const float* __restrict__ cbe1,
                               const float* __restrict__ cm1, const float* __restrict__ cv1,
                               const float* __restrict__ cg2, const float* __restrict__ cbe2,
                               const float* __restrict__ cm2, const float* __restrict__ cv2,
                               float* __restrict__ sc) {
    int i = threadIdx.x;
    if (i < NLAYERS * CDIM) {
        float s = g[i] * rsqrtf(v[i] + EPS_BN);
        sc[i] = s;
        sc[NLAYERS * CDIM + i] = b[i] - m[i] * s;
    }
    if (i < CDIM) {
        float s = cg1[i] * rsqrtf(cv1[i] + EPS_BN);
        sc[768 + i] = s;
        sc[896 + i] = cbe1[i] - cm1[i] * s;
    }
    if (i < 64) {
        float s = cg2[i] * rsqrtf(cv2[i] + EPS_BN);
        sc[1024 + i] = s;
        sc[1088 + i] = cbe2[i] - cm2[i] * s;
    }
}

// ---------------------------------------------------------------------------
// Convert x (fp32) -> xb (bf16)
// ---------------------------------------------------------------------------
__global__ __launch_bounds__(256) void convert_x(const float* __restrict__ x,
                                                 unsigned short* __restrict__ xb) {
    int i = blockIdx.x * 256 + threadIdx.x;          // one float4 per thread
    const int TOT = N_NODES * CDIM / 4;
    if (i >= TOT) return;
    float4 v = ((const float4*)x)[i];
    ushort4 o;
    o.x = f2bf(v.x); o.y = f2bf(v.y); o.z = f2bf(v.z); o.w = f2bf(v.w);
    ((ushort4*)xb)[i] = o;
}

// ---------------------------------------------------------------------------
// CSR build
// ---------------------------------------------------------------------------
__global__ __launch_bounds__(256) void hist_kernel(const int* __restrict__ ei,
                                                   int* __restrict__ deg) {
    int e = blockIdx.x * 256 + threadIdx.x;
    if (e >= N_EDGES) return;
    atomicAdd(&deg[ei[N_EDGES + e]], 1);
}

__global__ __launch_bounds__(256) void scan_blocks(const int* __restrict__ deg,
                                                   int* __restrict__ rowptr,
                                                   int* __restrict__ bsum) {
    __shared__ int lsum[256];
    int b = blockIdx.x, t = threadIdx.x;
    int base = b * SBLK + t * 4;
    int v[4];
#pragma unroll
    for (int k = 0; k < 4; ++k) {
        int i = base + k;
        v[k] = (i < N_NODES) ? deg[i] : 0;
    }
    int s = v[0] + v[1] + v[2] + v[3];
    lsum[t] = s;
    __syncthreads();
    for (int off = 1; off < 256; off <<= 1) {
        int x = (t >= off) ? lsum[t - off] : 0;
        __syncthreads();
        lsum[t] += x;
        __syncthreads();
    }
    int ex = (t == 0) ? 0 : lsum[t - 1];
#pragma unroll
    for (int k = 0; k < 4; ++k) {
        int i = base + k;
        if (i < N_NODES) rowptr[i] = ex;
        ex += v[k];
    }
    if (t == 255) bsum[b] = lsum[255];
}

__global__ __launch_bounds__(128) void scan_bsums(const int* __restrict__ bsum,
                                                  int* __restrict__ boff,
                                                  int* __restrict__ rowptr) {
    __shared__ int s[128];
    int t = threadIdx.x;
    int v = (t < NSB) ? bsum[t] : 0;
    s[t] = v;
    __syncthreads();
    for (int off = 1; off < 128; off <<= 1) {
        int x = (t >= off) ? s[t - off] : 0;
        __syncthreads();
        s[t] += x;
        __syncthreads();
    }
    if (t < NSB) boff[t] = (t == 0) ? 0 : s[t - 1];
    if (t == 127) rowptr[N_NODES] = N_EDGES;
}

__global__ __launch_bounds__(256) void scan_add(int* __restrict__ rowptr,
                                                const int* __restrict__ boff) {
    int off = boff[blockIdx.x];
    int base = blockIdx.x * SBLK + threadIdx.x * 4;
#pragma unroll
    for (int k = 0; k < 4; ++k) {
        int i = base + k;
        if (i < N_NODES) rowptr[i] += off;
    }
}

__global__ __launch_bounds__(256) void fill_kernel(const int* __restrict__ ei,
                                                   const int* __restrict__ rowptr,
                                                   int* __restrict__ cursor,
                                                   int* __restrict__ elist) {
    int e = blockIdx.x * 256 + threadIdx.x;
    if (e >= N_EDGES) return;
    int s = ei[e];
    int d = ei[N_EDGES + e];
    int pos = rowptr[d] + atomicAdd(&cursor[d], 1);
    elist[pos] = s;
}

// ---------------------------------------------------------------------------
// Fused SAGE layer, bf16 h storage:
//   hout[i,c] = bf16( relu( mean_agg[i,:] @ Wl + bl + hin[i,:] @ Wr )[c]*s[c] + t[c] )
// hin/hout bf16 (ushort); gather + GEMM accumulate fp32; W fp32.
// Block: 32 rows x 128 cols, 256 threads, 4x4 register tile.
// ---------------------------------------------------------------------------
__global__ __launch_bounds__(256) void sage_fused(const int* __restrict__ rowptr,
                                                  const int* __restrict__ elist,
                                                  const unsigned short* __restrict__ hin,
                                                  unsigned short* __restrict__ hout,
                                                  const float* __restrict__ Wl,
                                                  const float* __restrict__ bl,
                                                  const float* __restrict__ Wr,
                                                  const float* __restrict__ scale,
                                                  const float* __restrict__ shift) {
    __shared__ float sA[32][CDIM + 4];
    __shared__ float sH[32][CDIM + 4];

    int row0 = blockIdx.x * 32;
    int tid = threadIdx.x;
    int lane = tid & 31;      // channel group: floats lane*4..lane*4+3
    int grp = tid >> 5;       // 8 node-groups

    // ---- gather phase: 4 rounds x 8 nodes; 8 B (4 bf16) per lane per edge ----
    for (int rr = 0; rr < 4; ++rr) {
        int r = rr * 8 + grp;
        int node = row0 + r;
        int beg = rowptr[node];
        int end = rowptr[node + 1];
        float4 acc = make_float4(0.f, 0.f, 0.f, 0.f);
        int j = beg;
        for (; j + 4 <= end; j += 4) {
            int s0 = elist[j], s1 = elist[j + 1], s2 = elist[j + 2], s3 = elist[j + 3];
            uint2 u0 = ((const uint2*)(hin + (size_t)s0 * CDIM))[lane];
            uint2 u1 = ((const uint2*)(hin + (size_t)s1 * CDIM))[lane];
            uint2 u2 = ((const uint2*)(hin + (size_t)s2 * CDIM))[lane];
            uint2 u3 = ((const uint2*)(hin + (size_t)s3 * CDIM))[lane];
            float a0, b0, c0, d0, a1, b1, c1, d1;
            unpk(u0.x, a0, b0); unpk(u0.y, c0, d0);
            unpk(u1.x, a1, b1); unpk(u1.y, c1, d1);
            acc.x += a0 + a1; acc.y += b0 + b1; acc.z += c0 + c1; acc.w += d0 + d1;
            unpk(u2.x, a0, b0); unpk(u2.y, c0, d0);
            unpk(u3.x, a1, b1); unpk(u3.y, c1, d1);
            acc.x += a0 + a1; acc.y += b0 + b1; acc.z += c0 + c1; acc.w += d0 + d1;
        }
        for (; j < end; ++j) {
            int s0 = elist[j];
            uint2 u0 = ((const uint2*)(hin + (size_t)s0 * CDIM))[lane];
            float a0, b0, c0, d0;
            unpk(u0.x, a0, b0); unpk(u0.y, c0, d0);
            acc.x += a0; acc.y += b0; acc.z += c0; acc.w += d0;
        }
        float rin = 1.0f / fmaxf((float)(end - beg), 1.0f);
        acc.x *= rin; acc.y *= rin; acc.z *= rin; acc.w *= rin;
        *((float4*)&sA[r][lane * 4]) = acc;
    }

    // ---- stage own rows (bf16 -> fp32 into LDS) ----
    for (int it = 0; it < 4; ++it) {
        int idx = it * 256 + tid;     // 0..1023
        int r = idx >> 5;
        int c4 = idx & 31;
        uint2 u = ((const uint2*)(hin + (size_t)(row0 + r) * CDIM))[c4];
        float4 f;
        unpk(u.x, f.x, f.y); unpk(u.y, f.z, f.w);
        *((float4*)&sH[r][c4 * 4]) = f;
    }
    __syncthreads();

    // ---- GEMM phase ----
    int cg = tid & 31;
    int rg = tid >> 5;
    int c0 = cg * 4;
    int r0 = rg * 4;

    float acc[4][4];
#pragma unroll
    for (int r = 0; r < 4; ++r)
#pragma unroll
        for (int c = 0; c < 4; ++c) acc[r][c] = 0.0f;

    for (int k = 0; k < CDIM; ++k) {
        float4 wl = ((const float4*)(Wl + (size_t)k * CDIM))[cg];
        float4 wr = ((const float4*)(Wr + (size_t)k * CDIM))[cg];
#pragma unroll
        for (int r = 0; r < 4; ++r) {
            float a = sA[r0 + r][k];
            float hh = sH[r0 + r][k];
            acc[r][0] += a * wl.x + hh * wr.x;
            acc[r][1] += a * wl.y + hh * wr.y;
            acc[r][2] += a * wl.z + hh * wr.z;
            acc[r][3] += a * wl.w + hh * wr.w;
        }
    }

    float4 bb = *((const float4*)(bl + c0));
    float4 ss = *((const float4*)(scale + c0));
    float4 tt = *((const float4*)(shift + c0));
#pragma unroll
    for (int r = 0; r < 4; ++r) {
        float ox = fmaxf(acc[r][0] + bb.x, 0.0f) * ss.x + tt.x;
        float oy = fmaxf(acc[r][1] + bb.y, 0.0f) * ss.y + tt.y;
        float oz = fmaxf(acc[r][2] + bb.z, 0.0f) * ss.z + tt.z;
        float ow = fmaxf(acc[r][3] + bb.w, 0.0f) * ss.w + tt.w;
        ushort4 o;
        o.x = f2bf(ox); o.y = f2bf(oy); o.z = f2bf(oz); o.w = f2bf(ow);
        ((ushort4*)(hout + (size_t)(row0 + r0 + r) * CDIM))[cg] = o;
    }
}

// ---------------------------------------------------------------------------
// Head GEMM 1: bf16 input, fp32 weights/accum: out = relu(bn(hin @ W + b))
// ---------------------------------------------------------------------------
__global__ __launch_bounds__(256) void head_gemm1(const unsigned short* __restrict__ hin,
                                                  const float* __restrict__ W,
                                                  const float* __restrict__ bias,
                                                  const float* __restrict__ scale,
                                                  const float* __restrict__ shift,
                                                  float* __restrict__ out) {
    __shared__ float sH[32][CDIM + 4];
    int row0 = blockIdx.x * 32;
    int tid = threadIdx.x;

    for (int it = 0; it < 4; ++it) {
        int idx = it * 256 + tid;
        int r = idx >> 5;
        int c4 = idx & 31;
        int row = row0 + r;
        float4 f = make_float4(0.f, 0.f, 0.f, 0.f);
        if (row < BATCH) {
            uint2 u = ((const uint2*)(hin + (size_t)row * CDIM))[c4];
            unpk(u.x, f.x, f.y); unpk(u.y, f.z, f.w);
        }
        *((float4*)&sH[r][c4 * 4]) = f;
    }
    __syncthreads();

    int cg = tid & 31;
    int rg = tid >> 5;
    int c0 = cg * 4;
    int r0 = rg * 4;

    float acc[4][4];
#pragma unroll
    for (int r = 0; r < 4; ++r)
#pragma unroll
        for (int c = 0; c < 4; ++c) acc[r][c] = 0.0f;

    for (int k = 0; k < CDIM; ++k) {
        float4 w = ((const float4*)(W + (size_t)k * CDIM))[cg];
#pragma unroll
        for (int r = 0; r < 4; ++r) {
            float hh = sH[r0 + r][k];
            acc[r][0] += hh * w.x;
            acc[r][1] += hh * w.y;
            acc[r][2] += hh * w.z;
            acc[r][3] += hh * w.w;
        }
    }

    float4 bb = *((const float4*)(bias + c0));
    float4 ss = *((const float4*)(scale + c0));
    float4 tt = *((const float4*)(shift + c0));
#pragma unroll
    for (int r = 0; r < 4; ++r) {
        int row = row0 + r0 + r;
        if (row >= BATCH) continue;
        float4 o;
        o.x = fmaxf((acc[r][0] + bb.x) * ss.x + tt.x, 0.0f);
        o.y = fmaxf((acc[r][1] + bb.y) * ss.y + tt.y, 0.0f);
        o.z = fmaxf((acc[r][2] + bb.z) * ss.z + tt.z, 0.0f);
        o.w = fmaxf((acc[r][3] + bb.w) * ss.w + tt.w, 0.0f);
        ((float4*)(out + (size_t)row * CDIM))[cg] = o;
    }
}

// ---------------------------------------------------------------------------
// Head GEMM 2: 128 -> 64 fp32
// ---------------------------------------------------------------------------
__global__ __launch_bounds__(256) void head_gemm2(const float* __restrict__ hin,
                                                  const float* __restrict__ W,
                                                  const float* __restrict__ bias,
                                                  const float* __restrict__ scale,
                                                  const float* __restrict__ shift,
                                                  float* __restrict__ out) {
    __shared__ float sH[64][CDIM + 4];
    int row0 = blockIdx.x * 64;
    int tid = threadIdx.x;

    for (int it = 0; it < 8; ++it) {
        int idx = it * 256 + tid;
        int r = idx >> 5;
        int c4 = idx & 31;
        int row = row0 + r;
        float4 hv = make_float4(0.f, 0.f, 0.f, 0.f);
        if (row < BATCH) hv = ((const float4*)(hin + (size_t)row * CDIM))[c4];
        *((float4*)&sH[r][c4 * 4]) = hv;
    }
    __syncthreads();

    int cg = tid & 15;
    int rg = tid >> 4;
    int c0 = cg * 4;
    int r0 = rg * 4;

    float acc[4][4];
#pragma unroll
    for (int r = 0; r < 4; ++r)
#pragma unroll
        for (int c = 0; c < 4; ++c) acc[r][c] = 0.0f;

    for (int k = 0; k < CDIM; ++k) {
        float4 w = ((const float4*)(W + (size_t)k * 64))[cg];
#pragma unroll
        for (int r = 0; r < 4; ++r) {
            float hh = sH[r0 + r][k];
            acc[r][0] += hh * w.x;
            acc[r][1] += hh * w.y;
            acc[r][2] += hh * w.z;
            acc[r][3] += hh * w.w;
        }
    }

    float4 bb = *((const float4*)(bias + c0));
    float4 ss = *((const float4*)(scale + c0));
    float4 tt = *((const float4*)(shift + c0));
#pragma unroll
    for (int r = 0; r < 4; ++r) {
        int row = row0 + r0 + r;
        if (row >= BATCH) continue;
        float4 o;
        o.x = fmaxf((acc[r][0] + bb.x) * ss.x + tt.x, 0.0f);
        o.y = fmaxf((acc[r][1] + bb.y) * ss.y + tt.y, 0.0f);
        o.z = fmaxf((acc[r][2] + bb.z) * ss.z + tt.z, 0.0f);
        o.w = fmaxf((acc[r][3] + bb.w) * ss.w + tt.w, 0.0f);
        ((float4*)(out + (size_t)row * 64))[cg] = o;
    }
}

// ---------------------------------------------------------------------------
// Final: out[i] = t2[i,:] @ W3 + b3
// ---------------------------------------------------------------------------
__global__ __launch_bounds__(256) void head_final(const float* __restrict__ t2,
                                                  const float* __restrict__ W3,
                                                  const float* __restrict__ b3,
                                                  float* __restrict__ out) {
    __shared__ float w[64];
    if (threadIdx.x < 64) w[threadIdx.x] = W3[threadIdx.x];
    __syncthreads();
    int i = blockIdx.x * 256 + threadIdx.x;
    if (i >= BATCH) return;
    const float4* r = (const float4*)(t2 + (size_t)i * 64);
    float acc = b3[0];
#pragma unroll
    for (int k = 0; k < 16; ++k) {
        float4 v = r[k];
        acc += v.x * w[4 * k] + v.y * w[4 * k + 1] + v.z * w[4 * k + 2] + v.w * w[4 * k + 3];
    }
    out[i] = acc;
}

// ---------------------------------------------------------------------------
extern "C" void kernel_launch(void* const* d_in, const int* in_sizes, int n_in,
                              void* d_out, int out_size, void* d_ws, size_t ws_size,
                              hipStream_t stream) {
    const float* x    = (const float*)d_in[0];
    const int*   ei   = (const int*)d_in[1];
    const float* Wl   = (const float*)d_in[3];
    const float* bl   = (const float*)d_in[4];
    const float* Wr   = (const float*)d_in[5];
    const float* bn_g = (const float*)d_in[6];
    const float* bn_b = (const float*)d_in[7];
    const float* bn_m = (const float*)d_in[8];
    const float* bn_v = (const float*)d_in[9];
    const float* cW1  = (const float*)d_in[10];
    const float* cb1  = (const float*)d_in[11];
    const float* cg1  = (const float*)d_in[12];
    const float* cbe1 = (const float*)d_in[13];
    const float* cm1  = (const float*)d_in[14];
    const float* cv1  = (const float*)d_in[15];
    const float* cW2  = (const float*)d_in[16];
    const float* cb2  = (const float*)d_in[17];
    const float* cg2  = (const float*)d_in[18];
    const float* cbe2 = (const float*)d_in[19];
    const float* cm2  = (const float*)d_in[20];
    const float* cv2  = (const float*)d_in[21];
    const float* cW3  = (const float*)d_in[22];
    const float* cb3  = (const float*)d_in[23];

    // Workspace layout (4-byte units):
    float* ws  = (float*)d_ws;
    unsigned short* xb  = (unsigned short*)ws;                    // N*C bf16 = 6.4M floats
    unsigned short* hb0 = (unsigned short*)(ws + 6400000);        // N*C bf16
    unsigned short* hb1 = (unsigned short*)(ws + 12800000);       // N*C bf16
    float* sc   = ws + 19200000;                                  // 1152 floats
    int* rowptr = (int*)(sc + 1152);                              // N+1
    int* ideg   = rowptr + (N_NODES + 1);                         // N
    int* bsum   = ideg + N_NODES;                                 // 128
    int* boff   = bsum + 128;                                     // 128
    int* elist  = boff + 128;                                     // E
    float* t1   = (float*)xb;                                     // 50k*128 fp32 = xb size (xb dead after layer 0... reused after layer 2)
    float* t2   = (float*)hb1;                                    // 50k*64 fp32 (hb1 dead after layer 2)

    fold_bn_kernel<<<1, 384, 0, stream>>>(bn_g, bn_b, bn_m, bn_v,
                                          cg1, cbe1, cm1, cv1,
                                          cg2, cbe2, cm2, cv2, sc);

    convert_x<<<(N_NODES * CDIM / 4 + 255) / 256, 256, 0, stream>>>(x, xb);

    // ---- build CSR once ----
    hipMemsetAsync(ideg, 0, N_NODES * sizeof(int), stream);
    hist_kernel<<<(N_EDGES + 255) / 256, 256, 0, stream>>>(ei, ideg);
    scan_blocks<<<NSB, 256, 0, stream>>>(ideg, rowptr, bsum);
    scan_bsums<<<1, 128, 0, stream>>>(bsum, boff, rowptr);
    scan_add<<<NSB, 256, 0, stream>>>(rowptr, boff);
    hipMemsetAsync(ideg, 0, N_NODES * sizeof(int), stream);
    fill_kernel<<<(N_EDGES + 255) / 256, 256, 0, stream>>>(ei, rowptr, ideg, elist);

    // ---- 3 fused SAGE layers (bf16 ping-pong: xb->hb0->hb1->hb0) ----
    const unsigned short* lin[NLAYERS] = { xb, hb0, hb1 };
    unsigned short* lout[NLAYERS]      = { hb0, hb1, hb0 };
    for (int l = 0; l < NLAYERS; ++l) {
        sage_fused<<<N_NODES / 32, 256, 0, stream>>>(
            rowptr, elist, lin[l], lout[l],
            Wl + (size_t)l * CDIM * CDIM, bl + (size_t)l * CDIM,
            Wr + (size_t)l * CDIM * CDIM,
            sc + l * CDIM, sc + 384 + l * CDIM);
    }

    // ---- MLP head on first BATCH rows (input: hb0 bf16) ----
    head_gemm1<<<(BATCH + 31) / 32, 256, 0, stream>>>(hb0, cW1, cb1, sc + 768, sc + 896, t1);
    head_gemm2<<<(BATCH + 63) / 64, 256, 0, stream>>>(t1, cW2, cb2, sc + 1024, sc + 1088, t2);
    head_final<<<(BATCH + 255) / 256, 256, 0, stream>>>(t2, cW3, cb3, (float*)d_out);
}

// Round 5
// 625.734 us; speedup vs baseline: 14.2099x; 1.4972x over previous
//
#include <hip/hip_runtime.h>

#define N_NODES 100000
#define N_EDGES 1600000
#define CDIM    128
#define BATCH   50000
#define NLAYERS 3
#define EPS_BN  1e-5f
#define SBLK    1024
#define NSB     ((N_NODES + SBLK - 1) / SBLK)   // 98
#define LPAD    136   // LDS row stride in bf16 elems (272 B: 16B-aligned, bank-shift 4)

typedef __attribute__((ext_vector_type(8))) short short8;   // 8 bf16 (4 VGPRs)
typedef __attribute__((ext_vector_type(4))) float floatx4;  // MFMA accumulator

__device__ __forceinline__ unsigned short f2bf(float f) {
    unsigned int u = __float_as_uint(f);
    u = u + 0x7FFFu + ((u >> 16) & 1u);   // RTNE
    return (unsigned short)(u >> 16);
}
__device__ __forceinline__ void unpk(unsigned int u, float& lo, float& hi) {
    lo = __uint_as_float(u << 16);
    hi = __uint_as_float(u & 0xFFFF0000u);
}

// ---------------------------------------------------------------------------
// Fold BN params. sc[]: [0..383] layer scale, [384..767] layer shift,
// [768..895]/[896..1023] head1 s/t, [1024..1087]/[1088..1151] head2 s/t
// ---------------------------------------------------------------------------
__global__ void fold_bn_kernel(const float* __restrict__ g, const float* __restrict__ b,
                               const float* __restrict__ m, const float* __restrict__ v,
                               const float* __restrict__ cg1, const float* __restrict__ cbe1,
                               const float* __restrict__ cm1, const float* __restrict__ cv1,
                               const float* __restrict__ cg2, const float* __restrict__ cbe2,
                               const float* __restrict__ cm2, const float* __restrict__ cv2,
                               float* __restrict__ sc) {
    int i = threadIdx.x;
    if (i < NLAYERS * CDIM) {
        float s = g[i] * rsqrtf(v[i] + EPS_BN);
        sc[i] = s;
        sc[NLAYERS * CDIM + i] = b[i] - m[i] * s;
    }
    if (i < CDIM) {
        float s = cg1[i] * rsqrtf(cv1[i] + EPS_BN);
        sc[768 + i] = s;
        sc[896 + i] = cbe1[i] - cm1[i] * s;
    }
    if (i < 64) {
        float s = cg2[i] * rsqrtf(cv2[i] + EPS_BN);
        sc[1024 + i] = s;
        sc[1088 + i] = cbe2[i] - cm2[i] * s;
    }
}

// ---------------------------------------------------------------------------
// Convert x (fp32) -> xb (bf16)
// ---------------------------------------------------------------------------
__global__ __launch_bounds__(256) void convert_x(const float* __restrict__ x,
                                                 unsigned short* __restrict__ xb) {
    int i = blockIdx.x * 256 + threadIdx.x;
    const int TOT = N_NODES * CDIM / 4;
    if (i >= TOT) return;
    float4 v = ((const float4*)x)[i];
    ushort4 o;
    o.x = f2bf(v.x); o.y = f2bf(v.y); o.z = f2bf(v.z); o.w = f2bf(v.w);
    ((ushort4*)xb)[i] = o;
}

// ---------------------------------------------------------------------------
// Build Wcat^T in bf16: wcat[l][n][k], n in [0,128), k in [0,256):
//   k<128 -> Wl[l][k][n],  k>=128 -> Wr[l][k-128][n]
// (B-operand layout for MFMA wants contiguous k per output col n)
// ---------------------------------------------------------------------------
__global__ __launch_bounds__(256) void convert_w(const float* __restrict__ Wl,
                                                 const float* __restrict__ Wr,
                                                 unsigned short* __restrict__ wcat) {
    int i = blockIdx.x * 256 + threadIdx.x;        // l*32768 + n*256 + k
    const int TOT = NLAYERS * CDIM * 256;
    if (i >= TOT) return;
    int l = i >> 15;
    int n = (i >> 8) & 127;
    int k = i & 255;
    float w = (k < CDIM) ? Wl[((size_t)l * CDIM + k) * CDIM + n]
                         : Wr[((size_t)l * CDIM + (k - CDIM)) * CDIM + n];
    wcat[i] = f2bf(w);
}

// ---------------------------------------------------------------------------
// CSR build
// ---------------------------------------------------------------------------
__global__ __launch_bounds__(256) void hist_kernel(const int* __restrict__ ei,
                                                   int* __restrict__ deg) {
    int e = blockIdx.x * 256 + threadIdx.x;
    if (e >= N_EDGES) return;
    atomicAdd(&deg[ei[N_EDGES + e]], 1);
}

__global__ __launch_bounds__(256) void scan_blocks(const int* __restrict__ deg,
                                                   int* __restrict__ rowptr,
                                                   int* __restrict__ bsum) {
    __shared__ int lsum[256];
    int b = blockIdx.x, t = threadIdx.x;
    int base = b * SBLK + t * 4;
    int v[4];
#pragma unroll
    for (int k = 0; k < 4; ++k) {
        int i = base + k;
        v[k] = (i < N_NODES) ? deg[i] : 0;
    }
    int s = v[0] + v[1] + v[2] + v[3];
    lsum[t] = s;
    __syncthreads();
    for (int off = 1; off < 256; off <<= 1) {
        int x = (t >= off) ? lsum[t - off] : 0;
        __syncthreads();
        lsum[t] += x;
        __syncthreads();
    }
    int ex = (t == 0) ? 0 : lsum[t - 1];
#pragma unroll
    for (int k = 0; k < 4; ++k) {
        int i = base + k;
        if (i < N_NODES) rowptr[i] = ex;
        ex += v[k];
    }
    if (t == 255) bsum[b] = lsum[255];
}

__global__ __launch_bounds__(128) void scan_bsums(const int* __restrict__ bsum,
                                                  int* __restrict__ boff,
                                                  int* __restrict__ rowptr) {
    __shared__ int s[128];
    int t = threadIdx.x;
    int v = (t < NSB) ? bsum[t] : 0;
    s[t] = v;
    __syncthreads();
    for (int off = 1; off < 128; off <<= 1) {
        int x = (t >= off) ? s[t - off] : 0;
        __syncthreads();
        s[t] += x;
        __syncthreads();
    }
    if (t < NSB) boff[t] = (t == 0) ? 0 : s[t - 1];
    if (t == 127) rowptr[N_NODES] = N_EDGES;
}

__global__ __launch_bounds__(256) void scan_add(int* __restrict__ rowptr,
                                                const int* __restrict__ boff) {
    int off = boff[blockIdx.x];
    int base = blockIdx.x * SBLK + threadIdx.x * 4;
#pragma unroll
    for (int k = 0; k < 4; ++k) {
        int i = base + k;
        if (i < N_NODES) rowptr[i] += off;
    }
}

__global__ __launch_bounds__(256) void fill_kernel(const int* __restrict__ ei,
                                                   const int* __restrict__ rowptr,
                                                   int* __restrict__ cursor,
                                                   int* __restrict__ elist) {
    int e = blockIdx.x * 256 + threadIdx.x;
    if (e >= N_EDGES) return;
    int s = ei[e];
    int d = ei[N_EDGES + e];
    int pos = rowptr[d] + atomicAdd(&cursor[d], 1);
    elist[pos] = s;
}

// ---------------------------------------------------------------------------
// Fused SAGE layer, bf16 storage, MFMA GEMM:
//   hout = bf16( relu( [mean_agg | hin] @ [Wl;Wr] + bl ) * s + t )
// Block: 32 rows x 128 cols, 256 thr (4 waves). LDS: bf16 sA/sH (17.4 KB).
// Wave w computes cols [w*32, w*32+32): 2 M-tiles x 2 N-tiles of 16x16,
// K=256 via 8 x mfma_f32_16x16x32_bf16 per tile.
// __launch_bounds__(256,8): cap VGPR<=64 so 8 blocks/CU (occupancy 100%)
// — the gather phase is latency-bound and needs the wave slots.
// ---------------------------------------------------------------------------
__global__ __launch_bounds__(256, 8) void sage_fused(const int* __restrict__ rowptr,
                                                     const int* __restrict__ elist,
                                                     const unsigned short* __restrict__ hin,
                                                     unsigned short* __restrict__ hout,
                                                     const unsigned short* __restrict__ wcat,
                                                     const float* __restrict__ bl,
                                                     const float* __restrict__ scale,
                                                     const float* __restrict__ shift) {
    __shared__ unsigned short sA[32][LPAD];
    __shared__ unsigned short sH[32][LPAD];

    int row0 = blockIdx.x * 32;
    int tid = threadIdx.x;
    int lane = tid & 31;      // channel group: bf16 elems lane*4..lane*4+3
    int grp = tid >> 5;       // 8 node-groups

    // ---- gather phase: 4 rounds x 8 nodes; uint2 (4 bf16) per lane per edge ----
    for (int rr = 0; rr < 4; ++rr) {
        int r = rr * 8 + grp;
        int node = row0 + r;
        int beg = rowptr[node];
        int end = rowptr[node + 1];
        float4 acc = make_float4(0.f, 0.f, 0.f, 0.f);
        int j = beg;
        for (; j + 4 <= end; j += 4) {
            int s0 = elist[j], s1 = elist[j + 1], s2 = elist[j + 2], s3 = elist[j + 3];
            uint2 u0 = ((const uint2*)(hin + (size_t)s0 * CDIM))[lane];
            uint2 u1 = ((const uint2*)(hin + (size_t)s1 * CDIM))[lane];
            uint2 u2 = ((const uint2*)(hin + (size_t)s2 * CDIM))[lane];
            uint2 u3 = ((const uint2*)(hin + (size_t)s3 * CDIM))[lane];
            float a0, b0, c0, d0, a1, b1, c1, d1;
            unpk(u0.x, a0, b0); unpk(u0.y, c0, d0);
            unpk(u1.x, a1, b1); unpk(u1.y, c1, d1);
            acc.x += a0 + a1; acc.y += b0 + b1; acc.z += c0 + c1; acc.w += d0 + d1;
            unpk(u2.x, a0, b0); unpk(u2.y, c0, d0);
            unpk(u3.x, a1, b1); unpk(u3.y, c1, d1);
            acc.x += a0 + a1; acc.y += b0 + b1; acc.z += c0 + c1; acc.w += d0 + d1;
        }
        for (; j < end; ++j) {
            int s0 = elist[j];
            uint2 u0 = ((const uint2*)(hin + (size_t)s0 * CDIM))[lane];
            float a0, b0, c0, d0;
            unpk(u0.x, a0, b0); unpk(u0.y, c0, d0);
            acc.x += a0; acc.y += b0; acc.z += c0; acc.w += d0;
        }
        float rin = 1.0f / fmaxf((float)(end - beg), 1.0f);
        ushort4 o;
        o.x = f2bf(acc.x * rin); o.y = f2bf(acc.y * rin);
        o.z = f2bf(acc.z * rin); o.w = f2bf(acc.w * rin);
        *((ushort4*)&sA[r][lane * 4]) = o;
    }

    // ---- stage own rows (pure bf16 copy) ----
    for (int it = 0; it < 4; ++it) {
        int idx = it * 256 + tid;     // 0..1023
        int r = idx >> 5;
        int c4 = idx & 31;
        uint2 u = ((const uint2*)(hin + (size_t)(row0 + r) * CDIM))[c4];
        *((uint2*)&sH[r][c4 * 4]) = u;
    }
    __syncthreads();

    // ---- MFMA GEMM phase ----
    int wave = tid >> 6;
    int wl   = tid & 63;
    int ln16 = wl & 15;
    int quad = wl >> 4;

    floatx4 acc[2][2];
#pragma unroll
    for (int mt = 0; mt < 2; ++mt)
#pragma unroll
        for (int nt = 0; nt < 2; ++nt) acc[mt][nt] = (floatx4)0.0f;

    const unsigned short* wbase = wcat + ((size_t)(wave * 32 + ln16) * 256 + quad * 8);

#pragma unroll
    for (int kb = 0; kb < 8; ++kb) {
        int koff = (kb & 3) * 32 + quad * 8;
        const unsigned short* sbuf = (kb < 4) ? &sA[0][0] : &sH[0][0];
        short8 a0 = *((const short8*)(sbuf + (ln16)      * LPAD + koff));
        short8 a1 = *((const short8*)(sbuf + (ln16 + 16) * LPAD + koff));
        short8 b0 = *((const short8*)(wbase + kb * 32));
        short8 b1 = *((const short8*)(wbase + 16 * 256 + kb * 32));
        acc[0][0] = __builtin_amdgcn_mfma_f32_16x16x32_bf16(a0, b0, acc[0][0], 0, 0, 0);
        acc[1][0] = __builtin_amdgcn_mfma_f32_16x16x32_bf16(a1, b0, acc[1][0], 0, 0, 0);
        acc[0][1] = __builtin_amdgcn_mfma_f32_16x16x32_bf16(a0, b1, acc[0][1], 0, 0, 0);
        acc[1][1] = __builtin_amdgcn_mfma_f32_16x16x32_bf16(a1, b1, acc[1][1], 0, 0, 0);
    }

    // ---- epilogue: C layout col=lane&15, row=quad*4+reg ----
#pragma unroll
    for (int nt = 0; nt < 2; ++nt) {
        int col = wave * 32 + nt * 16 + ln16;
        float bb = bl[col];
        float ss = scale[col];
        float tt = shift[col];
#pragma unroll
        for (int mt = 0; mt < 2; ++mt) {
#pragma unroll
            for (int r = 0; r < 4; ++r) {
                int row = row0 + mt * 16 + quad * 4 + r;
                float v = fmaxf(acc[mt][nt][r] + bb, 0.0f) * ss + tt;
                hout[(size_t)row * CDIM + col] = f2bf(v);
            }
        }
    }
}

// ---------------------------------------------------------------------------
// Head GEMM 1: bf16 input, fp32 weights/accum: out = relu(bn(hin @ W + b))
// ---------------------------------------------------------------------------
__global__ __launch_bounds__(256) void head_gemm1(const unsigned short* __restrict__ hin,
                                                  const float* __restrict__ W,
                                                  const float* __restrict__ bias,
                                                  const float* __restrict__ scale,
                                                  const float* __restrict__ shift,
                                                  float* __restrict__ out) {
    __shared__ float sH[32][CDIM + 4];
    int row0 = blockIdx.x * 32;
    int tid = threadIdx.x;

    for (int it = 0; it < 4; ++it) {
        int idx = it * 256 + tid;
        int r = idx >> 5;
        int c4 = idx & 31;
        int row = row0 + r;
        float4 f = make_float4(0.f, 0.f, 0.f, 0.f);
        if (row < BATCH) {
            uint2 u = ((const uint2*)(hin + (size_t)row * CDIM))[c4];
            unpk(u.x, f.x, f.y); unpk(u.y, f.z, f.w);
        }
        *((float4*)&sH[r][c4 * 4]) = f;
    }
    __syncthreads();

    int cg = tid & 31;
    int rg = tid >> 5;
    int c0 = cg * 4;
    int r0 = rg * 4;

    float acc[4][4];
#pragma unroll
    for (int r = 0; r < 4; ++r)
#pragma unroll
        for (int c = 0; c < 4; ++c) acc[r][c] = 0.0f;

    for (int k = 0; k < CDIM; ++k) {
        float4 w = ((const float4*)(W + (size_t)k * CDIM))[cg];
#pragma unroll
        for (int r = 0; r < 4; ++r) {
            float hh = sH[r0 + r][k];
            acc[r][0] += hh * w.x;
            acc[r][1] += hh * w.y;
            acc[r][2] += hh * w.z;
            acc[r][3] += hh * w.w;
        }
    }

    float4 bb = *((const float4*)(bias + c0));
    float4 ss = *((const float4*)(scale + c0));
    float4 tt = *((const float4*)(shift + c0));
#pragma unroll
    for (int r = 0; r < 4; ++r) {
        int row = row0 + r0 + r;
        if (row >= BATCH) continue;
        float4 o;
        o.x = fmaxf((acc[r][0] + bb.x) * ss.x + tt.x, 0.0f);
        o.y = fmaxf((acc[r][1] + bb.y) * ss.y + tt.y, 0.0f);
        o.z = fmaxf((acc[r][2] + bb.z) * ss.z + tt.z, 0.0f);
        o.w = fmaxf((acc[r][3] + bb.w) * ss.w + tt.w, 0.0f);
        ((float4*)(out + (size_t)row * CDIM))[cg] = o;
    }
}

// ---------------------------------------------------------------------------
// Head GEMM 2: 128 -> 64 fp32
// ---------------------------------------------------------------------------
__global__ __launch_bounds__(256) void head_gemm2(const float* __restrict__ hin,
                                                  const float* __restrict__ W,
                                                  const float* __restrict__ bias,
                                                  const float* __restrict__ scale,
                                                  const float* __restrict__ shift,
                                                  float* __restrict__ out) {
    __shared__ float sH[64][CDIM + 4];
    int row0 = blockIdx.x * 64;
    int tid = threadIdx.x;

    for (int it = 0; it < 8; ++it) {
        int idx = it * 256 + tid;
        int r = idx >> 5;
        int c4 = idx & 31;
        int row = row0 + r;
        float4 hv = make_float4(0.f, 0.f, 0.f, 0.f);
        if (row < BATCH) hv = ((const float4*)(hin + (size_t)row * CDIM))[c4];
        *((float4*)&sH[r][c4 * 4]) = hv;
    }
    __syncthreads();

    int cg = tid & 15;
    int rg = tid >> 4;
    int c0 = cg * 4;
    int r0 = rg * 4;

    float acc[4][4];
#pragma unroll
    for (int r = 0; r < 4; ++r)
#pragma unroll
        for (int c = 0; c < 4; ++c) acc[r][c] = 0.0f;

    for (int k = 0; k < CDIM; ++k) {
        float4 w = ((const float4*)(W + (size_t)k * 64))[cg];
#pragma unroll
        for (int r = 0; r < 4; ++r) {
            float hh = sH[r0 + r][k];
            acc[r][0] += hh * w.x;
            acc[r][1] += hh * w.y;
            acc[r][2] += hh * w.z;
            acc[r][3] += hh * w.w;
        }
    }

    float4 bb = *((const float4*)(bias + c0));
    float4 ss = *((const float4*)(scale + c0));
    float4 tt = *((const float4*)(shift + c0));
#pragma unroll
    for (int r = 0; r < 4; ++r) {
        int row = row0 + r0 + r;
        if (row >= BATCH) continue;
        float4 o;
        o.x = fmaxf((acc[r][0] + bb.x) * ss.x + tt.x, 0.0f);
        o.y = fmaxf((acc[r][1] + bb.y) * ss.y + tt.y, 0.0f);
        o.z = fmaxf((acc[r][2] + bb.z) * ss.z + tt.z, 0.0f);
        o.w = fmaxf((acc[r][3] + bb.w) * ss.w + tt.w, 0.0f);
        ((float4*)(out + (size_t)row * 64))[cg] = o;
    }
}

// ---------------------------------------------------------------------------
// Final: out[i] = t2[i,:] @ W3 + b3
// ---------------------------------------------------------------------------
__global__ __launch_bounds__(256) void head_final(const float* __restrict__ t2,
                                                  const float* __restrict__ W3,
                                                  const float* __restrict__ b3,
                                                  float* __restrict__ out) {
    __shared__ float w[64];
    if (threadIdx.x < 64) w[threadIdx.x] = W3[threadIdx.x];
    __syncthreads();
    int i = blockIdx.x * 256 + threadIdx.x;
    if (i >= BATCH) return;
    const float4* r = (const float4*)(t2 + (size_t)i * 64);
    float acc = b3[0];
#pragma unroll
    for (int k = 0; k < 16; ++k) {
        float4 v = r[k];
        acc += v.x * w[4 * k] + v.y * w[4 * k + 1] + v.z * w[4 * k + 2] + v.w * w[4 * k + 3];
    }
    out[i] = acc;
}

// ---------------------------------------------------------------------------
extern "C" void kernel_launch(void* const* d_in, const int* in_sizes, int n_in,
                              void* d_out, int out_size, void* d_ws, size_t ws_size,
                              hipStream_t stream) {
    const float* x    = (const float*)d_in[0];
    const int*   ei   = (const int*)d_in[1];
    const float* Wl   = (const float*)d_in[3];
    const float* bl   = (const float*)d_in[4];
    const float* Wr   = (const float*)d_in[5];
    const float* bn_g = (const float*)d_in[6];
    const float* bn_b = (const float*)d_in[7];
    const float* bn_m = (const float*)d_in[8];
    const float* bn_v = (const float*)d_in[9];
    const float* cW1  = (const float*)d_in[10];
    const float* cb1  = (const float*)d_in[11];
    const float* cg1  = (const float*)d_in[12];
    const float* cbe1 = (const float*)d_in[13];
    const float* cm1  = (const float*)d_in[14];
    const float* cv1  = (const float*)d_in[15];
    const float* cW2  = (const float*)d_in[16];
    const float* cb2  = (const float*)d_in[17];
    const float* cg2  = (const float*)d_in[18];
    const float* cbe2 = (const float*)d_in[19];
    const float* cm2  = (const float*)d_in[20];
    const float* cv2  = (const float*)d_in[21];
    const float* cW3  = (const float*)d_in[22];
    const float* cb3  = (const float*)d_in[23];

    // Workspace layout (4-byte units):
    float* ws  = (float*)d_ws;
    unsigned short* xb  = (unsigned short*)ws;                    // N*C bf16
    unsigned short* hb0 = (unsigned short*)(ws + 6400000);        // N*C bf16
    unsigned short* hb1 = (unsigned short*)(ws + 12800000);       // N*C bf16
    float* sc   = ws + 19200000;                                  // 1152 floats
    int* rowptr = (int*)(sc + 1152);                              // N+1
    int* ideg   = rowptr + (N_NODES + 1);                         // N
    int* bsum   = ideg + N_NODES;                                 // 128
    int* boff   = bsum + 128;                                     // 128
    int* elist  = boff + 128;                                     // E
    unsigned short* wcat = (unsigned short*)(elist + N_EDGES + 32); // 3*128*256 bf16
    float* t1   = (float*)xb;                                     // 50k*128 fp32
    float* t2   = (float*)hb1;                                    // 50k*64 fp32

    fold_bn_kernel<<<1, 384, 0, stream>>>(bn_g, bn_b, bn_m, bn_v,
                                          cg1, cbe1, cm1, cv1,
                                          cg2, cbe2, cm2, cv2, sc);

    convert_x<<<(N_NODES * CDIM / 4 + 255) / 256, 256, 0, stream>>>(x, xb);
    convert_w<<<(NLAYERS * CDIM * 256 + 255) / 256, 256, 0, stream>>>(Wl, Wr, wcat);

    // ---- build CSR once ----
    hipMemsetAsync(ideg, 0, N_NODES * sizeof(int), stream);
    hist_kernel<<<(N_EDGES + 255) / 256, 256, 0, stream>>>(ei, ideg);
    scan_blocks<<<NSB, 256, 0, stream>>>(ideg, rowptr, bsum);
    scan_bsums<<<1, 128, 0, stream>>>(bsum, boff, rowptr);
    scan_add<<<NSB, 256, 0, stream>>>(rowptr, boff);
    hipMemsetAsync(ideg, 0, N_NODES * sizeof(int), stream);
    fill_kernel<<<(N_EDGES + 255) / 256, 256, 0, stream>>>(ei, rowptr, ideg, elist);

    // ---- 3 fused SAGE layers (bf16 ping-pong: xb->hb0->hb1->hb0) ----
    const unsigned short* lin[NLAYERS] = { xb, hb0, hb1 };
    unsigned short* lout[NLAYERS]      = { hb0, hb1, hb0 };
    for (int l = 0; l < NLAYERS; ++l) {
        sage_fused<<<N_NODES / 32, 256, 0, stream>>>(
            rowptr, elist, lin[l], lout[l],
            wcat + (size_t)l * CDIM * 256,
            bl + (size_t)l * CDIM,
            sc + l * CDIM, sc + 384 + l * CDIM);
    }

    // ---- MLP head on first BATCH rows (input: hb0 bf16) ----
    head_gemm1<<<(BATCH + 31) / 32, 256, 0, stream>>>(hb0, cW1, cb1, sc + 768, sc + 896, t1);
    head_gemm2<<<(BATCH + 63) / 64, 256, 0, stream>>>(t1, cW2, cb2, sc + 1024, sc + 1088, t2);
    head_final<<<(BATCH + 255) / 256, 256, 0, stream>>>(t2, cW3, cb3, (float*)d_out);
}

// Round 6
// 536.579 us; speedup vs baseline: 16.5710x; 1.1662x over previous
//
#include <hip/hip_runtime.h>

#define N_NODES 100000
#define N_EDGES 1600000
#define CDIM    128
#define BATCH   50000
#define NLAYERS 3
#define EPS_BN  1e-5f
#define LPAD    136   // LDS row stride in bf16 elems (272 B)

#define NBUCK   512
#define BW      196   // 512*196 = 100352 >= N_NODES
#define EPB     4096  // edges per block, passes A/B
#define NEB     ((N_EDGES + EPB - 1) / EPB)   // 391
#define CAP     4608  // max edges per bucket (mean 3125, sd 56 -> +26 sigma)

typedef __attribute__((ext_vector_type(8))) short short8;   // 8 bf16
typedef __attribute__((ext_vector_type(4))) float floatx4;  // MFMA acc

__device__ __forceinline__ unsigned short f2bf(float f) {
    unsigned int u = __float_as_uint(f);
    u = u + 0x7FFFu + ((u >> 16) & 1u);   // RTNE
    return (unsigned short)(u >> 16);
}
__device__ __forceinline__ void unpk(unsigned int u, float& lo, float& hi) {
    lo = __uint_as_float(u << 16);
    hi = __uint_as_float(u & 0xFFFF0000u);
}
__device__ __forceinline__ unsigned int pk2(float lo, float hi) {
    return (unsigned int)f2bf(lo) | ((unsigned int)f2bf(hi) << 16);
}

// ---------------------------------------------------------------------------
// Fold BN params. sc[]: [0..383] layer scale, [384..767] layer shift,
// [768..895]/[896..1023] head1 s/t, [1024..1087]/[1088..1151] head2 s/t
// ---------------------------------------------------------------------------
__global__ void fold_bn_kernel(const float* __restrict__ g, const float* __restrict__ b,
                               const float* __restrict__ m, const float* __restrict__ v,
                               const float* __restrict__ cg1, const float* __restrict__ cbe1,
                               const float* __restrict__ cm1, const float* __restrict__ cv1,
                               const float* __restrict__ cg2, const float* __restrict__ cbe2,
                               const float* __restrict__ cm2, const float* __restrict__ cv2,
                               float* __restrict__ sc) {
    int i = threadIdx.x;
    if (i < NLAYERS * CDIM) {
        float s = g[i] * rsqrtf(v[i] + EPS_BN);
        sc[i] = s;
        sc[NLAYERS * CDIM + i] = b[i] - m[i] * s;
    }
    if (i < CDIM) {
        float s = cg1[i] * rsqrtf(cv1[i] + EPS_BN);
        sc[768 + i] = s;
        sc[896 + i] = cbe1[i] - cm1[i] * s;
    }
    if (i < 64) {
        float s = cg2[i] * rsqrtf(cv2[i] + EPS_BN);
        sc[1024 + i] = s;
        sc[1088 + i] = cbe2[i] - cm2[i] * s;
    }
}

// ---------------------------------------------------------------------------
__global__ __launch_bounds__(256) void convert_x(const float* __restrict__ x,
                                                 unsigned short* __restrict__ xb) {
    int i = blockIdx.x * 256 + threadIdx.x;
    const int TOT = N_NODES * CDIM / 4;
    if (i >= TOT) return;
    float4 v = ((const float4*)x)[i];
    ushort4 o;
    o.x = f2bf(v.x); o.y = f2bf(v.y); o.z = f2bf(v.z); o.w = f2bf(v.w);
    ((ushort4*)xb)[i] = o;
}

// wcat[l][n][k]: k<128 -> Wl[l][k][n], k>=128 -> Wr[l][k-128][n]
__global__ __launch_bounds__(256) void convert_w(const float* __restrict__ Wl,
                                                 const float* __restrict__ Wr,
                                                 unsigned short* __restrict__ wcat) {
    int i = blockIdx.x * 256 + threadIdx.x;
    const int TOT = NLAYERS * CDIM * 256;
    if (i >= TOT) return;
    int l = i >> 15;
    int n = (i >> 8) & 127;
    int k = i & 255;
    float w = (k < CDIM) ? Wl[((size_t)l * CDIM + k) * CDIM + n]
                         : Wr[((size_t)l * CDIM + (k - CDIM)) * CDIM + n];
    wcat[i] = f2bf(w);
}

// ---------------------------------------------------------------------------
// Bucketed CSR build.
// Pass A: per-block LDS histogram of dst-buckets -> global bcnt
// ---------------------------------------------------------------------------
__global__ __launch_bounds__(256) void bucket_count(const int* __restrict__ ei,
                                                    int* __restrict__ bcnt) {
    __shared__ int lh[NBUCK];
    int tid = threadIdx.x;
    for (int t = tid; t < NBUCK; t += 256) lh[t] = 0;
    __syncthreads();
    int base = blockIdx.x * EPB;
    int cnt = min(EPB, N_EDGES - base);
    for (int i = tid; i < cnt; i += 256) {
        int d = ei[N_EDGES + base + i];
        atomicAdd(&lh[d / BW], 1);
    }
    __syncthreads();
    for (int t = tid; t < NBUCK; t += 256)
        if (lh[t]) atomicAdd(&bcnt[t], lh[t]);
}

// scan of 512 bucket counts -> bbase (exclusive, [512]=E), init bcur
__global__ __launch_bounds__(512) void scan512(const int* __restrict__ bcnt,
                                               int* __restrict__ bbase,
                                               int* __restrict__ bcur,
                                               int* __restrict__ rowptr) {
    __shared__ int s[NBUCK];
    int t = threadIdx.x;
    s[t] = bcnt[t];
    __syncthreads();
    for (int off = 1; off < NBUCK; off <<= 1) {
        int v = (t >= off) ? s[t - off] : 0;
        __syncthreads();
        s[t] += v;
        __syncthreads();
    }
    int ex = (t == 0) ? 0 : s[t - 1];
    bbase[t] = ex;
    bcur[t] = ex;
    if (t == NBUCK - 1) {
        bbase[NBUCK] = s[NBUCK - 1];
        rowptr[N_NODES] = N_EDGES;
    }
}

// Pass B: stage chunk in LDS, reserve per-bucket global chunks, write
// (src,dst) pairs grouped by bucket into ebuf.
__global__ __launch_bounds__(256) void bucket_fill(const int* __restrict__ ei,
                                                   int* __restrict__ bcur,
                                                   uint2* __restrict__ ebuf) {
    __shared__ int lh[NBUCK];
    __shared__ int gb[NBUCK];
    __shared__ int lc[NBUCK];
    __shared__ uint2 st[EPB];
    int tid = threadIdx.x;
    for (int t = tid; t < NBUCK; t += 256) { lh[t] = 0; lc[t] = 0; }
    __syncthreads();
    int base = blockIdx.x * EPB;
    int cnt = min(EPB, N_EDGES - base);
    for (int i = tid; i < cnt; i += 256) {
        int s = ei[base + i];
        int d = ei[N_EDGES + base + i];
        st[i] = make_uint2((unsigned)s, (unsigned)d);
        atomicAdd(&lh[d / BW], 1);
    }
    __syncthreads();
    for (int t = tid; t < NBUCK; t += 256) {
        int c = lh[t];
        gb[t] = c ? atomicAdd(&bcur[t], c) : 0;
    }
    __syncthreads();
    for (int i = tid; i < cnt; i += 256) {
        uint2 u = st[i];
        int b = (int)u.y / BW;
        int pos = gb[b] + atomicAdd(&lc[b], 1);
        ebuf[pos] = u;
    }
}

// Pass C: one block per bucket; local CSR in LDS; coalesced elist/rowptr out.
__global__ __launch_bounds__(256) void bucket_csr(const uint2* __restrict__ ebuf,
                                                  const int* __restrict__ bbase,
                                                  int* __restrict__ elist,
                                                  int* __restrict__ rowptr) {
    __shared__ uint2 st[CAP];
    __shared__ int out[CAP];
    __shared__ int h[256], sscan[256], pre[256], cur[256];
    int b = blockIdx.x;
    int tid = threadIdx.x;
    int beg = bbase[b];
    int cnt = min(bbase[b + 1] - beg, CAP);
    h[tid] = 0; cur[tid] = 0;
    __syncthreads();
    int nbase = b * BW;
    for (int i = tid; i < cnt; i += 256) {
        uint2 u = ebuf[beg + i];
        st[i] = u;
        atomicAdd(&h[(int)u.y - nbase], 1);
    }
    __syncthreads();
    sscan[tid] = h[tid];
    __syncthreads();
    for (int off = 1; off < 256; off <<= 1) {
        int v = (tid >= off) ? sscan[tid - off] : 0;
        __syncthreads();
        sscan[tid] += v;
        __syncthreads();
    }
    pre[tid] = sscan[tid] - h[tid];   // exclusive prefix
    __syncthreads();
    for (int i = tid; i < cnt; i += 256) {
        uint2 u = st[i];
        int ld = (int)u.y - nbase;
        int pos = pre[ld] + atomicAdd(&cur[ld], 1);
        out[pos] = (int)u.x;
    }
    __syncthreads();
    for (int i = tid; i < cnt; i += 256) elist[beg + i] = out[i];
    int gn = nbase + tid;
    if (tid < BW && gn < N_NODES) rowptr[gn] = beg + pre[tid];
}

// ---------------------------------------------------------------------------
// Fused SAGE layer, bf16 storage, MFMA GEMM:
//   hout = bf16( relu( [mean_agg | hin] @ [Wl;Wr] + bl ) * s + t )
// Gather: 32 lanes/node split into 2 sub-halves (even/odd edges); each lane
// loads uint4 (16 B = 8 channels) -> half the vmem instructions of R5;
// combine via __shfl_xor(16). 2-edge manual unroll for MLP.
// ---------------------------------------------------------------------------
__global__ __launch_bounds__(256, 8) void sage_fused(const int* __restrict__ rowptr,
                                                     const int* __restrict__ elist,
                                                     const unsigned short* __restrict__ hin,
                                                     unsigned short* __restrict__ hout,
                                                     const unsigned short* __restrict__ wcat,
                                                     const float* __restrict__ bl,
                                                     const float* __restrict__ scale,
                                                     const float* __restrict__ shift) {
    __shared__ unsigned short sA[32][LPAD];
    __shared__ unsigned short sH[32][LPAD];

    int row0 = blockIdx.x * 32;
    int tid = threadIdx.x;
    int lane = tid & 31;
    int grp = tid >> 5;       // 8 node-groups
    int sub = lane >> 4;      // 0/1: even/odd edges
    int li  = lane & 15;      // 16 lanes x 8 channels = 128

    for (int rr = 0; rr < 4; ++rr) {
        int r = rr * 8 + grp;
        int node = row0 + r;
        int beg = rowptr[node];
        int end = rowptr[node + 1];
        float a0 = 0.f, a1 = 0.f, a2 = 0.f, a3 = 0.f,
              a4 = 0.f, a5 = 0.f, a6 = 0.f, a7 = 0.f;
        int j = beg + sub;
        for (; j + 2 < end; j += 4) {
            int s0 = elist[j];
            int s1 = elist[j + 2];
            uint4 u0 = *((const uint4*)(hin + (size_t)s0 * CDIM + li * 8));
            uint4 u1 = *((const uint4*)(hin + (size_t)s1 * CDIM + li * 8));
            float lo, hi;
            unpk(u0.x, lo, hi); a0 += lo; a1 += hi;
            unpk(u0.y, lo, hi); a2 += lo; a3 += hi;
            unpk(u0.z, lo, hi); a4 += lo; a5 += hi;
            unpk(u0.w, lo, hi); a6 += lo; a7 += hi;
            unpk(u1.x, lo, hi); a0 += lo; a1 += hi;
            unpk(u1.y, lo, hi); a2 += lo; a3 += hi;
            unpk(u1.z, lo, hi); a4 += lo; a5 += hi;
            unpk(u1.w, lo, hi); a6 += lo; a7 += hi;
        }
        if (j < end) {
            int s0 = elist[j];
            uint4 u0 = *((const uint4*)(hin + (size_t)s0 * CDIM + li * 8));
            float lo, hi;
            unpk(u0.x, lo, hi); a0 += lo; a1 += hi;
            unpk(u0.y, lo, hi); a2 += lo; a3 += hi;
            unpk(u0.z, lo, hi); a4 += lo; a5 += hi;
            unpk(u0.w, lo, hi); a6 += lo; a7 += hi;
        }
        // combine sub-halves (lane L <-> L^16)
        a0 += __shfl_xor(a0, 16); a1 += __shfl_xor(a1, 16);
        a2 += __shfl_xor(a2, 16); a3 += __shfl_xor(a3, 16);
        a4 += __shfl_xor(a4, 16); a5 += __shfl_xor(a5, 16);
        a6 += __shfl_xor(a6, 16); a7 += __shfl_xor(a7, 16);
        if (sub == 0) {
            float rin = 1.0f / fmaxf((float)(end - beg), 1.0f);
            uint4 o;
            o.x = pk2(a0 * rin, a1 * rin);
            o.y = pk2(a2 * rin, a3 * rin);
            o.z = pk2(a4 * rin, a5 * rin);
            o.w = pk2(a6 * rin, a7 * rin);
            *((uint4*)&sA[r][li * 8]) = o;
        }
    }

    // ---- stage own rows (pure bf16 copy) ----
    for (int it = 0; it < 4; ++it) {
        int idx = it * 256 + tid;
        int r = idx >> 5;
        int c4 = idx & 31;
        uint2 u = ((const uint2*)(hin + (size_t)(row0 + r) * CDIM))[c4];
        *((uint2*)&sH[r][c4 * 4]) = u;
    }
    __syncthreads();

    // ---- MFMA GEMM phase ----
    int wave = tid >> 6;
    int wl   = tid & 63;
    int ln16 = wl & 15;
    int quad = wl >> 4;

    floatx4 acc[2][2];
#pragma unroll
    for (int mt = 0; mt < 2; ++mt)
#pragma unroll
        for (int nt = 0; nt < 2; ++nt) acc[mt][nt] = (floatx4)0.0f;

    const unsigned short* wbase = wcat + ((size_t)(wave * 32 + ln16) * 256 + quad * 8);

#pragma unroll
    for (int kb = 0; kb < 8; ++kb) {
        int koff = (kb & 3) * 32 + quad * 8;
        const unsigned short* sbuf = (kb < 4) ? &sA[0][0] : &sH[0][0];
        short8 a0 = *((const short8*)(sbuf + (ln16)      * LPAD + koff));
        short8 a1 = *((const short8*)(sbuf + (ln16 + 16) * LPAD + koff));
        short8 b0 = *((const short8*)(wbase + kb * 32));
        short8 b1 = *((const short8*)(wbase + 16 * 256 + kb * 32));
        acc[0][0] = __builtin_amdgcn_mfma_f32_16x16x32_bf16(a0, b0, acc[0][0], 0, 0, 0);
        acc[1][0] = __builtin_amdgcn_mfma_f32_16x16x32_bf16(a1, b0, acc[1][0], 0, 0, 0);
        acc[0][1] = __builtin_amdgcn_mfma_f32_16x16x32_bf16(a0, b1, acc[0][1], 0, 0, 0);
        acc[1][1] = __builtin_amdgcn_mfma_f32_16x16x32_bf16(a1, b1, acc[1][1], 0, 0, 0);
    }

    // ---- epilogue: C layout col=lane&15, row=quad*4+reg ----
#pragma unroll
    for (int nt = 0; nt < 2; ++nt) {
        int col = wave * 32 + nt * 16 + ln16;
        float bb = bl[col];
        float ss = scale[col];
        float tt = shift[col];
#pragma unroll
        for (int mt = 0; mt < 2; ++mt) {
#pragma unroll
            for (int r = 0; r < 4; ++r) {
                int row = row0 + mt * 16 + quad * 4 + r;
                float v = fmaxf(acc[mt][nt][r] + bb, 0.0f) * ss + tt;
                hout[(size_t)row * CDIM + col] = f2bf(v);
            }
        }
    }
}

// ---------------------------------------------------------------------------
// Head GEMM 1: bf16 input, fp32 weights/accum
// ---------------------------------------------------------------------------
__global__ __launch_bounds__(256) void head_gemm1(const unsigned short* __restrict__ hin,
                                                  const float* __restrict__ W,
                                                  const float* __restrict__ bias,
                                                  const float* __restrict__ scale,
                                                  const float* __restrict__ shift,
                                                  float* __restrict__ out) {
    __shared__ float sH[32][CDIM + 4];
    int row0 = blockIdx.x * 32;
    int tid = threadIdx.x;

    for (int it = 0; it < 4; ++it) {
        int idx = it * 256 + tid;
        int r = idx >> 5;
        int c4 = idx & 31;
        int row = row0 + r;
        float4 f = make_float4(0.f, 0.f, 0.f, 0.f);
        if (row < BATCH) {
            uint2 u = ((const uint2*)(hin + (size_t)row * CDIM))[c4];
            unpk(u.x, f.x, f.y); unpk(u.y, f.z, f.w);
        }
        *((float4*)&sH[r][c4 * 4]) = f;
    }
    __syncthreads();

    int cg = tid & 31;
    int rg = tid >> 5;
    int c0 = cg * 4;
    int r0 = rg * 4;

    float acc[4][4];
#pragma unroll
    for (int r = 0; r < 4; ++r)
#pragma unroll
        for (int c = 0; c < 4; ++c) acc[r][c] = 0.0f;

    for (int k = 0; k < CDIM; ++k) {
        float4 w = ((const float4*)(W + (size_t)k * CDIM))[cg];
#pragma unroll
        for (int r = 0; r < 4; ++r) {
            float hh = sH[r0 + r][k];
            acc[r][0] += hh * w.x;
            acc[r][1] += hh * w.y;
            acc[r][2] += hh * w.z;
            acc[r][3] += hh * w.w;
        }
    }

    float4 bb = *((const float4*)(bias + c0));
    float4 ss = *((const float4*)(scale + c0));
    float4 tt = *((const float4*)(shift + c0));
#pragma unroll
    for (int r = 0; r < 4; ++r) {
        int row = row0 + r0 + r;
        if (row >= BATCH) continue;
        float4 o;
        o.x = fmaxf((acc[r][0] + bb.x) * ss.x + tt.x, 0.0f);
        o.y = fmaxf((acc[r][1] + bb.y) * ss.y + tt.y, 0.0f);
        o.z = fmaxf((acc[r][2] + bb.z) * ss.z + tt.z, 0.0f);
        o.w = fmaxf((acc[r][3] + bb.w) * ss.w + tt.w, 0.0f);
        ((float4*)(out + (size_t)row * CDIM))[cg] = o;
    }
}

// ---------------------------------------------------------------------------
// Head GEMM 2: 128 -> 64 fp32
// ---------------------------------------------------------------------------
__global__ __launch_bounds__(256) void head_gemm2(const float* __restrict__ hin,
                                                  const float* __restrict__ W,
                                                  const float* __restrict__ bias,
                                                  const float* __restrict__ scale,
                                                  const float* __restrict__ shift,
                                                  float* __restrict__ out) {
    __shared__ float sH[64][CDIM + 4];
    int row0 = blockIdx.x * 64;
    int tid = threadIdx.x;

    for (int it = 0; it < 8; ++it) {
        int idx = it * 256 + tid;
        int r = idx >> 5;
        int c4 = idx & 31;
        int row = row0 + r;
        float4 hv = make_float4(0.f, 0.f, 0.f, 0.f);
        if (row < BATCH) hv = ((const float4*)(hin + (size_t)row * CDIM))[c4];
        *((float4*)&sH[r][c4 * 4]) = hv;
    }
    __syncthreads();

    int cg = tid & 15;
    int rg = tid >> 4;
    int c0 = cg * 4;
    int r0 = rg * 4;

    float acc[4][4];
#pragma unroll
    for (int r = 0; r < 4; ++r)
#pragma unroll
        for (int c = 0; c < 4; ++c) acc[r][c] = 0.0f;

    for (int k = 0; k < CDIM; ++k) {
        float4 w = ((const float4*)(W + (size_t)k * 64))[cg];
#pragma unroll
        for (int r = 0; r < 4; ++r) {
            float hh = sH[r0 + r][k];
            acc[r][0] += hh * w.x;
            acc[r][1] += hh * w.y;
            acc[r][2] += hh * w.z;
            acc[r][3] += hh * w.w;
        }
    }

    float4 bb = *((const float4*)(bias + c0));
    float4 ss = *((const float4*)(scale + c0));
    float4 tt = *((const float4*)(shift + c0));
#pragma unroll
    for (int r = 0; r < 4; ++r) {
        int row = row0 + r0 + r;
        if (row >= BATCH) continue;
        float4 o;
        o.x = fmaxf((acc[r][0] + bb.x) * ss.x + tt.x, 0.0f);
        o.y = fmaxf((acc[r][1] + bb.y) * ss.y + tt.y, 0.0f);
        o.z = fmaxf((acc[r][2] + bb.z) * ss.z + tt.z, 0.0f);
        o.w = fmaxf((acc[r][3] + bb.w) * ss.w + tt.w, 0.0f);
        ((float4*)(out + (size_t)row * 64))[cg] = o;
    }
}

// ---------------------------------------------------------------------------
__global__ __launch_bounds__(256) void head_final(const float* __restrict__ t2,
                                                  const float* __restrict__ W3,
                                                  const float* __restrict__ b3,
                                                  float* __restrict__ out) {
    __shared__ float w[64];
    if (threadIdx.x < 64) w[threadIdx.x] = W3[threadIdx.x];
    __syncthreads();
    int i = blockIdx.x * 256 + threadIdx.x;
    if (i >= BATCH) return;
    const float4* r = (const float4*)(t2 + (size_t)i * 64);
    float acc = b3[0];
#pragma unroll
    for (int k = 0; k < 16; ++k) {
        float4 v = r[k];
        acc += v.x * w[4 * k] + v.y * w[4 * k + 1] + v.z * w[4 * k + 2] + v.w * w[4 * k + 3];
    }
    out[i] = acc;
}

// ---------------------------------------------------------------------------
extern "C" void kernel_launch(void* const* d_in, const int* in_sizes, int n_in,
                              void* d_out, int out_size, void* d_ws, size_t ws_size,
                              hipStream_t stream) {
    const float* x    = (const float*)d_in[0];
    const int*   ei   = (const int*)d_in[1];
    const float* Wl   = (const float*)d_in[3];
    const float* bl   = (const float*)d_in[4];
    const float* Wr   = (const float*)d_in[5];
    const float* bn_g = (const float*)d_in[6];
    const float* bn_b = (const float*)d_in[7];
    const float* bn_m = (const float*)d_in[8];
    const float* bn_v = (const float*)d_in[9];
    const float* cW1  = (const float*)d_in[10];
    const float* cb1  = (const float*)d_in[11];
    const float* cg1  = (const float*)d_in[12];
    const float* cbe1 = (const float*)d_in[13];
    const float* cm1  = (const float*)d_in[14];
    const float* cv1  = (const float*)d_in[15];
    const float* cW2  = (const float*)d_in[16];
    const float* cb2  = (const float*)d_in[17];
    const float* cg2  = (const float*)d_in[18];
    const float* cbe2 = (const float*)d_in[19];
    const float* cm2  = (const float*)d_in[20];
    const float* cv2  = (const float*)d_in[21];
    const float* cW3  = (const float*)d_in[22];
    const float* cb3  = (const float*)d_in[23];

    // Workspace layout (float units):
    float* ws  = (float*)d_ws;
    unsigned short* xb  = (unsigned short*)ws;                    // N*C bf16
    unsigned short* hb0 = (unsigned short*)(ws + 6400000);        // N*C bf16
    unsigned short* hb1 = (unsigned short*)(ws + 12800000);       // N*C bf16
    float* sc   = ws + 19200000;                                  // 1152
    int* rowptr = (int*)(sc + 1152);                              // N+1
    int* bcnt   = rowptr + (N_NODES + 1);                         // 512
    int* bbase  = bcnt + NBUCK;                                   // 513
    int* bcur   = bbase + NBUCK + 1;                              // 512
    int* elist  = bcur + NBUCK;                                   // E
    uint2* ebuf = (uint2*)(elist + N_EDGES);                      // E pairs
    unsigned short* wcat = (unsigned short*)(ebuf + N_EDGES);     // 3*128*256
    float* t1   = (float*)xb;                                     // 50k*128 fp32
    float* t2   = (float*)hb1;                                    // 50k*64 fp32

    fold_bn_kernel<<<1, 384, 0, stream>>>(bn_g, bn_b, bn_m, bn_v,
                                          cg1, cbe1, cm1, cv1,
                                          cg2, cbe2, cm2, cv2, sc);

    convert_x<<<(N_NODES * CDIM / 4 + 255) / 256, 256, 0, stream>>>(x, xb);
    convert_w<<<(NLAYERS * CDIM * 256 + 255) / 256, 256, 0, stream>>>(Wl, Wr, wcat);

    // ---- bucketed CSR build ----
    hipMemsetAsync(bcnt, 0, NBUCK * sizeof(int), stream);
    bucket_count<<<NEB, 256, 0, stream>>>(ei, bcnt);
    scan512<<<1, NBUCK, 0, stream>>>(bcnt, bbase, bcur, rowptr);
    bucket_fill<<<NEB, 256, 0, stream>>>(ei, bcur, ebuf);
    bucket_csr<<<NBUCK, 256, 0, stream>>>(ebuf, bbase, elist, rowptr);

    // ---- 3 fused SAGE layers (bf16 ping-pong: xb->hb0->hb1->hb0) ----
    const unsigned short* lin[NLAYERS] = { xb, hb0, hb1 };
    unsigned short* lout[NLAYERS]      = { hb0, hb1, hb0 };
    for (int l = 0; l < NLAYERS; ++l) {
        sage_fused<<<N_NODES / 32, 256, 0, stream>>>(
            rowptr, elist, lin[l], lout[l],
            wcat + (size_t)l * CDIM * 256,
            bl + (size_t)l * CDIM,
            sc + l * CDIM, sc + 384 + l * CDIM);
    }

    // ---- MLP head on first BATCH rows (input: hb0 bf16) ----
    head_gemm1<<<(BATCH + 31) / 32, 256, 0, stream>>>(hb0, cW1, cb1, sc + 768, sc + 896, t1);
    head_gemm2<<<(BATCH + 63) / 64, 256, 0, stream>>>(t1, cW2, cb2, sc + 1024, sc + 1088, t2);
    head_final<<<(BATCH + 255) / 256, 256, 0, stream>>>(t2, cW3, cb3, (float*)d_out);
}

// Round 7
// 495.840 us; speedup vs baseline: 17.9325x; 1.0822x over previous
//
#include <hip/hip_runtime.h>

#define N_NODES 100000
#define N_EDGES 1600000
#define CDIM    128
#define BATCH   50000
#define NLAYERS 3
#define EPS_BN  1e-5f
#define LPAD    136   // LDS row stride in bf16 elems (272 B)

#define NBUCK   512
#define BW      196   // 512*196 = 100352 >= N_NODES
#define EPB     4096  // edges per block, passes A/B
#define NEB     ((N_EDGES + EPB - 1) / EPB)   // 391
#define CAP     4608  // max edges per bucket (mean 3125)

typedef __attribute__((ext_vector_type(8))) short short8;   // 8 bf16
typedef __attribute__((ext_vector_type(4))) float floatx4;  // MFMA acc

__device__ __forceinline__ unsigned short f2bf(float f) {
    unsigned int u = __float_as_uint(f);
    u = u + 0x7FFFu + ((u >> 16) & 1u);   // RTNE
    return (unsigned short)(u >> 16);
}
__device__ __forceinline__ void unpk(unsigned int u, float& lo, float& hi) {
    lo = __uint_as_float(u << 16);
    hi = __uint_as_float(u & 0xFFFF0000u);
}
__device__ __forceinline__ unsigned int pk2(float lo, float hi) {
    return (unsigned int)f2bf(lo) | ((unsigned int)f2bf(hi) << 16);
}

// ---------------------------------------------------------------------------
// Fold BN params. sc[]: [0..383] layer scale, [384..767] layer shift,
// [768..895]/[896..1023] head1 s/t, [1024..1087]/[1088..1151] head2 s/t
// ---------------------------------------------------------------------------
__global__ void fold_bn_kernel(const float* __restrict__ g, const float* __restrict__ b,
                               const float* __restrict__ m, const float* __restrict__ v,
                               const float* __restrict__ cg1, const float* __restrict__ cbe1,
                               const float* __restrict__ cm1, const float* __restrict__ cv1,
                               const float* __restrict__ cg2, const float* __restrict__ cbe2,
                               const float* __restrict__ cm2, const float* __restrict__ cv2,
                               float* __restrict__ sc) {
    int i = threadIdx.x;
    if (i < NLAYERS * CDIM) {
        float s = g[i] * rsqrtf(v[i] + EPS_BN);
        sc[i] = s;
        sc[NLAYERS * CDIM + i] = b[i] - m[i] * s;
    }
    if (i < CDIM) {
        float s = cg1[i] * rsqrtf(cv1[i] + EPS_BN);
        sc[768 + i] = s;
        sc[896 + i] = cbe1[i] - cm1[i] * s;
    }
    if (i < 64) {
        float s = cg2[i] * rsqrtf(cv2[i] + EPS_BN);
        sc[1024 + i] = s;
        sc[1088 + i] = cbe2[i] - cm2[i] * s;
    }
}

// ---------------------------------------------------------------------------
__global__ __launch_bounds__(256) void convert_x(const float* __restrict__ x,
                                                 unsigned short* __restrict__ xb) {
    int i = blockIdx.x * 256 + threadIdx.x;
    const int TOT = N_NODES * CDIM / 4;
    if (i >= TOT) return;
    float4 v = ((const float4*)x)[i];
    ushort4 o;
    o.x = f2bf(v.x); o.y = f2bf(v.y); o.z = f2bf(v.z); o.w = f2bf(v.w);
    ((ushort4*)xb)[i] = o;
}

// wcat[l][n][k]: k<128 -> Wl[l][k][n], k>=128 -> Wr[l][k-128][n]
__global__ __launch_bounds__(256) void convert_w(const float* __restrict__ Wl,
                                                 const float* __restrict__ Wr,
                                                 unsigned short* __restrict__ wcat) {
    int i = blockIdx.x * 256 + threadIdx.x;
    const int TOT = NLAYERS * CDIM * 256;
    if (i >= TOT) return;
    int l = i >> 15;
    int n = (i >> 8) & 127;
    int k = i & 255;
    float w = (k < CDIM) ? Wl[((size_t)l * CDIM + k) * CDIM + n]
                         : Wr[((size_t)l * CDIM + (k - CDIM)) * CDIM + n];
    wcat[i] = f2bf(w);
}

// ---------------------------------------------------------------------------
// Bucketed CSR build (passes A/B/C) — see R6 notes; coalesced writes.
// ---------------------------------------------------------------------------
__global__ __launch_bounds__(256) void bucket_count(const int* __restrict__ ei,
                                                    int* __restrict__ bcnt) {
    __shared__ int lh[NBUCK];
    int tid = threadIdx.x;
    for (int t = tid; t < NBUCK; t += 256) lh[t] = 0;
    __syncthreads();
    int base = blockIdx.x * EPB;
    int cnt = min(EPB, N_EDGES - base);
    for (int i = tid; i < cnt; i += 256) {
        int d = ei[N_EDGES + base + i];
        atomicAdd(&lh[d / BW], 1);
    }
    __syncthreads();
    for (int t = tid; t < NBUCK; t += 256)
        if (lh[t]) atomicAdd(&bcnt[t], lh[t]);
}

__global__ __launch_bounds__(512) void scan512(const int* __restrict__ bcnt,
                                               int* __restrict__ bbase,
                                               int* __restrict__ bcur,
                                               int* __restrict__ rowptr) {
    __shared__ int s[NBUCK];
    int t = threadIdx.x;
    s[t] = bcnt[t];
    __syncthreads();
    for (int off = 1; off < NBUCK; off <<= 1) {
        int v = (t >= off) ? s[t - off] : 0;
        __syncthreads();
        s[t] += v;
        __syncthreads();
    }
    int ex = (t == 0) ? 0 : s[t - 1];
    bbase[t] = ex;
    bcur[t] = ex;
    if (t == NBUCK - 1) {
        bbase[NBUCK] = s[NBUCK - 1];
        rowptr[N_NODES] = N_EDGES;
    }
}

__global__ __launch_bounds__(256) void bucket_fill(const int* __restrict__ ei,
                                                   int* __restrict__ bcur,
                                                   uint2* __restrict__ ebuf) {
    __shared__ int lh[NBUCK];
    __shared__ int gb[NBUCK];
    __shared__ int lc[NBUCK];
    __shared__ uint2 st[EPB];
    int tid = threadIdx.x;
    for (int t = tid; t < NBUCK; t += 256) { lh[t] = 0; lc[t] = 0; }
    __syncthreads();
    int base = blockIdx.x * EPB;
    int cnt = min(EPB, N_EDGES - base);
    for (int i = tid; i < cnt; i += 256) {
        int s = ei[base + i];
        int d = ei[N_EDGES + base + i];
        st[i] = make_uint2((unsigned)s, (unsigned)d);
        atomicAdd(&lh[d / BW], 1);
    }
    __syncthreads();
    for (int t = tid; t < NBUCK; t += 256) {
        int c = lh[t];
        gb[t] = c ? atomicAdd(&bcur[t], c) : 0;
    }
    __syncthreads();
    for (int i = tid; i < cnt; i += 256) {
        uint2 u = st[i];
        int b = (int)u.y / BW;
        int pos = gb[b] + atomicAdd(&lc[b], 1);
        ebuf[pos] = u;
    }
}

__global__ __launch_bounds__(256) void bucket_csr(const uint2* __restrict__ ebuf,
                                                  const int* __restrict__ bbase,
                                                  int* __restrict__ elist,
                                                  int* __restrict__ rowptr) {
    __shared__ uint2 st[CAP];
    __shared__ int out[CAP];
    __shared__ int h[256], sscan[256], pre[256], cur[256];
    int b = blockIdx.x;
    int tid = threadIdx.x;
    int beg = bbase[b];
    int cnt = min(bbase[b + 1] - beg, CAP);
    h[tid] = 0; cur[tid] = 0;
    __syncthreads();
    int nbase = b * BW;
    for (int i = tid; i < cnt; i += 256) {
        uint2 u = ebuf[beg + i];
        st[i] = u;
        atomicAdd(&h[(int)u.y - nbase], 1);
    }
    __syncthreads();
    sscan[tid] = h[tid];
    __syncthreads();
    for (int off = 1; off < 256; off <<= 1) {
        int v = (tid >= off) ? sscan[tid - off] : 0;
        __syncthreads();
        sscan[tid] += v;
        __syncthreads();
    }
    pre[tid] = sscan[tid] - h[tid];
    __syncthreads();
    for (int i = tid; i < cnt; i += 256) {
        uint2 u = st[i];
        int ld = (int)u.y - nbase;
        int pos = pre[ld] + atomicAdd(&cur[ld], 1);
        out[pos] = (int)u.x;
    }
    __syncthreads();
    for (int i = tid; i < cnt; i += 256) elist[beg + i] = out[i];
    int gn = nbase + tid;
    if (tid < BW && gn < N_NODES) rowptr[gn] = beg + pre[tid];
}

// ---------------------------------------------------------------------------
// Fused SAGE layer, bf16 storage, MFMA GEMM.
// Gather: per 32-lane group, 2 sub-halves of 16 lanes; sub s takes 4-edge
// chunks [beg+8k+4s, +4) -> 4 independent uint4 row-loads per iteration
// (8 outstanding rows per group — latency hiding).
// Epilogue: C staged through LDS, stored coalesced 16 B/lane.
// ---------------------------------------------------------------------------
__global__ __launch_bounds__(256, 8) void sage_fused(const int* __restrict__ rowptr,
                                                     const int* __restrict__ elist,
                                                     const unsigned short* __restrict__ hin,
                                                     unsigned short* __restrict__ hout,
                                                     const unsigned short* __restrict__ wcat,
                                                     const float* __restrict__ bl,
                                                     const float* __restrict__ scale,
                                                     const float* __restrict__ shift) {
    __shared__ unsigned short sA[32][LPAD];
    __shared__ unsigned short sH[32][LPAD];

    int row0 = blockIdx.x * 32;
    int tid = threadIdx.x;
    int lane = tid & 31;
    int grp = tid >> 5;       // 8 node-groups
    int sub = lane >> 4;      // 0/1: chunk parity
    int li  = lane & 15;      // 16 lanes x 8 channels = 128

    for (int rr = 0; rr < 4; ++rr) {
        int r = rr * 8 + grp;
        int node = row0 + r;
        int beg = rowptr[node];
        int end = rowptr[node + 1];
        float a0 = 0.f, a1 = 0.f, a2 = 0.f, a3 = 0.f,
              a4 = 0.f, a5 = 0.f, a6 = 0.f, a7 = 0.f;
        int j = beg + sub * 4;
        for (; j + 4 <= end; j += 8) {
            int s0 = elist[j], s1 = elist[j + 1], s2 = elist[j + 2], s3 = elist[j + 3];
            uint4 u0 = *((const uint4*)(hin + (size_t)s0 * CDIM + li * 8));
            uint4 u1 = *((const uint4*)(hin + (size_t)s1 * CDIM + li * 8));
            uint4 u2 = *((const uint4*)(hin + (size_t)s2 * CDIM + li * 8));
            uint4 u3 = *((const uint4*)(hin + (size_t)s3 * CDIM + li * 8));
            float lo, hi;
            unpk(u0.x, lo, hi); a0 += lo; a1 += hi;
            unpk(u0.y, lo, hi); a2 += lo; a3 += hi;
            unpk(u0.z, lo, hi); a4 += lo; a5 += hi;
            unpk(u0.w, lo, hi); a6 += lo; a7 += hi;
            unpk(u1.x, lo, hi); a0 += lo; a1 += hi;
            unpk(u1.y, lo, hi); a2 += lo; a3 += hi;
            unpk(u1.z, lo, hi); a4 += lo; a5 += hi;
            unpk(u1.w, lo, hi); a6 += lo; a7 += hi;
            unpk(u2.x, lo, hi); a0 += lo; a1 += hi;
            unpk(u2.y, lo, hi); a2 += lo; a3 += hi;
            unpk(u2.z, lo, hi); a4 += lo; a5 += hi;
            unpk(u2.w, lo, hi); a6 += lo; a7 += hi;
            unpk(u3.x, lo, hi); a0 += lo; a1 += hi;
            unpk(u3.y, lo, hi); a2 += lo; a3 += hi;
            unpk(u3.z, lo, hi); a4 += lo; a5 += hi;
            unpk(u3.w, lo, hi); a6 += lo; a7 += hi;
        }
        for (; j < end; ++j) {
            int s0 = elist[j];
            uint4 u0 = *((const uint4*)(hin + (size_t)s0 * CDIM + li * 8));
            float lo, hi;
            unpk(u0.x, lo, hi); a0 += lo; a1 += hi;
            unpk(u0.y, lo, hi); a2 += lo; a3 += hi;
            unpk(u0.z, lo, hi); a4 += lo; a5 += hi;
            unpk(u0.w, lo, hi); a6 += lo; a7 += hi;
        }
        // combine sub-halves (lane L <-> L^16)
        a0 += __shfl_xor(a0, 16); a1 += __shfl_xor(a1, 16);
        a2 += __shfl_xor(a2, 16); a3 += __shfl_xor(a3, 16);
        a4 += __shfl_xor(a4, 16); a5 += __shfl_xor(a5, 16);
        a6 += __shfl_xor(a6, 16); a7 += __shfl_xor(a7, 16);
        if (sub == 0) {
            float rin = 1.0f / fmaxf((float)(end - beg), 1.0f);
            uint4 o;
            o.x = pk2(a0 * rin, a1 * rin);
            o.y = pk2(a2 * rin, a3 * rin);
            o.z = pk2(a4 * rin, a5 * rin);
            o.w = pk2(a6 * rin, a7 * rin);
            *((uint4*)&sA[r][li * 8]) = o;
        }
    }

    // ---- stage own rows (pure bf16 copy) ----
    for (int it = 0; it < 4; ++it) {
        int idx = it * 256 + tid;
        int r = idx >> 5;
        int c4 = idx & 31;
        uint2 u = ((const uint2*)(hin + (size_t)(row0 + r) * CDIM))[c4];
        *((uint2*)&sH[r][c4 * 4]) = u;
    }
    __syncthreads();

    // ---- MFMA GEMM phase ----
    int wave = tid >> 6;
    int wl   = tid & 63;
    int ln16 = wl & 15;
    int quad = wl >> 4;

    floatx4 acc[2][2];
#pragma unroll
    for (int mt = 0; mt < 2; ++mt)
#pragma unroll
        for (int nt = 0; nt < 2; ++nt) acc[mt][nt] = (floatx4)0.0f;

    const unsigned short* wbase = wcat + ((size_t)(wave * 32 + ln16) * 256 + quad * 8);

#pragma unroll
    for (int kb = 0; kb < 8; ++kb) {
        int koff = (kb & 3) * 32 + quad * 8;
        const unsigned short* sbuf = (kb < 4) ? &sA[0][0] : &sH[0][0];
        short8 a0 = *((const short8*)(sbuf + (ln16)      * LPAD + koff));
        short8 a1 = *((const short8*)(sbuf + (ln16 + 16) * LPAD + koff));
        short8 b0 = *((const short8*)(wbase + kb * 32));
        short8 b1 = *((const short8*)(wbase + 16 * 256 + kb * 32));
        acc[0][0] = __builtin_amdgcn_mfma_f32_16x16x32_bf16(a0, b0, acc[0][0], 0, 0, 0);
        acc[1][0] = __builtin_amdgcn_mfma_f32_16x16x32_bf16(a1, b0, acc[1][0], 0, 0, 0);
        acc[0][1] = __builtin_amdgcn_mfma_f32_16x16x32_bf16(a0, b1, acc[0][1], 0, 0, 0);
        acc[1][1] = __builtin_amdgcn_mfma_f32_16x16x32_bf16(a1, b1, acc[1][1], 0, 0, 0);
    }

    // ---- epilogue: bn+relu, stage C in LDS (reuse sA), coalesced store ----
    __syncthreads();   // all sA/sH reads complete before overwrite
#pragma unroll
    for (int nt = 0; nt < 2; ++nt) {
        int col = wave * 32 + nt * 16 + ln16;
        float bb = bl[col];
        float ss = scale[col];
        float tt = shift[col];
#pragma unroll
        for (int mt = 0; mt < 2; ++mt) {
#pragma unroll
            for (int r = 0; r < 4; ++r) {
                float v = fmaxf(acc[mt][nt][r] + bb, 0.0f) * ss + tt;
                sA[mt * 16 + quad * 4 + r][col] = f2bf(v);
            }
        }
    }
    __syncthreads();
#pragma unroll
    for (int it = 0; it < 2; ++it) {
        int idx = it * 256 + tid;   // 0..511: 32 rows x 16 uint4
        int r = idx >> 4;
        int c = idx & 15;
        uint4 u = *((const uint4*)&sA[r][c * 8]);
        *((uint4*)(hout + (size_t)(row0 + r) * CDIM + c * 8)) = u;
    }
}

// ---------------------------------------------------------------------------
// Head GEMM 1: bf16 input, fp32 weights/accum
// ---------------------------------------------------------------------------
__global__ __launch_bounds__(256) void head_gemm1(const unsigned short* __restrict__ hin,
                                                  const float* __restrict__ W,
                                                  const float* __restrict__ bias,
                                                  const float* __restrict__ scale,
                                                  const float* __restrict__ shift,
                                                  float* __restrict__ out) {
    __shared__ float sH[32][CDIM + 4];
    int row0 = blockIdx.x * 32;
    int tid = threadIdx.x;

    for (int it = 0; it < 4; ++it) {
        int idx = it * 256 + tid;
        int r = idx >> 5;
        int c4 = idx & 31;
        int row = row0 + r;
        float4 f = make_float4(0.f, 0.f, 0.f, 0.f);
        if (row < BATCH) {
            uint2 u = ((const uint2*)(hin + (size_t)row * CDIM))[c4];
            unpk(u.x, f.x, f.y); unpk(u.y, f.z, f.w);
        }
        *((float4*)&sH[r][c4 * 4]) = f;
    }
    __syncthreads();

    int cg = tid & 31;
    int rg = tid >> 5;
    int c0 = cg * 4;
    int r0 = rg * 4;

    float acc[4][4];
#pragma unroll
    for (int r = 0; r < 4; ++r)
#pragma unroll
        for (int c = 0; c < 4; ++c) acc[r][c] = 0.0f;

    for (int k = 0; k < CDIM; ++k) {
        float4 w = ((const float4*)(W + (size_t)k * CDIM))[cg];
#pragma unroll
        for (int r = 0; r < 4; ++r) {
            float hh = sH[r0 + r][k];
            acc[r][0] += hh * w.x;
            acc[r][1] += hh * w.y;
            acc[r][2] += hh * w.z;
            acc[r][3] += hh * w.w;
        }
    }

    float4 bb = *((const float4*)(bias + c0));
    float4 ss = *((const float4*)(scale + c0));
    float4 tt = *((const float4*)(shift + c0));
#pragma unroll
    for (int r = 0; r < 4; ++r) {
        int row = row0 + r0 + r;
        if (row >= BATCH) continue;
        float4 o;
        o.x = fmaxf((acc[r][0] + bb.x) * ss.x + tt.x, 0.0f);
        o.y = fmaxf((acc[r][1] + bb.y) * ss.y + tt.y, 0.0f);
        o.z = fmaxf((acc[r][2] + bb.z) * ss.z + tt.z, 0.0f);
        o.w = fmaxf((acc[r][3] + bb.w) * ss.w + tt.w, 0.0f);
        ((float4*)(out + (size_t)row * CDIM))[cg] = o;
    }
}

// ---------------------------------------------------------------------------
// Head GEMM 2: 128 -> 64 fp32
// ---------------------------------------------------------------------------
__global__ __launch_bounds__(256) void head_gemm2(const float* __restrict__ hin,
                                                  const float* __restrict__ W,
                                                  const float* __restrict__ bias,
                                                  const float* __restrict__ scale,
                                                  const float* __restrict__ shift,
                                                  float* __restrict__ out) {
    __shared__ float sH[64][CDIM + 4];
    int row0 = blockIdx.x * 64;
    int tid = threadIdx.x;

    for (int it = 0; it < 8; ++it) {
        int idx = it * 256 + tid;
        int r = idx >> 5;
        int c4 = idx & 31;
        int row = row0 + r;
        float4 hv = make_float4(0.f, 0.f, 0.f, 0.f);
        if (row < BATCH) hv = ((const float4*)(hin + (size_t)row * CDIM))[c4];
        *((float4*)&sH[r][c4 * 4]) = hv;
    }
    __syncthreads();

    int cg = tid & 15;
    int rg = tid >> 4;
    int c0 = cg * 4;
    int r0 = rg * 4;

    float acc[4][4];
#pragma unroll
    for (int r = 0; r < 4; ++r)
#pragma unroll
        for (int c = 0; c < 4; ++c) acc[r][c] = 0.0f;

    for (int k = 0; k < CDIM; ++k) {
        float4 w = ((const float4*)(W + (size_t)k * 64))[cg];
#pragma unroll
        for (int r = 0; r < 4; ++r) {
            float hh = sH[r0 + r][k];
            acc[r][0] += hh * w.x;
            acc[r][1] += hh * w.y;
            acc[r][2] += hh * w.z;
            acc[r][3] += hh * w.w;
        }
    }

    float4 bb = *((const float4*)(bias + c0));
    float4 ss = *((const float4*)(scale + c0));
    float4 tt = *((const float4*)(shift + c0));
#pragma unroll
    for (int r = 0; r < 4; ++r) {
        int row = row0 + r0 + r;
        if (row >= BATCH) continue;
        float4 o;
        o.x = fmaxf((acc[r][0] + bb.x) * ss.x + tt.x, 0.0f);
        o.y = fmaxf((acc[r][1] + bb.y) * ss.y + tt.y, 0.0f);
        o.z = fmaxf((acc[r][2] + bb.z) * ss.z + tt.z, 0.0f);
        o.w = fmaxf((acc[r][3] + bb.w) * ss.w + tt.w, 0.0f);
        ((float4*)(out + (size_t)row * 64))[cg] = o;
    }
}

// ---------------------------------------------------------------------------
__global__ __launch_bounds__(256) void head_final(const float* __restrict__ t2,
                                                  const float* __restrict__ W3,
                                                  const float* __restrict__ b3,
                                                  float* __restrict__ out) {
    __shared__ float w[64];
    if (threadIdx.x < 64) w[threadIdx.x] = W3[threadIdx.x];
    __syncthreads();
    int i = blockIdx.x * 256 + threadIdx.x;
    if (i >= BATCH) return;
    const float4* r = (const float4*)(t2 + (size_t)i * 64);
    float acc = b3[0];
#pragma unroll
    for (int k = 0; k < 16; ++k) {
        float4 v = r[k];
        acc += v.x * w[4 * k] + v.y * w[4 * k + 1] + v.z * w[4 * k + 2] + v.w * w[4 * k + 3];
    }
    out[i] = acc;
}

// ---------------------------------------------------------------------------
extern "C" void kernel_launch(void* const* d_in, const int* in_sizes, int n_in,
                              void* d_out, int out_size, void* d_ws, size_t ws_size,
                              hipStream_t stream) {
    const float* x    = (const float*)d_in[0];
    const int*   ei   = (const int*)d_in[1];
    const float* Wl   = (const float*)d_in[3];
    const float* bl   = (const float*)d_in[4];
    const float* Wr   = (const float*)d_in[5];
    const float* bn_g = (const float*)d_in[6];
    const float* bn_b = (const float*)d_in[7];
    const float* bn_m = (const float*)d_in[8];
    const float* bn_v = (const float*)d_in[9];
    const float* cW1  = (const float*)d_in[10];
    const float* cb1  = (const float*)d_in[11];
    const float* cg1  = (const float*)d_in[12];
    const float* cbe1 = (const float*)d_in[13];
    const float* cm1  = (const float*)d_in[14];
    const float* cv1  = (const float*)d_in[15];
    const float* cW2  = (const float*)d_in[16];
    const float* cb2  = (const float*)d_in[17];
    const float* cg2  = (const float*)d_in[18];
    const float* cbe2 = (const float*)d_in[19];
    const float* cm2  = (const float*)d_in[20];
    const float* cv2  = (const float*)d_in[21];
    const float* cW3  = (const float*)d_in[22];
    const float* cb3  = (const float*)d_in[23];

    // Workspace layout (float units):
    float* ws  = (float*)d_ws;
    unsigned short* xb  = (unsigned short*)ws;                    // N*C bf16
    unsigned short* hb0 = (unsigned short*)(ws + 6400000);        // N*C bf16
    unsigned short* hb1 = (unsigned short*)(ws + 12800000);       // N*C bf16
    float* sc   = ws + 19200000;                                  // 1152
    int* rowptr = (int*)(sc + 1152);                              // N+1
    int* bcnt   = rowptr + (N_NODES + 1);                         // 512
    int* bbase  = bcnt + NBUCK;                                   // 513
    int* bcur   = bbase + NBUCK + 1;                              // 512
    int* elist  = bcur + NBUCK;                                   // E
    uint2* ebuf = (uint2*)(elist + N_EDGES);                      // E pairs
    unsigned short* wcat = (unsigned short*)(ebuf + N_EDGES);     // 3*128*256
    float* t1   = (float*)xb;                                     // 50k*128 fp32
    float* t2   = (float*)hb1;                                    // 50k*64 fp32

    fold_bn_kernel<<<1, 384, 0, stream>>>(bn_g, bn_b, bn_m, bn_v,
                                          cg1, cbe1, cm1, cv1,
                                          cg2, cbe2, cm2, cv2, sc);

    convert_x<<<(N_NODES * CDIM / 4 + 255) / 256, 256, 0, stream>>>(x, xb);
    convert_w<<<(NLAYERS * CDIM * 256 + 255) / 256, 256, 0, stream>>>(Wl, Wr, wcat);

    // ---- bucketed CSR build ----
    hipMemsetAsync(bcnt, 0, NBUCK * sizeof(int), stream);
    bucket_count<<<NEB, 256, 0, stream>>>(ei, bcnt);
    scan512<<<1, NBUCK, 0, stream>>>(bcnt, bbase, bcur, rowptr);
    bucket_fill<<<NEB, 256, 0, stream>>>(ei, bcur, ebuf);
    bucket_csr<<<NBUCK, 256, 0, stream>>>(ebuf, bbase, elist, rowptr);

    // ---- 3 fused SAGE layers (bf16 ping-pong: xb->hb0->hb1->hb0) ----
    const unsigned short* lin[NLAYERS] = { xb, hb0, hb1 };
    unsigned short* lout[NLAYERS]      = { hb0, hb1, hb0 };
    for (int l = 0; l < NLAYERS; ++l) {
        sage_fused<<<N_NODES / 32, 256, 0, stream>>>(
            rowptr, elist, lin[l], lout[l],
            wcat + (size_t)l * CDIM * 256,
            bl + (size_t)l * CDIM,
            sc + l * CDIM, sc + 384 + l * CDIM);
    }

    // ---- MLP head on first BATCH rows (input: hb0 bf16) ----
    head_gemm1<<<(BATCH + 31) / 32, 256, 0, stream>>>(hb0, cW1, cb1, sc + 768, sc + 896, t1);
    head_gemm2<<<(BATCH + 63) / 64, 256, 0, stream>>>(t1, cW2, cb2, sc + 1024, sc + 1088, t2);
    head_final<<<(BATCH + 255) / 256, 256, 0, stream>>>(t2, cW3, cb3, (float*)d_out);
}

// Round 8
// 444.675 us; speedup vs baseline: 19.9958x; 1.1151x over previous
//
#include <hip/hip_runtime.h>

#define N_NODES 100000
#define N_EDGES 1600000
#define CDIM    128
#define BATCH   50000
#define NLAYERS 3
#define EPS_BN  1e-5f
#define LPAD    136   // LDS row stride in bf16 elems (272 B)

#define NBUCK   512
#define BW      196   // 512*196 = 100352 >= N_NODES; BW<256 so local dst fits 8 bits
#define EPB     4096  // edges per block, passes A/B
#define NEB     ((N_EDGES + EPB - 1) / EPB)   // 391
#define CAP     4608  // max edges per bucket (mean 3125)

typedef __attribute__((ext_vector_type(8))) short short8;   // 8 bf16
typedef __attribute__((ext_vector_type(4))) float floatx4;  // MFMA acc

__device__ __forceinline__ unsigned short f2bf(float f) {
    unsigned int u = __float_as_uint(f);
    u = u + 0x7FFFu + ((u >> 16) & 1u);   // RTNE
    return (unsigned short)(u >> 16);
}
__device__ __forceinline__ void unpk(unsigned int u, float& lo, float& hi) {
    lo = __uint_as_float(u << 16);
    hi = __uint_as_float(u & 0xFFFF0000u);
}
__device__ __forceinline__ unsigned int pk2(float lo, float hi) {
    return (unsigned int)f2bf(lo) | ((unsigned int)f2bf(hi) << 16);
}

// ---------------------------------------------------------------------------
// Fold BN params. sc[]: [0..383] layer scale, [384..767] layer shift,
// [768..895]/[896..1023] head1 s/t, [1024..1087]/[1088..1151] head2 s/t
// ---------------------------------------------------------------------------
__global__ void fold_bn_kernel(const float* __restrict__ g, const float* __restrict__ b,
                               const float* __restrict__ m, const float* __restrict__ v,
                               const float* __restrict__ cg1, const float* __restrict__ cbe1,
                               const float* __restrict__ cm1, const float* __restrict__ cv1,
                               const float* __restrict__ cg2, const float* __restrict__ cbe2,
                               const float* __restrict__ cm2, const float* __restrict__ cv2,
                               float* __restrict__ sc) {
    int i = threadIdx.x;
    if (i < NLAYERS * CDIM) {
        float s = g[i] * rsqrtf(v[i] + EPS_BN);
        sc[i] = s;
        sc[NLAYERS * CDIM + i] = b[i] - m[i] * s;
    }
    if (i < CDIM) {
        float s = cg1[i] * rsqrtf(cv1[i] + EPS_BN);
        sc[768 + i] = s;
        sc[896 + i] = cbe1[i] - cm1[i] * s;
    }
    if (i < 64) {
        float s = cg2[i] * rsqrtf(cv2[i] + EPS_BN);
        sc[1024 + i] = s;
        sc[1088 + i] = cbe2[i] - cm2[i] * s;
    }
}

// ---------------------------------------------------------------------------
__global__ __launch_bounds__(256) void convert_x(const float* __restrict__ x,
                                                 unsigned short* __restrict__ xb) {
    int i = blockIdx.x * 256 + threadIdx.x;
    const int TOT = N_NODES * CDIM / 4;
    if (i >= TOT) return;
    float4 v = ((const float4*)x)[i];
    ushort4 o;
    o.x = f2bf(v.x); o.y = f2bf(v.y); o.z = f2bf(v.z); o.w = f2bf(v.w);
    ((ushort4*)xb)[i] = o;
}

// wcat[l][n][k]: k<128 -> Wl[l][k][n], k>=128 -> Wr[l][k-128][n]
__global__ __launch_bounds__(256) void convert_w(const float* __restrict__ Wl,
                                                 const float* __restrict__ Wr,
                                                 unsigned short* __restrict__ wcat) {
    int i = blockIdx.x * 256 + threadIdx.x;
    const int TOT = NLAYERS * CDIM * 256;
    if (i >= TOT) return;
    int l = i >> 15;
    int n = (i >> 8) & 127;
    int k = i & 255;
    float w = (k < CDIM) ? Wl[((size_t)l * CDIM + k) * CDIM + n]
                         : Wr[((size_t)l * CDIM + (k - CDIM)) * CDIM + n];
    wcat[i] = f2bf(w);
}

// head weights -> bf16 [n][k]: wh1 128x128 from cW1[k][n], wh2 64x128 from cW2[k][n]
__global__ __launch_bounds__(256) void convert_whead(const float* __restrict__ cW1,
                                                     const float* __restrict__ cW2,
                                                     unsigned short* __restrict__ wh1,
                                                     unsigned short* __restrict__ wh2) {
    int i = blockIdx.x * 256 + threadIdx.x;
    if (i < 128 * 128) {
        int n = i >> 7, k = i & 127;
        wh1[i] = f2bf(cW1[k * 128 + n]);
    } else if (i < 128 * 128 + 64 * 128) {
        int j = i - 128 * 128;
        int n = j >> 7, k = j & 127;
        wh2[j] = f2bf(cW2[k * 64 + n]);
    }
}

// ---------------------------------------------------------------------------
// Bucketed CSR build. ebuf entry packs src (17 bits) | local-dst (8 bits)<<17.
// ---------------------------------------------------------------------------
__global__ __launch_bounds__(256) void bucket_count(const int* __restrict__ ei,
                                                    int* __restrict__ bcnt) {
    __shared__ int lh[NBUCK];
    int tid = threadIdx.x;
    for (int t = tid; t < NBUCK; t += 256) lh[t] = 0;
    __syncthreads();
    int base = blockIdx.x * EPB;
    int cnt = min(EPB, N_EDGES - base);
    for (int i = tid; i < cnt; i += 256) {
        int d = ei[N_EDGES + base + i];
        atomicAdd(&lh[d / BW], 1);
    }
    __syncthreads();
    for (int t = tid; t < NBUCK; t += 256)
        if (lh[t]) atomicAdd(&bcnt[t], lh[t]);
}

__global__ __launch_bounds__(512) void scan512(const int* __restrict__ bcnt,
                                               int* __restrict__ bbase,
                                               int* __restrict__ bcur,
                                               int* __restrict__ rowptr) {
    __shared__ int s[NBUCK];
    int t = threadIdx.x;
    s[t] = bcnt[t];
    __syncthreads();
    for (int off = 1; off < NBUCK; off <<= 1) {
        int v = (t >= off) ? s[t - off] : 0;
        __syncthreads();
        s[t] += v;
        __syncthreads();
    }
    int ex = (t == 0) ? 0 : s[t - 1];
    bbase[t] = ex;
    bcur[t] = ex;
    if (t == NBUCK - 1) {
        bbase[NBUCK] = s[NBUCK - 1];
        rowptr[N_NODES] = N_EDGES;
    }
}

__global__ __launch_bounds__(256) void bucket_fill(const int* __restrict__ ei,
                                                   int* __restrict__ bcur,
                                                   unsigned int* __restrict__ ebuf) {
    __shared__ int lh[NBUCK];
    __shared__ int gb[NBUCK];
    __shared__ int lc[NBUCK];
    __shared__ unsigned int st[EPB];
    int tid = threadIdx.x;
    for (int t = tid; t < NBUCK; t += 256) { lh[t] = 0; lc[t] = 0; }
    __syncthreads();
    int base = blockIdx.x * EPB;
    int cnt = min(EPB, N_EDGES - base);
    for (int i = tid; i < cnt; i += 256) {
        int s = ei[base + i];
        int d = ei[N_EDGES + base + i];
        int b = d / BW;
        int ld = d - b * BW;
        st[i] = (unsigned)s | ((unsigned)ld << 17) | ((unsigned)b << 25);  // b<512 needs 9... pack bucket separately
        // NOTE: b needs 9 bits (512) and 17+8+9=34 > 32 — so recompute b from ld? Can't.
        // Instead store bucket implicitly: recompute from dst. Store dst low bits? Simpler:
        // store src|ld<<17 and bucket in a parallel pass below via lh walk is complex.
        // => keep bucket recomputation: store full dst instead of ld.
        st[i] = (unsigned)s | ((unsigned)ld << 17);   // final: src + local dst
        lh[b] = lh[b];  // no-op to keep b live
        atomicAdd(&lh[b], 1);
    }
    __syncthreads();
    for (int t = tid; t < NBUCK; t += 256) {
        int c = lh[t];
        gb[t] = c ? atomicAdd(&bcur[t], c) : 0;
    }
    __syncthreads();
    for (int i = tid; i < cnt; i += 256) {
        // recompute bucket from dst for routing
        int d = ei[N_EDGES + base + i];
        int b = d / BW;
        unsigned int u = st[i];
        int pos = gb[b] + atomicAdd(&lc[b], 1);
        ebuf[pos] = u;
    }
}

__global__ __launch_bounds__(256) void bucket_csr(const unsigned int* __restrict__ ebuf,
                                                  const int* __restrict__ bbase,
                                                  int* __restrict__ elist,
                                                  int* __restrict__ rowptr) {
    __shared__ unsigned int st[CAP];
    __shared__ int out[CAP];
    __shared__ int h[256], sscan[256], pre[256], cur[256];
    int b = blockIdx.x;
    int tid = threadIdx.x;
    int beg = bbase[b];
    int cnt = min(bbase[b + 1] - beg, CAP);
    h[tid] = 0; cur[tid] = 0;
    __syncthreads();
    int nbase = b * BW;
    for (int i = tid; i < cnt; i += 256) {
        unsigned int u = ebuf[beg + i];
        st[i] = u;
        atomicAdd(&h[u >> 17], 1);
    }
    __syncthreads();
    sscan[tid] = h[tid];
    __syncthreads();
    for (int off = 1; off < 256; off <<= 1) {
        int v = (tid >= off) ? sscan[tid - off] : 0;
        __syncthreads();
        sscan[tid] += v;
        __syncthreads();
    }
    pre[tid] = sscan[tid] - h[tid];
    __syncthreads();
    for (int i = tid; i < cnt; i += 256) {
        unsigned int u = st[i];
        int ld = u >> 17;
        int pos = pre[ld] + atomicAdd(&cur[ld], 1);
        out[pos] = (int)(u & 0x1FFFFu);
    }
    __syncthreads();
    for (int i = tid; i < cnt; i += 256) elist[beg + i] = out[i];
    int gn = nbase + tid;
    if (tid < BW && gn < N_NODES) rowptr[gn] = beg + pre[tid];
}

// ---------------------------------------------------------------------------
// Fused SAGE layer (unchanged from R7): deep gather + MFMA GEMM + coalesced C.
// ---------------------------------------------------------------------------
__global__ __launch_bounds__(256, 8) void sage_fused(const int* __restrict__ rowptr,
                                                     const int* __restrict__ elist,
                                                     const unsigned short* __restrict__ hin,
                                                     unsigned short* __restrict__ hout,
                                                     const unsigned short* __restrict__ wcat,
                                                     const float* __restrict__ bl,
                                                     const float* __restrict__ scale,
                                                     const float* __restrict__ shift) {
    __shared__ unsigned short sA[32][LPAD];
    __shared__ unsigned short sH[32][LPAD];

    int row0 = blockIdx.x * 32;
    int tid = threadIdx.x;
    int lane = tid & 31;
    int grp = tid >> 5;
    int sub = lane >> 4;
    int li  = lane & 15;

    for (int rr = 0; rr < 4; ++rr) {
        int r = rr * 8 + grp;
        int node = row0 + r;
        int beg = rowptr[node];
        int end = rowptr[node + 1];
        float a0 = 0.f, a1 = 0.f, a2 = 0.f, a3 = 0.f,
              a4 = 0.f, a5 = 0.f, a6 = 0.f, a7 = 0.f;
        int j = beg + sub * 4;
        for (; j + 4 <= end; j += 8) {
            int s0 = elist[j], s1 = elist[j + 1], s2 = elist[j + 2], s3 = elist[j + 3];
            uint4 u0 = *((const uint4*)(hin + (size_t)s0 * CDIM + li * 8));
            uint4 u1 = *((const uint4*)(hin + (size_t)s1 * CDIM + li * 8));
            uint4 u2 = *((const uint4*)(hin + (size_t)s2 * CDIM + li * 8));
            uint4 u3 = *((const uint4*)(hin + (size_t)s3 * CDIM + li * 8));
            float lo, hi;
            unpk(u0.x, lo, hi); a0 += lo; a1 += hi;
            unpk(u0.y, lo, hi); a2 += lo; a3 += hi;
            unpk(u0.z, lo, hi); a4 += lo; a5 += hi;
            unpk(u0.w, lo, hi); a6 += lo; a7 += hi;
            unpk(u1.x, lo, hi); a0 += lo; a1 += hi;
            unpk(u1.y, lo, hi); a2 += lo; a3 += hi;
            unpk(u1.z, lo, hi); a4 += lo; a5 += hi;
            unpk(u1.w, lo, hi); a6 += lo; a7 += hi;
            unpk(u2.x, lo, hi); a0 += lo; a1 += hi;
            unpk(u2.y, lo, hi); a2 += lo; a3 += hi;
            unpk(u2.z, lo, hi); a4 += lo; a5 += hi;
            unpk(u2.w, lo, hi); a6 += lo; a7 += hi;
            unpk(u3.x, lo, hi); a0 += lo; a1 += hi;
            unpk(u3.y, lo, hi); a2 += lo; a3 += hi;
            unpk(u3.z, lo, hi); a4 += lo; a5 += hi;
            unpk(u3.w, lo, hi); a6 += lo; a7 += hi;
        }
        for (; j < end; ++j) {
            int s0 = elist[j];
            uint4 u0 = *((const uint4*)(hin + (size_t)s0 * CDIM + li * 8));
            float lo, hi;
            unpk(u0.x, lo, hi); a0 += lo; a1 += hi;
            unpk(u0.y, lo, hi); a2 += lo; a3 += hi;
            unpk(u0.z, lo, hi); a4 += lo; a5 += hi;
            unpk(u0.w, lo, hi); a6 += lo; a7 += hi;
        }
        a0 += __shfl_xor(a0, 16); a1 += __shfl_xor(a1, 16);
        a2 += __shfl_xor(a2, 16); a3 += __shfl_xor(a3, 16);
        a4 += __shfl_xor(a4, 16); a5 += __shfl_xor(a5, 16);
        a6 += __shfl_xor(a6, 16); a7 += __shfl_xor(a7, 16);
        if (sub == 0) {
            float rin = 1.0f / fmaxf((float)(end - beg), 1.0f);
            uint4 o;
            o.x = pk2(a0 * rin, a1 * rin);
            o.y = pk2(a2 * rin, a3 * rin);
            o.z = pk2(a4 * rin, a5 * rin);
            o.w = pk2(a6 * rin, a7 * rin);
            *((uint4*)&sA[r][li * 8]) = o;
        }
    }

    for (int it = 0; it < 4; ++it) {
        int idx = it * 256 + tid;
        int r = idx >> 5;
        int c4 = idx & 31;
        uint2 u = ((const uint2*)(hin + (size_t)(row0 + r) * CDIM))[c4];
        *((uint2*)&sH[r][c4 * 4]) = u;
    }
    __syncthreads();

    int wave = tid >> 6;
    int wl   = tid & 63;
    int ln16 = wl & 15;
    int quad = wl >> 4;

    floatx4 acc[2][2];
#pragma unroll
    for (int mt = 0; mt < 2; ++mt)
#pragma unroll
        for (int nt = 0; nt < 2; ++nt) acc[mt][nt] = (floatx4)0.0f;

    const unsigned short* wbase = wcat + ((size_t)(wave * 32 + ln16) * 256 + quad * 8);

#pragma unroll
    for (int kb = 0; kb < 8; ++kb) {
        int koff = (kb & 3) * 32 + quad * 8;
        const unsigned short* sbuf = (kb < 4) ? &sA[0][0] : &sH[0][0];
        short8 a0 = *((const short8*)(sbuf + (ln16)      * LPAD + koff));
        short8 a1 = *((const short8*)(sbuf + (ln16 + 16) * LPAD + koff));
        short8 b0 = *((const short8*)(wbase + kb * 32));
        short8 b1 = *((const short8*)(wbase + 16 * 256 + kb * 32));
        acc[0][0] = __builtin_amdgcn_mfma_f32_16x16x32_bf16(a0, b0, acc[0][0], 0, 0, 0);
        acc[1][0] = __builtin_amdgcn_mfma_f32_16x16x32_bf16(a1, b0, acc[1][0], 0, 0, 0);
        acc[0][1] = __builtin_amdgcn_mfma_f32_16x16x32_bf16(a0, b1, acc[0][1], 0, 0, 0);
        acc[1][1] = __builtin_amdgcn_mfma_f32_16x16x32_bf16(a1, b1, acc[1][1], 0, 0, 0);
    }

    __syncthreads();
#pragma unroll
    for (int nt = 0; nt < 2; ++nt) {
        int col = wave * 32 + nt * 16 + ln16;
        float bb = bl[col];
        float ss = scale[col];
        float tt = shift[col];
#pragma unroll
        for (int mt = 0; mt < 2; ++mt) {
#pragma unroll
            for (int r = 0; r < 4; ++r) {
                float v = fmaxf(acc[mt][nt][r] + bb, 0.0f) * ss + tt;
                sA[mt * 16 + quad * 4 + r][col] = f2bf(v);
            }
        }
    }
    __syncthreads();
#pragma unroll
    for (int it = 0; it < 2; ++it) {
        int idx = it * 256 + tid;
        int r = idx >> 4;
        int c = idx & 15;
        uint4 u = *((const uint4*)&sA[r][c * 8]);
        *((uint4*)(hout + (size_t)(row0 + r) * CDIM + c * 8)) = u;
    }
}

// ---------------------------------------------------------------------------
// Fused MLP head: per 64-row block,
//   z1 = relu(bn1(h @ cW1 + b1))      [MFMA, K=128 -> 128 cols]
//   z2 = relu(bn2(z1 @ cW2 + b2))     [MFMA, K=128 -> 64 cols]
//   out = z2 @ W3 + b3                [fused into epilogue-2 shuffle-reduce]
// Single LDS tile reused for h then z1. 4 waves: GEMM1 wave->32 cols,
// GEMM2 wave->16 cols.
// ---------------------------------------------------------------------------
__global__ __launch_bounds__(256, 4) void head_fused(const unsigned short* __restrict__ hin,
                                                     const unsigned short* __restrict__ wh1,
                                                     const unsigned short* __restrict__ wh2,
                                                     const float* __restrict__ cb1,
                                                     const float* __restrict__ s1,
                                                     const float* __restrict__ t1,
                                                     const float* __restrict__ cb2,
                                                     const float* __restrict__ s2,
                                                     const float* __restrict__ t2,
                                                     const float* __restrict__ W3,
                                                     const float* __restrict__ b3,
                                                     float* __restrict__ out) {
    __shared__ unsigned short sZ[64][LPAD];
    __shared__ float sP[4][64];
    __shared__ float sw3[64];

    int row0 = blockIdx.x * 64;
    int tid = threadIdx.x;
    if (tid < 64) sw3[tid] = W3[tid];

    // stage 64 input rows (bf16 copy); rows < N_NODES always, safe past BATCH
    for (int it = 0; it < 4; ++it) {
        int idx = it * 256 + tid;
        int r = idx >> 4;
        int c = idx & 15;
        uint4 u = *((const uint4*)(hin + (size_t)(row0 + r) * CDIM + c * 8));
        *((uint4*)&sZ[r][c * 8]) = u;
    }
    __syncthreads();

    int wave = tid >> 6;
    int wl   = tid & 63;
    int ln16 = wl & 15;
    int quad = wl >> 4;

    // ---- GEMM1: 64x128 @ 128x128; wave covers cols [wave*32, wave*32+32) ----
    floatx4 a1[4][2];
#pragma unroll
    for (int mt = 0; mt < 4; ++mt) { a1[mt][0] = (floatx4)0.0f; a1[mt][1] = (floatx4)0.0f; }

    const unsigned short* w1a = wh1 + (size_t)(wave * 32 + ln16) * 128 + quad * 8;
    const unsigned short* w1b = w1a + 16 * 128;

#pragma unroll
    for (int kb = 0; kb < 4; ++kb) {
        int koff = kb * 32 + quad * 8;
        short8 b0 = *((const short8*)(w1a + kb * 32));
        short8 b1 = *((const short8*)(w1b + kb * 32));
#pragma unroll
        for (int mt = 0; mt < 4; ++mt) {
            short8 af = *((const short8*)(&sZ[mt * 16 + ln16][koff]));
            a1[mt][0] = __builtin_amdgcn_mfma_f32_16x16x32_bf16(af, b0, a1[mt][0], 0, 0, 0);
            a1[mt][1] = __builtin_amdgcn_mfma_f32_16x16x32_bf16(af, b1, a1[mt][1], 0, 0, 0);
        }
    }

    __syncthreads();   // all sZ reads done before overwrite with z1
#pragma unroll
    for (int nt = 0; nt < 2; ++nt) {
        int col = wave * 32 + nt * 16 + ln16;
        float bb = cb1[col], ss = s1[col], tt = t1[col];
#pragma unroll
        for (int mt = 0; mt < 4; ++mt) {
#pragma unroll
            for (int r = 0; r < 4; ++r) {
                float v = fmaxf((a1[mt][nt][r] + bb) * ss + tt, 0.0f);
                sZ[mt * 16 + quad * 4 + r][col] = f2bf(v);
            }
        }
    }
    __syncthreads();

    // ---- GEMM2: 64x128 @ 128x64; wave covers cols [wave*16, wave*16+16) ----
    floatx4 a2[4];
#pragma unroll
    for (int mt = 0; mt < 4; ++mt) a2[mt] = (floatx4)0.0f;

    const unsigned short* w2a = wh2 + (size_t)(wave * 16 + ln16) * 128 + quad * 8;

#pragma unroll
    for (int kb = 0; kb < 4; ++kb) {
        int koff = kb * 32 + quad * 8;
        short8 b0 = *((const short8*)(w2a + kb * 32));
#pragma unroll
        for (int mt = 0; mt < 4; ++mt) {
            short8 af = *((const short8*)(&sZ[mt * 16 + ln16][koff]));
            a2[mt] = __builtin_amdgcn_mfma_f32_16x16x32_bf16(af, b0, a2[mt], 0, 0, 0);
        }
    }

    // ---- epilogue2: relu(bn2)*W3, reduce over the wave's 16 cols ----
    {
        int col = wave * 16 + ln16;
        float bb = cb2[col], ss = s2[col], tt = t2[col];
        float w3v = sw3[col];
#pragma unroll
        for (int mt = 0; mt < 4; ++mt) {
#pragma unroll
            for (int r = 0; r < 4; ++r) {
                float v = fmaxf((a2[mt][r] + bb) * ss + tt, 0.0f) * w3v;
                v += __shfl_xor(v, 1);
                v += __shfl_xor(v, 2);
                v += __shfl_xor(v, 4);
                v += __shfl_xor(v, 8);
                if (ln16 == 0) sP[wave][mt * 16 + quad * 4 + r] = v;
            }
        }
    }
    __syncthreads();
    if (tid < 64) {
        int row = row0 + tid;
        if (row < BATCH)
            out[row] = sP[0][tid] + sP[1][tid] + sP[2][tid] + sP[3][tid] + b3[0];
    }
}

// ---------------------------------------------------------------------------
extern "C" void kernel_launch(void* const* d_in, const int* in_sizes, int n_in,
                              void* d_out, int out_size, void* d_ws, size_t ws_size,
                              hipStream_t stream) {
    const float* x    = (const float*)d_in[0];
    const int*   ei   = (const int*)d_in[1];
    const float* Wl   = (const float*)d_in[3];
    const float* bl   = (const float*)d_in[4];
    const float* Wr   = (const float*)d_in[5];
    const float* bn_g = (const float*)d_in[6];
    const float* bn_b = (const float*)d_in[7];
    const float* bn_m = (const float*)d_in[8];
    const float* bn_v = (const float*)d_in[9];
    const float* cW1  = (const float*)d_in[10];
    const float* cb1  = (const float*)d_in[11];
    const float* cg1  = (const float*)d_in[12];
    const float* cbe1 = (const float*)d_in[13];
    const float* cm1  = (const float*)d_in[14];
    const float* cv1  = (const float*)d_in[15];
    const float* cW2  = (const float*)d_in[16];
    const float* cb2  = (const float*)d_in[17];
    const float* cg2  = (const float*)d_in[18];
    const float* cbe2 = (const float*)d_in[19];
    const float* cm2  = (const float*)d_in[20];
    const float* cv2  = (const float*)d_in[21];
    const float* cW3  = (const float*)d_in[22];
    const float* cb3  = (const float*)d_in[23];

    // Workspace layout (float-index units; all vector-load regions 16B-aligned):
    float* ws  = (float*)d_ws;
    unsigned short* xb  = (unsigned short*)ws;                      // N*C bf16
    unsigned short* hb0 = (unsigned short*)(ws + 6400000);          // N*C bf16
    unsigned short* hb1 = (unsigned short*)(ws + 12800000);         // N*C bf16
    float* sc    = ws + 19200000;                                   // 1152
    int* rowptr  = (int*)(ws + 19201152);                           // 100001
    int* bcnt    = (int*)(ws + 19301156);                           // 512
    int* bbase   = (int*)(ws + 19301668);                           // 513
    int* bcur    = (int*)(ws + 19302184);                           // 512
    int* elist   = (int*)(ws + 19302696);                           // E
    unsigned int* ebuf = (unsigned int*)(ws + 20902696);            // E (packed)
    unsigned short* wcat = (unsigned short*)(ws + 22502696);        // 3*128*256
    unsigned short* wh1  = (unsigned short*)(ws + 22551848);        // 128*128
    unsigned short* wh2  = (unsigned short*)(ws + 22560040);        // 64*128

    fold_bn_kernel<<<1, 384, 0, stream>>>(bn_g, bn_b, bn_m, bn_v,
                                          cg1, cbe1, cm1, cv1,
                                          cg2, cbe2, cm2, cv2, sc);

    convert_x<<<(N_NODES * CDIM / 4 + 255) / 256, 256, 0, stream>>>(x, xb);
    convert_w<<<(NLAYERS * CDIM * 256 + 255) / 256, 256, 0, stream>>>(Wl, Wr, wcat);
    convert_whead<<<(128 * 128 + 64 * 128 + 255) / 256, 256, 0, stream>>>(cW1, cW2, wh1, wh2);

    // ---- bucketed CSR build ----
    hipMemsetAsync(bcnt, 0, NBUCK * sizeof(int), stream);
    bucket_count<<<NEB, 256, 0, stream>>>(ei, bcnt);
    scan512<<<1, NBUCK, 0, stream>>>(bcnt, bbase, bcur, rowptr);
    bucket_fill<<<NEB, 256, 0, stream>>>(ei, bcur, ebuf);
    bucket_csr<<<NBUCK, 256, 0, stream>>>(ebuf, bbase, elist, rowptr);

    // ---- 3 fused SAGE layers (bf16 ping-pong: xb->hb0->hb1->hb0) ----
    const unsigned short* lin[NLAYERS] = { xb, hb0, hb1 };
    unsigned short* lout[NLAYERS]      = { hb0, hb1, hb0 };
    for (int l = 0; l < NLAYERS; ++l) {
        sage_fused<<<N_NODES / 32, 256, 0, stream>>>(
            rowptr, elist, lin[l], lout[l],
            wcat + (size_t)l * CDIM * 256,
            bl + (size_t)l * CDIM,
            sc + l * CDIM, sc + 384 + l * CDIM);
    }

    // ---- fused MLP head on first BATCH rows (input: hb0 bf16) ----
    head_fused<<<(BATCH + 63) / 64, 256, 0, stream>>>(
        hb0, wh1, wh2,
        cb1, sc + 768, sc + 896,
        cb2, sc + 1024, sc + 1088,
        cW3, cb3, (float*)d_out);
}

// Round 9
// 421.164 us; speedup vs baseline: 21.1120x; 1.0558x over previous
//
#include <hip/hip_runtime.h>

#define N_NODES 100000
#define N_EDGES 1600000
#define CDIM    128
#define BATCH   50000
#define NLAYERS 3
#define EPS_BN  1e-5f
#define LPAD    136   // LDS row stride in bf16 elems (272 B)

#define NBUCK   1024
#define BW      98      // 1024*98 = 100352 >= N_NODES; local dst fits 7 bits (<128)
#define EPB     4096    // edges per block in bucket_fill
#define NEB     ((N_EDGES + EPB - 1) / EPB)   // 391
#define EBCAP   2048    // ebuf slots per bucket (mean 1562, sd ~40 -> +12 sigma)
#define CAPP    2752    // elist slots per bucket (2048 + 98*7 padded, mult of 8)

typedef __attribute__((ext_vector_type(8))) short short8;   // 8 bf16
typedef __attribute__((ext_vector_type(4))) float floatx4;  // MFMA acc

__device__ __forceinline__ unsigned short f2bf(float f) {
    unsigned int u = __float_as_uint(f);
    u = u + 0x7FFFu + ((u >> 16) & 1u);   // RTNE
    return (unsigned short)(u >> 16);
}
__device__ __forceinline__ void unpk(unsigned int u, float& lo, float& hi) {
    lo = __uint_as_float(u << 16);
    hi = __uint_as_float(u & 0xFFFF0000u);
}
__device__ __forceinline__ unsigned int pk2(float lo, float hi) {
    return (unsigned int)f2bf(lo) | ((unsigned int)f2bf(hi) << 16);
}

// Workspace float-offsets
#define OFF_HB0   6400080
#define OFF_HB1   12800160
#define OFF_SC    19200240
#define OFF_RP2   19201392
#define OFF_RDEG  19401392
#define OFF_BCUR  19501392
#define OFF_ELIST 19502416
#define OFF_EBUF  22320464
#define OFF_WCAT  24417616
#define OFF_WH1   24466768
#define OFF_WH2   24474960

// ---------------------------------------------------------------------------
// Mega setup kernel: block-role partitioned.
//  [0, 12500)           convert_x  (N*C/4 float4s)
//  [12500, 12884)       convert_w  (3*128*256 elems)
//  [12884, 12980)       convert_whead (128*128 + 64*128)
//  12980                fold_bn + bcur init + zero rows of xb/hb0/hb1
// ---------------------------------------------------------------------------
#define XBLK 12500
#define WBLK 384
#define HBLK 96
__global__ __launch_bounds__(256) void setup_all(
        const float* __restrict__ x,
        const float* __restrict__ Wl, const float* __restrict__ Wr,
        const float* __restrict__ cW1, const float* __restrict__ cW2,
        const float* __restrict__ g, const float* __restrict__ b,
        const float* __restrict__ m, const float* __restrict__ v,
        const float* __restrict__ cg1, const float* __restrict__ cbe1,
        const float* __restrict__ cm1, const float* __restrict__ cv1,
        const float* __restrict__ cg2, const float* __restrict__ cbe2,
        const float* __restrict__ cm2, const float* __restrict__ cv2,
        float* __restrict__ ws) {
    int blk = blockIdx.x;
    int tid = threadIdx.x;
    unsigned short* xb  = (unsigned short*)ws;
    unsigned short* hb0 = (unsigned short*)(ws + OFF_HB0);
    unsigned short* hb1 = (unsigned short*)(ws + OFF_HB1);

    if (blk < XBLK) {
        int i = blk * 256 + tid;           // < 3,200,000
        float4 vv = ((const float4*)x)[i];
        ushort4 o;
        o.x = f2bf(vv.x); o.y = f2bf(vv.y); o.z = f2bf(vv.z); o.w = f2bf(vv.w);
        ((ushort4*)xb)[i] = o;
        return;
    }
    if (blk < XBLK + WBLK) {
        unsigned short* wcat = (unsigned short*)(ws + OFF_WCAT);
        int i = (blk - XBLK) * 256 + tid;  // l*32768 + n*256 + k
        int l = i >> 15;
        int n = (i >> 8) & 127;
        int k = i & 255;
        float w = (k < CDIM) ? Wl[((size_t)l * CDIM + k) * CDIM + n]
                             : Wr[((size_t)l * CDIM + (k - CDIM)) * CDIM + n];
        wcat[i] = f2bf(w);
        return;
    }
    if (blk < XBLK + WBLK + HBLK) {
        unsigned short* wh1 = (unsigned short*)(ws + OFF_WH1);
        unsigned short* wh2 = (unsigned short*)(ws + OFF_WH2);
        int i = (blk - XBLK - WBLK) * 256 + tid;
        if (i < 128 * 128) {
            int n = i >> 7, k = i & 127;
            wh1[i] = f2bf(cW1[k * 128 + n]);
        } else if (i < 128 * 128 + 64 * 128) {
            int j = i - 128 * 128;
            int n = j >> 7, k = j & 127;
            wh2[j] = f2bf(cW2[k * 64 + n]);
        }
        return;
    }
    // misc block
    float* sc = ws + OFF_SC;
    int* bcur = (int*)(ws + OFF_BCUR);
    for (int i = tid; i < NLAYERS * CDIM; i += 256) {
        float s = g[i] * rsqrtf(v[i] + EPS_BN);
        sc[i] = s;
        sc[NLAYERS * CDIM + i] = b[i] - m[i] * s;
    }
    if (tid < CDIM) {
        float s = cg1[tid] * rsqrtf(cv1[tid] + EPS_BN);
        sc[768 + tid] = s;
        sc[896 + tid] = cbe1[tid] - cm1[tid] * s;
    }
    if (tid < 64) {
        float s = cg2[tid] * rsqrtf(cv2[tid] + EPS_BN);
        sc[1024 + tid] = s;
        sc[1088 + tid] = cbe2[tid] - cm2[tid] * s;
    }
    for (int i = tid; i < NBUCK; i += 256) bcur[i] = i * EBCAP;
    // zero sentinel row (node N_NODES) in all three h buffers
    if (tid < 48) {
        int buf = tid >> 4, c = tid & 15;
        unsigned short* p = (buf == 0 ? xb : buf == 1 ? hb0 : hb1) + (size_t)N_NODES * CDIM;
        ((uint4*)p)[c] = make_uint4(0, 0, 0, 0);
    }
}

// ---------------------------------------------------------------------------
// bucket_fill: stage EPB edges in LDS (src|ld<<17 + bucket ushort), reserve
// per-bucket chunks in fixed ebuf regions, scatter bucket-grouped.
// ---------------------------------------------------------------------------
__global__ __launch_bounds__(256) void bucket_fill(const int* __restrict__ ei,
                                                   int* __restrict__ bcur,
                                                   unsigned int* __restrict__ ebuf) {
    __shared__ unsigned int st[EPB];      // 16 KB
    __shared__ unsigned short sb[EPB];    // 8 KB
    __shared__ int lh[NBUCK];             // 4 KB
    __shared__ int gb[NBUCK];             // 4 KB
    __shared__ int lc[NBUCK];             // 4 KB
    int tid = threadIdx.x;
    for (int t = tid; t < NBUCK; t += 256) { lh[t] = 0; lc[t] = 0; }
    __syncthreads();
    int base = blockIdx.x * EPB;
    int cnt = min(EPB, N_EDGES - base);
    for (int k = tid; k < cnt / 4; k += 256) {
        int4 s4 = ((const int4*)(ei + base))[k];
        int4 d4 = ((const int4*)(ei + N_EDGES + base))[k];
        int i0 = k * 4;
#pragma unroll
        for (int q = 0; q < 4; ++q) {
            int s = (q == 0) ? s4.x : (q == 1) ? s4.y : (q == 2) ? s4.z : s4.w;
            int d = (q == 0) ? d4.x : (q == 1) ? d4.y : (q == 2) ? d4.z : d4.w;
            int bk = (unsigned)d / BW;
            int ld = d - bk * BW;
            st[i0 + q] = (unsigned)s | ((unsigned)ld << 17);
            sb[i0 + q] = (unsigned short)bk;
            atomicAdd(&lh[bk], 1);
        }
    }
    __syncthreads();
    for (int t = tid; t < NBUCK; t += 256) {
        int c = lh[t];
        gb[t] = c ? atomicAdd(&bcur[t], c) : 0;
    }
    __syncthreads();
    for (int i = tid; i < cnt; i += 256) {
        int bk = sb[i];
        int pos = gb[bk] + atomicAdd(&lc[bk], 1);
        ebuf[pos] = st[i];
    }
}

// ---------------------------------------------------------------------------
// bucket_csr: one block per bucket. Build 8-padded local CSR in LDS
// (sentinel src = N_NODES -> zero row), write coalesced elist, rowptr2
// (beg, padded_len) and rdeg (1/max(deg,1)).
// ---------------------------------------------------------------------------
__global__ __launch_bounds__(256) void bucket_csr(const unsigned int* __restrict__ ebuf,
                                                  const int* __restrict__ bcur,
                                                  int* __restrict__ elist,
                                                  int2* __restrict__ rowptr2,
                                                  float* __restrict__ rdeg) {
    __shared__ unsigned int st[EBCAP];    // 8 KB
    __shared__ int out[CAPP];             // 11 KB
    __shared__ int h[128], ppre[128], cur[128], sscan[256];
    __shared__ int tot;
    int b = blockIdx.x;
    int tid = threadIdx.x;
    int ebase = b * EBCAP;
    int cnt = min(bcur[b] - ebase, EBCAP);
    if (tid < 128) { h[tid] = 0; cur[tid] = 0; }
    __syncthreads();
    for (int i = tid; i < cnt; i += 256) {
        unsigned int u = ebuf[ebase + i];
        st[i] = u;
        atomicAdd(&h[u >> 17], 1);
    }
    __syncthreads();
    int pad = (tid < 128) ? ((h[tid] + 7) & ~7) : 0;
    sscan[tid] = pad;
    __syncthreads();
    for (int off = 1; off < 256; off <<= 1) {
        int vv = (tid >= off) ? sscan[tid - off] : 0;
        __syncthreads();
        sscan[tid] += vv;
        __syncthreads();
    }
    if (tid < 128) ppre[tid] = sscan[tid] - pad;
    if (tid == 127) tot = sscan[127];
    __syncthreads();
    int total_pad = tot;
    for (int i = tid; i < total_pad; i += 256) out[i] = N_NODES;  // sentinel
    __syncthreads();
    for (int i = tid; i < cnt; i += 256) {
        unsigned int u = st[i];
        int ld = u >> 17;
        int pos = ppre[ld] + atomicAdd(&cur[ld], 1);
        out[pos] = (int)(u & 0x1FFFFu);
    }
    __syncthreads();
    int obase = b * CAPP;
    for (int i = tid; i < total_pad; i += 256) elist[obase + i] = out[i];
    if (tid < BW) {
        int gn = b * BW + tid;
        if (gn < N_NODES) {
            rowptr2[gn] = make_int2(obase + ppre[tid], (h[tid] + 7) & ~7);
            rdeg[gn] = 1.0f / fmaxf((float)h[tid], 1.0f);
        }
    }
}

// ---------------------------------------------------------------------------
// Fused SAGE layer: branch-free padded gather (int4 elist, zero-row sentinel),
// MFMA GEMM, coalesced bf16 C store.
// ---------------------------------------------------------------------------
__global__ __launch_bounds__(256, 8) void sage_fused(const int2* __restrict__ rowptr2,
                                                     const float* __restrict__ rdeg,
                                                     const int* __restrict__ elist,
                                                     const unsigned short* __restrict__ hin,
                                                     unsigned short* __restrict__ hout,
                                                     const unsigned short* __restrict__ wcat,
                                                     const float* __restrict__ bl,
                                                     const float* __restrict__ scale,
                                                     const float* __restrict__ shift) {
    __shared__ unsigned short sA[32][LPAD];
    __shared__ unsigned short sH[32][LPAD];

    int row0 = blockIdx.x * 32;
    int tid = threadIdx.x;
    int lane = tid & 31;
    int grp = tid >> 5;       // 8 node-groups
    int sub = lane >> 4;      // 0/1: chunk parity
    int li  = lane & 15;      // 16 lanes x 8 channels

    for (int rr = 0; rr < 4; ++rr) {
        int r = rr * 8 + grp;
        int node = row0 + r;
        int2 rp = rowptr2[node];
        int beg = rp.x;
        int end = beg + rp.y;
        float a0 = 0.f, a1 = 0.f, a2 = 0.f, a3 = 0.f,
              a4 = 0.f, a5 = 0.f, a6 = 0.f, a7 = 0.f;
        for (int j = beg + sub * 4; j < end; j += 8) {
            int4 sv = *((const int4*)(elist + j));
            uint4 u0 = *((const uint4*)(hin + (size_t)sv.x * CDIM + li * 8));
            uint4 u1 = *((const uint4*)(hin + (size_t)sv.y * CDIM + li * 8));
            uint4 u2 = *((const uint4*)(hin + (size_t)sv.z * CDIM + li * 8));
            uint4 u3 = *((const uint4*)(hin + (size_t)sv.w * CDIM + li * 8));
            float lo, hi;
            unpk(u0.x, lo, hi); a0 += lo; a1 += hi;
            unpk(u0.y, lo, hi); a2 += lo; a3 += hi;
            unpk(u0.z, lo, hi); a4 += lo; a5 += hi;
            unpk(u0.w, lo, hi); a6 += lo; a7 += hi;
            unpk(u1.x, lo, hi); a0 += lo; a1 += hi;
            unpk(u1.y, lo, hi); a2 += lo; a3 += hi;
            unpk(u1.z, lo, hi); a4 += lo; a5 += hi;
            unpk(u1.w, lo, hi); a6 += lo; a7 += hi;
            unpk(u2.x, lo, hi); a0 += lo; a1 += hi;
            unpk(u2.y, lo, hi); a2 += lo; a3 += hi;
            unpk(u2.z, lo, hi); a4 += lo; a5 += hi;
            unpk(u2.w, lo, hi); a6 += lo; a7 += hi;
            unpk(u3.x, lo, hi); a0 += lo; a1 += hi;
            unpk(u3.y, lo, hi); a2 += lo; a3 += hi;
            unpk(u3.z, lo, hi); a4 += lo; a5 += hi;
            unpk(u3.w, lo, hi); a6 += lo; a7 += hi;
        }
        a0 += __shfl_xor(a0, 16); a1 += __shfl_xor(a1, 16);
        a2 += __shfl_xor(a2, 16); a3 += __shfl_xor(a3, 16);
        a4 += __shfl_xor(a4, 16); a5 += __shfl_xor(a5, 16);
        a6 += __shfl_xor(a6, 16); a7 += __shfl_xor(a7, 16);
        if (sub == 0) {
            float rin = rdeg[node];
            uint4 o;
            o.x = pk2(a0 * rin, a1 * rin);
            o.y = pk2(a2 * rin, a3 * rin);
            o.z = pk2(a4 * rin, a5 * rin);
            o.w = pk2(a6 * rin, a7 * rin);
            *((uint4*)&sA[r][li * 8]) = o;
        }
    }

    // stage own rows (bf16 copy)
    for (int it = 0; it < 4; ++it) {
        int idx = it * 256 + tid;
        int r = idx >> 5;
        int c4 = idx & 31;
        uint2 u = ((const uint2*)(hin + (size_t)(row0 + r) * CDIM))[c4];
        *((uint2*)&sH[r][c4 * 4]) = u;
    }
    __syncthreads();

    int wave = tid >> 6;
    int wl   = tid & 63;
    int ln16 = wl & 15;
    int quad = wl >> 4;

    floatx4 acc[2][2];
#pragma unroll
    for (int mt = 0; mt < 2; ++mt)
#pragma unroll
        for (int nt = 0; nt < 2; ++nt) acc[mt][nt] = (floatx4)0.0f;

    const unsigned short* wbase = wcat + ((size_t)(wave * 32 + ln16) * 256 + quad * 8);

#pragma unroll
    for (int kb = 0; kb < 8; ++kb) {
        int koff = (kb & 3) * 32 + quad * 8;
        const unsigned short* sbuf = (kb < 4) ? &sA[0][0] : &sH[0][0];
        short8 a0 = *((const short8*)(sbuf + (ln16)      * LPAD + koff));
        short8 a1 = *((const short8*)(sbuf + (ln16 + 16) * LPAD + koff));
        short8 b0 = *((const short8*)(wbase + kb * 32));
        short8 b1 = *((const short8*)(wbase + 16 * 256 + kb * 32));
        acc[0][0] = __builtin_amdgcn_mfma_f32_16x16x32_bf16(a0, b0, acc[0][0], 0, 0, 0);
        acc[1][0] = __builtin_amdgcn_mfma_f32_16x16x32_bf16(a1, b0, acc[1][0], 0, 0, 0);
        acc[0][1] = __builtin_amdgcn_mfma_f32_16x16x32_bf16(a0, b1, acc[0][1], 0, 0, 0);
        acc[1][1] = __builtin_amdgcn_mfma_f32_16x16x32_bf16(a1, b1, acc[1][1], 0, 0, 0);
    }

    __syncthreads();
#pragma unroll
    for (int nt = 0; nt < 2; ++nt) {
        int col = wave * 32 + nt * 16 + ln16;
        float bb = bl[col];
        float ss = scale[col];
        float tt = shift[col];
#pragma unroll
        for (int mt = 0; mt < 2; ++mt) {
#pragma unroll
            for (int r = 0; r < 4; ++r) {
                float v = fmaxf(acc[mt][nt][r] + bb, 0.0f) * ss + tt;
                sA[mt * 16 + quad * 4 + r][col] = f2bf(v);
            }
        }
    }
    __syncthreads();
#pragma unroll
    for (int it = 0; it < 2; ++it) {
        int idx = it * 256 + tid;
        int r = idx >> 4;
        int c = idx & 15;
        uint4 u = *((const uint4*)&sA[r][c * 8]);
        *((uint4*)(hout + (size_t)(row0 + r) * CDIM + c * 8)) = u;
    }
}

// ---------------------------------------------------------------------------
// Fused MLP head (unchanged from R8)
// ---------------------------------------------------------------------------
__global__ __launch_bounds__(256, 4) void head_fused(const unsigned short* __restrict__ hin,
                                                     const unsigned short* __restrict__ wh1,
                                                     const unsigned short* __restrict__ wh2,
                                                     const float* __restrict__ cb1,
                                                     const float* __restrict__ s1,
                                                     const float* __restrict__ t1,
                                                     const float* __restrict__ cb2,
                                                     const float* __restrict__ s2,
                                                     const float* __restrict__ t2,
                                                     const float* __restrict__ W3,
                                                     const float* __restrict__ b3,
                                                     float* __restrict__ out) {
    __shared__ unsigned short sZ[64][LPAD];
    __shared__ float sP[4][64];
    __shared__ float sw3[64];

    int row0 = blockIdx.x * 64;
    int tid = threadIdx.x;
    if (tid < 64) sw3[tid] = W3[tid];

    for (int it = 0; it < 4; ++it) {
        int idx = it * 256 + tid;
        int r = idx >> 4;
        int c = idx & 15;
        uint4 u = *((const uint4*)(hin + (size_t)(row0 + r) * CDIM + c * 8));
        *((uint4*)&sZ[r][c * 8]) = u;
    }
    __syncthreads();

    int wave = tid >> 6;
    int wl   = tid & 63;
    int ln16 = wl & 15;
    int quad = wl >> 4;

    floatx4 a1[4][2];
#pragma unroll
    for (int mt = 0; mt < 4; ++mt) { a1[mt][0] = (floatx4)0.0f; a1[mt][1] = (floatx4)0.0f; }

    const unsigned short* w1a = wh1 + (size_t)(wave * 32 + ln16) * 128 + quad * 8;
    const unsigned short* w1b = w1a + 16 * 128;

#pragma unroll
    for (int kb = 0; kb < 4; ++kb) {
        int koff = kb * 32 + quad * 8;
        short8 b0 = *((const short8*)(w1a + kb * 32));
        short8 b1 = *((const short8*)(w1b + kb * 32));
#pragma unroll
        for (int mt = 0; mt < 4; ++mt) {
            short8 af = *((const short8*)(&sZ[mt * 16 + ln16][koff]));
            a1[mt][0] = __builtin_amdgcn_mfma_f32_16x16x32_bf16(af, b0, a1[mt][0], 0, 0, 0);
            a1[mt][1] = __builtin_amdgcn_mfma_f32_16x16x32_bf16(af, b1, a1[mt][1], 0, 0, 0);
        }
    }

    __syncthreads();
#pragma unroll
    for (int nt = 0; nt < 2; ++nt) {
        int col = wave * 32 + nt * 16 + ln16;
        float bb = cb1[col], ss = s1[col], tt = t1[col];
#pragma unroll
        for (int mt = 0; mt < 4; ++mt) {
#pragma unroll
            for (int r = 0; r < 4; ++r) {
                float v = fmaxf((a1[mt][nt][r] + bb) * ss + tt, 0.0f);
                sZ[mt * 16 + quad * 4 + r][col] = f2bf(v);
            }
        }
    }
    __syncthreads();

    floatx4 a2[4];
#pragma unroll
    for (int mt = 0; mt < 4; ++mt) a2[mt] = (floatx4)0.0f;

    const unsigned short* w2a = wh2 + (size_t)(wave * 16 + ln16) * 128 + quad * 8;

#pragma unroll
    for (int kb = 0; kb < 4; ++kb) {
        int koff = kb * 32 + quad * 8;
        short8 b0 = *((const short8*)(w2a + kb * 32));
#pragma unroll
        for (int mt = 0; mt < 4; ++mt) {
            short8 af = *((const short8*)(&sZ[mt * 16 + ln16][koff]));
            a2[mt] = __builtin_amdgcn_mfma_f32_16x16x32_bf16(af, b0, a2[mt], 0, 0, 0);
        }
    }

    {
        int col = wave * 16 + ln16;
        float bb = cb2[col], ss = s2[col], tt = t2[col];
        float w3v = sw3[col];
#pragma unroll
        for (int mt = 0; mt < 4; ++mt) {
#pragma unroll
            for (int r = 0; r < 4; ++r) {
                float v = fmaxf((a2[mt][r] + bb) * ss + tt, 0.0f) * w3v;
                v += __shfl_xor(v, 1);
                v += __shfl_xor(v, 2);
                v += __shfl_xor(v, 4);
                v += __shfl_xor(v, 8);
                if (ln16 == 0) sP[wave][mt * 16 + quad * 4 + r] = v;
            }
        }
    }
    __syncthreads();
    if (tid < 64) {
        int row = row0 + tid;
        if (row < BATCH)
            out[row] = sP[0][tid] + sP[1][tid] + sP[2][tid] + sP[3][tid] + b3[0];
    }
}

// ---------------------------------------------------------------------------
extern "C" void kernel_launch(void* const* d_in, const int* in_sizes, int n_in,
                              void* d_out, int out_size, void* d_ws, size_t ws_size,
                              hipStream_t stream) {
    const float* x    = (const float*)d_in[0];
    const int*   ei   = (const int*)d_in[1];
    const float* Wl   = (const float*)d_in[3];
    const float* bl   = (const float*)d_in[4];
    const float* Wr   = (const float*)d_in[5];
    const float* bn_g = (const float*)d_in[6];
    const float* bn_b = (const float*)d_in[7];
    const float* bn_m = (const float*)d_in[8];
    const float* bn_v = (const float*)d_in[9];
    const float* cW1  = (const float*)d_in[10];
    const float* cb1  = (const float*)d_in[11];
    const float* cg1  = (const float*)d_in[12];
    const float* cbe1 = (const float*)d_in[13];
    const float* cm1  = (const float*)d_in[14];
    const float* cv1  = (const float*)d_in[15];
    const float* cW2  = (const float*)d_in[16];
    const float* cb2  = (const float*)d_in[17];
    const float* cg2  = (const float*)d_in[18];
    const float* cbe2 = (const float*)d_in[19];
    const float* cm2  = (const float*)d_in[20];
    const float* cv2  = (const float*)d_in[21];
    const float* cW3  = (const float*)d_in[22];
    const float* cb3  = (const float*)d_in[23];

    float* ws  = (float*)d_ws;
    unsigned short* xb  = (unsigned short*)ws;
    unsigned short* hb0 = (unsigned short*)(ws + OFF_HB0);
    unsigned short* hb1 = (unsigned short*)(ws + OFF_HB1);
    float* sc    = ws + OFF_SC;
    int2* rowptr2 = (int2*)(ws + OFF_RP2);
    float* rdeg  = ws + OFF_RDEG;
    int* bcur    = (int*)(ws + OFF_BCUR);
    int* elist   = (int*)(ws + OFF_ELIST);
    unsigned int* ebuf = (unsigned int*)(ws + OFF_EBUF);
    unsigned short* wcat = (unsigned short*)(ws + OFF_WCAT);
    unsigned short* wh1  = (unsigned short*)(ws + OFF_WH1);
    unsigned short* wh2  = (unsigned short*)(ws + OFF_WH2);

    setup_all<<<XBLK + WBLK + HBLK + 1, 256, 0, stream>>>(
        x, Wl, Wr, cW1, cW2,
        bn_g, bn_b, bn_m, bn_v,
        cg1, cbe1, cm1, cv1,
        cg2, cbe2, cm2, cv2, ws);

    bucket_fill<<<NEB, 256, 0, stream>>>(ei, bcur, ebuf);
    bucket_csr<<<NBUCK, 256, 0, stream>>>(ebuf, bcur, elist, rowptr2, rdeg);

    const unsigned short* lin[NLAYERS] = { xb, hb0, hb1 };
    unsigned short* lout[NLAYERS]      = { hb0, hb1, hb0 };
    for (int l = 0; l < NLAYERS; ++l) {
        sage_fused<<<N_NODES / 32, 256, 0, stream>>>(
            rowptr2, rdeg, elist, lin[l], lout[l],
            wcat + (size_t)l * CDIM * 256,
            bl + (size_t)l * CDIM,
            sc + l * CDIM, sc + 384 + l * CDIM);
    }

    head_fused<<<(BATCH + 63) / 64, 256, 0, stream>>>(
        hb0, wh1, wh2,
        cb1, sc + 768, sc + 896,
        cb2, sc + 1024, sc + 1088,
        cW3, cb3, (float*)d_out);
}